// Round 11
// baseline (1848.156 us; speedup 1.0000x reference)
//
#include <hip/hip_runtime.h>

#define N_NODES 10000
#define EMB     128
#define NE      320000
#define NE_TOT  330000   // + one self-loop per node
#define NB      256
#define NTT     200
#define RH      256
#define G3      768

typedef unsigned short u16;
typedef u16    u16x8  __attribute__((ext_vector_type(8)));
typedef __bf16 bf16x8 __attribute__((ext_vector_type(8)));
typedef float  f32x4  __attribute__((ext_vector_type(4)));

static __device__ __forceinline__ float bf2f(u16 u){
  unsigned int x = ((unsigned int)u) << 16;
  return __builtin_bit_cast(float, x);
}
static __device__ __forceinline__ u16 f2bf(float f){
  unsigned int x = __builtin_bit_cast(unsigned int, f);
  x += 0x7fffu + ((x >> 16) & 1u);
  return (u16)(x >> 16);
}

// async global->LDS, 16B per lane; lds dest must be the WAVE base (HW adds lane*16)
static __device__ __forceinline__ void stage16(const u16* g, u16* lds_wavebase, u16* lds_lane){
#if __has_builtin(__builtin_amdgcn_global_load_lds)
  __builtin_amdgcn_global_load_lds(
      (const __attribute__((address_space(1))) unsigned int*)g,
      (__attribute__((address_space(3))) unsigned int*)lds_wavebase, 16, 0, 0);
  (void)lds_lane;
#else
  *(u16x8*)lds_lane = *(const u16x8*)g;
#endif
}

// ---------------- CSR build ----------------
__global__ void k_deg(const int* __restrict__ eidx, const float* __restrict__ ew,
                      int* __restrict__ deg, float* __restrict__ wsum){
  int i = blockIdx.x*256 + threadIdx.x;
  if(i >= NE) return;
  int d = eidx[NE + i];
  atomicAdd(&deg[d], 1);
  atomicAdd(&wsum[d], ew[i]);
}

__global__ __launch_bounds__(1024) void k_scan(const int* __restrict__ deg,
                      float* __restrict__ wsum, int* __restrict__ off){
  __shared__ int part[1024];
  int tid = threadIdx.x;
  int n0 = tid*10;
  int s = 0;
  for(int i=0;i<10;++i){ int n=n0+i; if(n<N_NODES) s += deg[n]+1; }
  part[tid] = s;
  for(int i=0;i<10;++i){
    int n=n0+i;
    if(n<N_NODES){ int d=deg[n]; wsum[n] = wsum[n] / (float)(d>1?d:1); }
  }
  __syncthreads();
  for(int st=1; st<1024; st<<=1){
    int v = (tid>=st) ? part[tid-st] : 0;
    __syncthreads();
    part[tid] += v;
    __syncthreads();
  }
  int base = tid ? part[tid-1] : 0;
  for(int i=0;i<10;++i){ int n=n0+i; if(n<N_NODES){ off[n]=base; base += deg[n]+1; } }
  if(tid==999) off[N_NODES] = base;
}

__global__ void k_scatter(const int* __restrict__ eidx, const float* __restrict__ ew,
                          const float* __restrict__ la, const int* __restrict__ off,
                          int* __restrict__ fill, int* __restrict__ csrs, float* __restrict__ csrw){
  int i = blockIdx.x*256 + threadIdx.x;
  if(i >= NE_TOT) return;
  int s, d; float w;
  if(i < NE){ s = eidx[i]; d = eidx[NE+i]; w = ew[i]; }
  else      { int n = i-NE; s=n; d=n; w = la[n]; }   // self-loop, weight = mean incoming
  int pos = off[d] + atomicAdd(&fill[d], 1);
  csrs[pos] = s; csrw[pos] = w;
}

// ---------------- Whh f32 -> bf16 preconvert (once per call) ----------------
__global__ void k_cvtw(const float* __restrict__ W, u16* __restrict__ Wb, int n){
  int i = blockIdx.x*256 + threadIdx.x;
  if(i < n) Wb[i] = f2bf(W[i]);
}

// ---------------- MFMA GEMM: C = A @ W^T + bias ----------------
template<int AMODE, bool OUTF32>
__global__ __launch_bounds__(256) void k_gemm(
    const void* __restrict__ Av, const float* __restrict__ W, const float* __restrict__ bias,
    void* __restrict__ out,
    int M, int N, int K,
    const int* __restrict__ gidx, const int* __restrict__ ridx, const float* __restrict__ remb,
    int t0, int chk,
    const int* __restrict__ lens)
{
  int tid = threadIdx.x;
  int wid = tid >> 6, l = tid & 63;
  int lr = l & 15, lg = l >> 4;
  int bm = blockIdx.x*128 + wid*32;
  int bn = blockIdx.y*64;
  f32x4 acc[2][4] = {};
  int nk = K >> 5;
  for(int kt=0; kt<nk; ++kt){
    int k0 = kt*32 + lg*8;
    bf16x8 af[2];
    #pragma unroll
    for(int mi=0; mi<2; ++mi){
      int row = bm + mi*16 + lr;
      u16x8 v = {0,0,0,0,0,0,0,0};
      if(row < M){
        if constexpr(AMODE == 1){
          int b = row / chk, tt = row - b*chk;
          int gi = b*NTT + t0 + tt;
          const float* ar = (const float*)Av + (size_t)gidx[gi]*K + k0;
          const float* rr = remb + (size_t)ridx[gi]*K + k0;
          #pragma unroll
          for(int e=0;e<8;++e) v[e] = f2bf(ar[e] + rr[e]);
        } else if constexpr(AMODE == 0){
          const float* ar = (const float*)Av + (size_t)row*K + k0;
          #pragma unroll
          for(int e=0;e<8;++e) v[e] = f2bf(ar[e]);
        } else {
          v = *(const u16x8*)((const u16*)Av + (size_t)row*K + k0);
        }
      }
      af[mi] = __builtin_bit_cast(bf16x8, v);
    }
    #pragma unroll
    for(int nt=0; nt<4; ++nt){
      int col = bn + nt*16 + lr;
      const float* wr = W + (size_t)col*K + k0;
      u16x8 wv;
      #pragma unroll
      for(int e=0;e<8;++e) wv[e] = f2bf(wr[e]);
      bf16x8 bfr = __builtin_bit_cast(bf16x8, wv);
      acc[0][nt] = __builtin_amdgcn_mfma_f32_16x16x32_bf16(af[0], bfr, acc[0][nt], 0,0,0);
      acc[1][nt] = __builtin_amdgcn_mfma_f32_16x16x32_bf16(af[1], bfr, acc[1][nt], 0,0,0);
    }
  }
  #pragma unroll
  for(int mi=0; mi<2; ++mi){
    #pragma unroll
    for(int nt=0; nt<4; ++nt){
      int col = bn + nt*16 + lr;
      float bc = bias[col];
      #pragma unroll
      for(int r=0; r<4; ++r){
        int row = bm + mi*16 + lg*4 + r;
        if(row >= M) continue;
        float v = acc[mi][nt][r] + bc;
        if(lens){ int b = row/NTT; int t = row - b*NTT; if(t >= lens[b]) v = bc; }
        if constexpr(OUTF32) ((float*)out)[(size_t)row*N + col] = v;
        else                 ((u16*) out)[(size_t)row*N + col] = f2bf(v);
      }
    }
  }
}

// ---------------- GATv2 attention + aggregate + bias + ELU ----------------
__global__ __launch_bounds__(256) void k_attn(
    const int* __restrict__ off, const int* __restrict__ csrs, const float* __restrict__ csrw,
    const u16* __restrict__ xl, const u16* __restrict__ xr,
    const float* __restrict__ We, const float* __restrict__ att, const float* __restrict__ bias,
    float* __restrict__ hout)
{
  int wid = threadIdx.x >> 6, l = threadIdx.x & 63;
  int n = blockIdx.x*4 + wid;
  int d0 = 2*l;
  const unsigned int* xl2 = (const unsigned int*)xl;
  unsigned int xru = ((const unsigned int*)xr)[n*64 + l];
  float xrx = bf2f((u16)xru), xry = bf2f((u16)(xru>>16));
  float wex = We[d0],  wey = We[d0+1];
  float atx = att[d0], aty = att[d0+1];
  int p0 = off[n], p1 = off[n+1];
  float mx = -1e30f;
  for(int p=p0; p<p1; ++p){
    int s = csrs[p]; float w = csrw[p];
    unsigned int u = xl2[s*64 + l];
    float ax = bf2f((u16)u)       + xrx + w*wex;
    float ay = bf2f((u16)(u>>16)) + xry + w*wey;
    ax = ax > 0.f ? ax : 0.2f*ax;
    ay = ay > 0.f ? ay : 0.2f*ay;
    float c = ax*atx + ay*aty;
    c += __shfl_xor(c,1); c += __shfl_xor(c,2); c += __shfl_xor(c,4); c += __shfl_xor(c,8);
    mx = fmaxf(mx, c);
  }
  float den = 0.f, a0 = 0.f, a1 = 0.f;
  for(int p=p0; p<p1; ++p){
    int s = csrs[p]; float w = csrw[p];
    unsigned int u = xl2[s*64 + l];
    float xlx = bf2f((u16)u), xly = bf2f((u16)(u>>16));
    float ax = xlx + xrx + w*wex;
    float ay = xly + xry + w*wey;
    ax = ax > 0.f ? ax : 0.2f*ax;
    ay = ay > 0.f ? ay : 0.2f*ay;
    float c = ax*atx + ay*aty;
    c += __shfl_xor(c,1); c += __shfl_xor(c,2); c += __shfl_xor(c,4); c += __shfl_xor(c,8);
    float al = __expf(c - mx);
    den += al; a0 += al*xlx; a1 += al*xly;
  }
  float inv = 1.f/(den + 1e-16f);
  float o0 = a0*inv + bias[d0];
  float o1 = a1*inv + bias[d0+1];
  o0 = o0 > 0.f ? o0 : (__expf(o0) - 1.f);   // ELU
  o1 = o1 > 0.f ? o1 : (__expf(o1) - 1.f);
  hout[n*EMB + d0]   = o0;
  hout[n*EMB + d0+1] = o1;
}

// ---------------- GRU chunk: 16 blocks x 16 batch rows, 4 waves (1/SIMD) ----------------
// ONE barrier per step: h double-buffered AND xg double-buffered; stage(t+1) issued at
// step top; before the single barrier wait lgkmcnt(0) + vmcnt(16) — exactly the 16
// in-flight hseq stores may fly (vmcnt retires in issue order; the 6 stage loads are
// oldest). Whh in 96 AGPR-pinned fragments (R9, proven resident & no remat).

#define DECLW(nt) f32x4 wf_##nt##_0, wf_##nt##_1, wf_##nt##_2, wf_##nt##_3, \
                        wf_##nt##_4, wf_##nt##_5, wf_##nt##_6, wf_##nt##_7; float bh_##nt;

#define LDW1(nt,kt) { u16x8 wv = *(const u16x8*)(wr + (kt)*32 + lg*8); \
  wf_##nt##_##kt = __builtin_bit_cast(f32x4, wv); \
  asm volatile("" : "+a"(wf_##nt##_##kt)); }

#define LDW(nt) { int nrow = ((nt)>>2)*256 + wid*64 + ((nt)&3)*16 + lr; \
  bh_##nt = bhh[nrow]; const u16* wr = whb + (size_t)nrow*RH; \
  LDW1(nt,0) LDW1(nt,1) LDW1(nt,2) LDW1(nt,3) LDW1(nt,4) LDW1(nt,5) LDW1(nt,6) LDW1(nt,7) }

#define MFMA1(acc, af, wf) asm volatile( \
  "v_mfma_f32_16x16x32_bf16 %0, %1, %2, %0" : "+v"(acc) : "v"(af), "a"(wf));

#define MST(kt) { int kg = ((kt)*4 + lg) ^ lr; \
  f32x4 af = __builtin_bit_cast(f32x4, *(const u16x8*)(hrd + lr*RH + kg*8)); \
  MFMA1(acc0,  af, wf_0_##kt)  MFMA1(acc1,  af, wf_1_##kt) \
  MFMA1(acc2,  af, wf_2_##kt)  MFMA1(acc3,  af, wf_3_##kt) \
  MFMA1(acc4,  af, wf_4_##kt)  MFMA1(acc5,  af, wf_5_##kt) \
  MFMA1(acc6,  af, wf_6_##kt)  MFMA1(acc7,  af, wf_7_##kt) \
  MFMA1(acc8,  af, wf_8_##kt)  MFMA1(acc9,  af, wf_9_##kt) \
  MFMA1(acc10, af, wf_10_##kt) MFMA1(acc11, af, wf_11_##kt) }

// gates for one jt: reads xgr (LDS), accs (regs); writes hwr (LDS) + hseq (global)
#define GATES(jt, aR, aZ, aN, bR, bZ, bN, OP) { \
  int jl = wid*64 + (jt)*16 + lr; int jgr = jl>>3, jo = jl&7; \
  _Pragma("unroll") for(int r=0;r<4;++r){ \
    int row = lg*4 + r; \
    const u16* xrow = xgr + row*G3; \
    float xrv = bf2f(xrow[((jgr     )^row)*8 + jo]); \
    float xzv = bf2f(xrow[((jgr + 32)^row)*8 + jo]); \
    float xnv = bf2f(xrow[((jgr + 64)^row)*8 + jo]); \
    float hr = aR[r] + bR; float hz = aZ[r] + bZ; float hn = aN[r] + bN; \
    float rg = 1.f/(1.f + __expf(-(xrv + hr))); \
    float zg = 1.f/(1.f + __expf(-(xzv + hz))); \
    float nn = xnv + rg*hn; \
    float tg = 1.f - 2.f/(__expf(2.f*nn) + 1.f); \
    float hv = (1.f - zg)*tg + zg*hst[(jt)*4+r]; \
    int live = (t < lenr[r]); \
    float hk = live ? hv : hst[(jt)*4+r];       /* freeze past len (ref-exact) */ \
    hst[(jt)*4+r] = hk; \
    hwr[row*RH + (jgr^row)*8 + jo] = f2bf(hk); \
    OP[r][(jt)*16] = live ? f2bf(hv) : (u16)0;  /* pad_packed zero */ \
  } }

__global__ __launch_bounds__(256,1) __attribute__((amdgpu_waves_per_eu(1,1))) void k_gru(
    const u16* __restrict__ xgc, const u16* __restrict__ whb, const float* __restrict__ bhh,
    const int* __restrict__ lens, u16* __restrict__ hseq, float* __restrict__ hsave,
    int t0, int t1, int chk)
{
  int tid = threadIdx.x;
  int wid = tid >> 6, l = tid & 63;
  int lr = l & 15, lg = l >> 4;
  int b0 = blockIdx.x*16;
  __shared__ u16 lds_h[2][16*RH];    // 16 KB (double-buffered h)
  __shared__ u16 lds_xg[2][16*G3];   // 48 KB (double-buffered xg)

  int maxlen = 0;
  for(int i=0;i<16;++i){ int v = lens[b0+i]; maxlen = v>maxlen ? v : maxlen; }
  int tend = maxlen < t1 ? maxlen : t1;
  int nsteps = tend - t0; if(nsteps < 0) nsteps = 0;

  // Whh bf16 B-fragments: 96 AGPR-pinned values (proven resident, R9)
  DECLW(0) DECLW(1) DECLW(2)  DECLW(3)  DECLW(4)  DECLW(5)
  DECLW(6) DECLW(7) DECLW(8)  DECLW(9)  DECLW(10) DECLW(11)
  LDW(0) LDW(1) LDW(2)  LDW(3)  LDW(4)  LDW(5)
  LDW(6) LDW(7) LDW(8)  LDW(9)  LDW(10) LDW(11)

  // h init into lds_h[0] (swizzled: granule c of row holds logical granule c^row)
  #pragma unroll
  for(int it=0; it<2; ++it){
    int c = it*256 + tid;
    int row = c>>5, cl = c&31, cg = cl^row;
    u16x8 v = {0,0,0,0,0,0,0,0};
    if(t0 > 0){
      const float* hp = hsave + (size_t)(b0+row)*RH + cg*8;
      #pragma unroll
      for(int e=0;e<8;++e) v[e] = f2bf(hp[e]);
    }
    *(u16x8*)(&lds_h[0][0] + c*8) = v;
  }
  float hst[16];
  int lenr[4];
  u16* op[4];
  #pragma unroll
  for(int r=0;r<4;++r){
    int row = lg*4 + r;
    lenr[r] = lens[b0 + row];
    op[r] = hseq + ((size_t)((b0+row)*NTT + t0))*RH + wid*64 + lr;
    #pragma unroll
    for(int jt=0;jt<4;++jt){
      int j = wid*64 + jt*16 + lr;
      hst[jt*4+r] = (t0>0) ? hsave[(size_t)(b0+row)*RH + j] : 0.f;
    }
  }

  // staging addresses (pre-swizzled global source, linear LDS dest within buffer)
  const u16* xsrc[6]; int lboff[6]; int lloff[6];
  #pragma unroll
  for(int it=0; it<6; ++it){
    int ppos = it*256 + tid;                 // 1536 granules = 16 rows x 96
    int row = ppos/96;
    int cg  = (ppos - row*96) ^ row;
    xsrc[it]  = xgc + ((size_t)((b0+row)*chk))*G3 + cg*8;
    lboff[it] = (it*256 + wid*64)*8;
    lloff[it] = ppos*8;
  }

  // prologue: stage t0 into xg buf0, full drain, publish
  if(nsteps > 0){
    #pragma unroll
    for(int it=0; it<6; ++it){
      stage16(xsrc[it], &lds_xg[0][0] + lboff[it], &lds_xg[0][0] + lloff[it]);
      xsrc[it] += G3;
    }
  }
  asm volatile("s_waitcnt vmcnt(0)" ::: "memory");
  asm volatile("s_waitcnt lgkmcnt(0)" ::: "memory");
  __builtin_amdgcn_sched_barrier(0);
  __builtin_amdgcn_s_barrier();
  __builtin_amdgcn_sched_barrier(0);

  for(int s=0; s<nsteps; ++s){
    int t = t0 + s;
    const u16* hrd = &lds_h[s&1][0];
    u16*       hwr = &lds_h[(s+1)&1][0];
    const u16* xgr = &lds_xg[s&1][0];
    int more = (s+1 < nsteps);

    // issue next-step stage early (lands during this step's compute)
    if(more){
      u16* bufn = &lds_xg[(s+1)&1][0];
      #pragma unroll
      for(int it=0; it<6; ++it){
        stage16(xsrc[it], bufn + lboff[it], bufn + lloff[it]);
        xsrc[it] += G3;
      }
    }

    // hg = h @ Whh^T  (A from lds_h[cur]; B from AGPRs)
    f32x4 acc0 = {}, acc1 = {}, acc2 = {}, acc3 = {}, acc4 = {}, acc5 = {},
          acc6 = {}, acc7 = {}, acc8 = {}, acc9 = {}, acc10 = {}, acc11 = {};
    MST(0) MST(1) MST(2) MST(3) MST(4) MST(5) MST(6) MST(7)

    // gates read xg[cur] (published at previous barrier) — no intra-step barrier
    GATES(0, acc0, acc4, acc8,  bh_0, bh_4, bh_8,  op)
    GATES(1, acc1, acc5, acc9,  bh_1, bh_5, bh_9,  op)
    GATES(2, acc2, acc6, acc10, bh_2, bh_6, bh_10, op)
    GATES(3, acc3, acc7, acc11, bh_3, bh_7, bh_11, op)
    #pragma unroll
    for(int r=0;r<4;++r) op[r] += RH;

    if(more){
      asm volatile("s_waitcnt lgkmcnt(0)" ::: "memory");   // h[nxt] writes + xg reads done
      asm volatile("s_waitcnt vmcnt(16)" ::: "memory");    // 6 stage loads landed; stores fly
      __builtin_amdgcn_sched_barrier(0);
      __builtin_amdgcn_s_barrier();                        // publish h[nxt] + xg[nxt]
      __builtin_amdgcn_sched_barrier(0);
    }
  }

  // zero-fill [max(tend,t0), t1) so hseq is fully written & deterministic
  for(int t = (tend > t0 ? tend : t0); t < t1; ++t){
    #pragma unroll
    for(int r=0;r<4;++r){
      #pragma unroll
      for(int jt=0;jt<4;++jt) op[r][jt*16] = 0;
      op[r] += RH;
    }
  }

  // save exact f32 state for next chunk (frozen at len, ref-exact)
  #pragma unroll
  for(int jt=0;jt<4;++jt)
    #pragma unroll
    for(int r=0;r<4;++r){
      int j = wid*64 + jt*16 + lr, row = lg*4 + r;
      hsave[(size_t)(b0+row)*RH + j] = hst[jt*4+r];
    }
}

// ---------------- launcher ----------------
extern "C" void kernel_launch(void* const* d_in, const int* in_sizes, int n_in,
                              void* d_out, int out_size, void* d_ws, size_t ws_size,
                              hipStream_t stream){
  (void)in_sizes; (void)n_in; (void)out_size;
  const int*   skills = (const int*)d_in[0];
  const int*   resp   = (const int*)d_in[1];
  const int*   lens   = (const int*)d_in[2];
  const int*   eidx   = (const int*)d_in[3];
  const float* ew     = (const float*)d_in[4];
  const float* emb    = (const float*)d_in[5];
  const float* gW[2][7];
  for(int l2=0;l2<2;++l2) for(int j=0;j<7;++j) gW[l2][j] = (const float*)d_in[6 + l2*7 + j];
  const float* remb  = (const float*)d_in[20];
  const float* Wih   = (const float*)d_in[21];
  const float* Whh   = (const float*)d_in[22];
  const float* bih   = (const float*)d_in[23];
  const float* bhh   = (const float*)d_in[24];
  const float* projW = (const float*)d_in[25];
  const float* projb = (const float*)d_in[26];

  char* p = (char*)d_ws;
  size_t o = 0;
  auto take = [&](size_t bytes)->char*{ char* r = p + o; o = (o + bytes + 255) & ~(size_t)255; return r; };
  int*   deg  = (int*)  take(4*N_NODES);
  int*   fill = (int*)  take(4*N_NODES);
  float* wsum = (float*)take(4*N_NODES);
  size_t zbytes = o;                        // deg+fill+wsum zeroed each call
  int*   off   = (int*)  take(4*(N_NODES+1));
  int*   csrs  = (int*)  take(4*NE_TOT);
  float* csrw  = (float*)take(4*NE_TOT);
  u16*   xl    = (u16*)  take(2UL*N_NODES*EMB);
  u16*   xr    = (u16*)  take(2UL*N_NODES*EMB);
  float* h1    = (float*)take(4UL*N_NODES*EMB);
  float* hsave = (float*)take(4UL*NB*RH);
  u16*   whb   = (u16*)  take(2UL*G3*RH);
  u16*   hseq  = (u16*)  take(2UL*NB*NTT*RH);
  size_t fixed_end = o;
  // xg chunk length: largest of {200,100,50,25} that fits ws_size
  int chk = 200;
  while(chk > 25 && fixed_end + 2UL*NB*(size_t)chk*G3 > ws_size) chk /= 2;
  u16*   xgc  = (u16*)  take(2UL*NB*(size_t)chk*G3);

  float* outP = (float*)d_out;                     // h_proj [256,200,128] f32
  float* outE = outP + (size_t)NB*NTT*EMB;         // skill_embs [10000,128] f32

  hipMemsetAsync(d_ws, 0, zbytes, stream);
  k_deg<<<(NE+255)/256, 256, 0, stream>>>(eidx, ew, deg, wsum);
  k_scan<<<1, 1024, 0, stream>>>(deg, wsum, off);
  k_scatter<<<(NE_TOT+255)/256, 256, 0, stream>>>(eidx, ew, wsum, off, fill, csrs, csrw);
  k_cvtw<<<(G3*RH+255)/256, 256, 0, stream>>>(Whh, whb, G3*RH);

  dim3 gN((N_NODES+127)/128, EMB/64);
  // layer 0 (A = emb f32 -> xl/xr bf16)
  k_gemm<0,false><<<gN, 256, 0, stream>>>(emb, gW[0][0], gW[0][1], xl, N_NODES, EMB, EMB,
                                 nullptr, nullptr, nullptr, 0,0, nullptr);
  k_gemm<0,false><<<gN, 256, 0, stream>>>(emb, gW[0][2], gW[0][3], xr, N_NODES, EMB, EMB,
                                 nullptr, nullptr, nullptr, 0,0, nullptr);
  k_attn<<<N_NODES/4, 256, 0, stream>>>(off, csrs, csrw, xl, xr, gW[0][4], gW[0][5], gW[0][6], h1);
  // layer 1 (A = h1 f32)
  k_gemm<0,false><<<gN, 256, 0, stream>>>(h1, gW[1][0], gW[1][1], xl, N_NODES, EMB, EMB,
                                 nullptr, nullptr, nullptr, 0,0, nullptr);
  k_gemm<0,false><<<gN, 256, 0, stream>>>(h1, gW[1][2], gW[1][3], xr, N_NODES, EMB, EMB,
                                 nullptr, nullptr, nullptr, 0,0, nullptr);
  k_attn<<<N_NODES/4, 256, 0, stream>>>(off, csrs, csrw, xl, xr, gW[1][4], gW[1][5], gW[1][6], outE);

  // chunked: xg = (skill_embs[skills]+resp_emb[resp]) @ Wih^T + bih, then GRU chunk
  for(int t0=0; t0<NTT; t0+=chk){
    k_gemm<1,false><<<dim3(NB*chk/128, G3/64), 256, 0, stream>>>(outE, Wih, bih, xgc,
                                 NB*chk, G3, EMB, skills, resp, remb, t0, chk, nullptr);
    k_gru<<<16, 256, 0, stream>>>(xgc, whb, bhh, lens, hseq, hsave, t0, t0+chk, chk);
  }
  // proj: A = hseq bf16, out f32 (+ lens mask; hseq rows t>=len are exact zeros)
  k_gemm<2,true><<<dim3(NB*NTT/128, EMB/64), 256, 0, stream>>>(hseq, projW, projb, outP,
                                 NB*NTT, EMB, RH,
                                 nullptr, nullptr, nullptr, 0,0, lens);
}

// Round 14
// 868.196 us; speedup vs baseline: 2.1287x; 2.1287x over previous
//
#include <hip/hip_runtime.h>

#define N_NODES 10000
#define EMB     128
#define NE      320000
#define NE_TOT  330000   // + one self-loop per node
#define NB      256
#define NTT     200
#define RH      256
#define G3      768

typedef unsigned short u16;
typedef u16    u16x8  __attribute__((ext_vector_type(8)));
typedef __bf16 bf16x8 __attribute__((ext_vector_type(8)));
typedef float  f32x4  __attribute__((ext_vector_type(4)));

static __device__ __forceinline__ float bf2f(u16 u){
  unsigned int x = ((unsigned int)u) << 16;
  return __builtin_bit_cast(float, x);
}
static __device__ __forceinline__ u16 f2bf(float f){
  unsigned int x = __builtin_bit_cast(unsigned int, f);
  x += 0x7fffu + ((x >> 16) & 1u);
  return (u16)(x >> 16);
}

// async global->LDS, 16B per lane; lds dest must be the WAVE base (HW adds lane*16)
static __device__ __forceinline__ void stage16(const u16* g, u16* lds_wavebase, u16* lds_lane){
#if __has_builtin(__builtin_amdgcn_global_load_lds)
  __builtin_amdgcn_global_load_lds(
      (const __attribute__((address_space(1))) unsigned int*)g,
      (__attribute__((address_space(3))) unsigned int*)lds_wavebase, 16, 0, 0);
  (void)lds_lane;
#else
  *(u16x8*)lds_lane = *(const u16x8*)g;
#endif
}

// ---------------- CSR build ----------------
__global__ void k_deg(const int* __restrict__ eidx, const float* __restrict__ ew,
                      int* __restrict__ deg, float* __restrict__ wsum){
  int i = blockIdx.x*256 + threadIdx.x;
  if(i >= NE) return;
  int d = eidx[NE + i];
  atomicAdd(&deg[d], 1);
  atomicAdd(&wsum[d], ew[i]);
}

__global__ __launch_bounds__(1024) void k_scan(const int* __restrict__ deg,
                      float* __restrict__ wsum, int* __restrict__ off){
  __shared__ int part[1024];
  int tid = threadIdx.x;
  int n0 = tid*10;
  int s = 0;
  for(int i=0;i<10;++i){ int n=n0+i; if(n<N_NODES) s += deg[n]+1; }
  part[tid] = s;
  for(int i=0;i<10;++i){
    int n=n0+i;
    if(n<N_NODES){ int d=deg[n]; wsum[n] = wsum[n] / (float)(d>1?d:1); }
  }
  __syncthreads();
  for(int st=1; st<1024; st<<=1){
    int v = (tid>=st) ? part[tid-st] : 0;
    __syncthreads();
    part[tid] += v;
    __syncthreads();
  }
  int base = tid ? part[tid-1] : 0;
  for(int i=0;i<10;++i){ int n=n0+i; if(n<N_NODES){ off[n]=base; base += deg[n]+1; } }
  if(tid==999) off[N_NODES] = base;
}

__global__ void k_scatter(const int* __restrict__ eidx, const float* __restrict__ ew,
                          const float* __restrict__ la, const int* __restrict__ off,
                          int* __restrict__ fill, int* __restrict__ csrs, float* __restrict__ csrw){
  int i = blockIdx.x*256 + threadIdx.x;
  if(i >= NE_TOT) return;
  int s, d; float w;
  if(i < NE){ s = eidx[i]; d = eidx[NE+i]; w = ew[i]; }
  else      { int n = i-NE; s=n; d=n; w = la[n]; }   // self-loop, weight = mean incoming
  int pos = off[d] + atomicAdd(&fill[d], 1);
  csrs[pos] = s; csrw[pos] = w;
}

// ---------------- Whh f32 -> bf16 preconvert (once per call) ----------------
__global__ void k_cvtw(const float* __restrict__ W, u16* __restrict__ Wb, int n){
  int i = blockIdx.x*256 + threadIdx.x;
  if(i < n) Wb[i] = f2bf(W[i]);
}

// ---------------- MFMA GEMM: C = A @ W^T + bias ----------------
template<int AMODE, bool OUTF32>
__global__ __launch_bounds__(256) void k_gemm(
    const void* __restrict__ Av, const float* __restrict__ W, const float* __restrict__ bias,
    void* __restrict__ out,
    int M, int N, int K,
    const int* __restrict__ gidx, const int* __restrict__ ridx, const float* __restrict__ remb,
    int t0, int chk,
    const int* __restrict__ lens)
{
  int tid = threadIdx.x;
  int wid = tid >> 6, l = tid & 63;
  int lr = l & 15, lg = l >> 4;
  int bm = blockIdx.x*128 + wid*32;
  int bn = blockIdx.y*64;
  f32x4 acc[2][4] = {};
  int nk = K >> 5;
  for(int kt=0; kt<nk; ++kt){
    int k0 = kt*32 + lg*8;
    bf16x8 af[2];
    #pragma unroll
    for(int mi=0; mi<2; ++mi){
      int row = bm + mi*16 + lr;
      u16x8 v = {0,0,0,0,0,0,0,0};
      if(row < M){
        if constexpr(AMODE == 1){
          int b = row / chk, tt = row - b*chk;
          int gi = b*NTT + t0 + tt;
          const float* ar = (const float*)Av + (size_t)gidx[gi]*K + k0;
          const float* rr = remb + (size_t)ridx[gi]*K + k0;
          #pragma unroll
          for(int e=0;e<8;++e) v[e] = f2bf(ar[e] + rr[e]);
        } else if constexpr(AMODE == 0){
          const float* ar = (const float*)Av + (size_t)row*K + k0;
          #pragma unroll
          for(int e=0;e<8;++e) v[e] = f2bf(ar[e]);
        } else {
          v = *(const u16x8*)((const u16*)Av + (size_t)row*K + k0);
        }
      }
      af[mi] = __builtin_bit_cast(bf16x8, v);
    }
    #pragma unroll
    for(int nt=0; nt<4; ++nt){
      int col = bn + nt*16 + lr;
      const float* wr = W + (size_t)col*K + k0;
      u16x8 wv;
      #pragma unroll
      for(int e=0;e<8;++e) wv[e] = f2bf(wr[e]);
      bf16x8 bfr = __builtin_bit_cast(bf16x8, wv);
      acc[0][nt] = __builtin_amdgcn_mfma_f32_16x16x32_bf16(af[0], bfr, acc[0][nt], 0,0,0);
      acc[1][nt] = __builtin_amdgcn_mfma_f32_16x16x32_bf16(af[1], bfr, acc[1][nt], 0,0,0);
    }
  }
  #pragma unroll
  for(int mi=0; mi<2; ++mi){
    #pragma unroll
    for(int nt=0; nt<4; ++nt){
      int col = bn + nt*16 + lr;
      float bc = bias[col];
      #pragma unroll
      for(int r=0; r<4; ++r){
        int row = bm + mi*16 + lg*4 + r;
        if(row >= M) continue;
        float v = acc[mi][nt][r] + bc;
        if(lens){ int b = row/NTT; int t = row - b*NTT; if(t >= lens[b]) v = bc; }
        if constexpr(OUTF32) ((float*)out)[(size_t)row*N + col] = v;
        else                 ((u16*) out)[(size_t)row*N + col] = f2bf(v);
      }
    }
  }
}

// ---------------- GATv2 attention + aggregate + bias + ELU ----------------
__global__ __launch_bounds__(256) void k_attn(
    const int* __restrict__ off, const int* __restrict__ csrs, const float* __restrict__ csrw,
    const u16* __restrict__ xl, const u16* __restrict__ xr,
    const float* __restrict__ We, const float* __restrict__ att, const float* __restrict__ bias,
    float* __restrict__ hout)
{
  int wid = threadIdx.x >> 6, l = threadIdx.x & 63;
  int n = blockIdx.x*4 + wid;
  int d0 = 2*l;
  const unsigned int* xl2 = (const unsigned int*)xl;
  unsigned int xru = ((const unsigned int*)xr)[n*64 + l];
  float xrx = bf2f((u16)xru), xry = bf2f((u16)(xru>>16));
  float wex = We[d0],  wey = We[d0+1];
  float atx = att[d0], aty = att[d0+1];
  int p0 = off[n], p1 = off[n+1];
  float mx = -1e30f;
  for(int p=p0; p<p1; ++p){
    int s = csrs[p]; float w = csrw[p];
    unsigned int u = xl2[s*64 + l];
    float ax = bf2f((u16)u)       + xrx + w*wex;
    float ay = bf2f((u16)(u>>16)) + xry + w*wey;
    ax = ax > 0.f ? ax : 0.2f*ax;
    ay = ay > 0.f ? ay : 0.2f*ay;
    float c = ax*atx + ay*aty;
    c += __shfl_xor(c,1); c += __shfl_xor(c,2); c += __shfl_xor(c,4); c += __shfl_xor(c,8);
    mx = fmaxf(mx, c);
  }
  float den = 0.f, a0 = 0.f, a1 = 0.f;
  for(int p=p0; p<p1; ++p){
    int s = csrs[p]; float w = csrw[p];
    unsigned int u = xl2[s*64 + l];
    float xlx = bf2f((u16)u), xly = bf2f((u16)(u>>16));
    float ax = xlx + xrx + w*wex;
    float ay = xly + xry + w*wey;
    ax = ax > 0.f ? ax : 0.2f*ax;
    ay = ay > 0.f ? ay : 0.2f*ay;
    float c = ax*atx + ay*aty;
    c += __shfl_xor(c,1); c += __shfl_xor(c,2); c += __shfl_xor(c,4); c += __shfl_xor(c,8);
    float al = __expf(c - mx);
    den += al; a0 += al*xlx; a1 += al*xly;
  }
  float inv = 1.f/(den + 1e-16f);
  float o0 = a0*inv + bias[d0];
  float o1 = a1*inv + bias[d0+1];
  o0 = o0 > 0.f ? o0 : (__expf(o0) - 1.f);   // ELU
  o1 = o1 > 0.f ? o1 : (__expf(o1) - 1.f);
  hout[n*EMB + d0]   = o0;
  hout[n*EMB + d0+1] = o1;
}

// ---------------- GRU chunk: 256 blocks x 1 batch row, 4 waves (1/SIMD) ----------------
// ALL 256 CUs busy. Per block: h[1,256] @ Whh^T (M=16 tile, rows 1-15 masked to zero
// via lr==0 on the A-fragment; broadcast LDS read). Gates: 4 h-elems per lane (lanes
// 0-15). Whh in 96 AGPR-pinned fragments. Single barrier/step, counted vmcnt(4)
// (queue = [stage-load, 4 stores]; counter retires in issue order).

#define DECLW(nt) f32x4 wf_##nt##_0, wf_##nt##_1, wf_##nt##_2, wf_##nt##_3, \
                        wf_##nt##_4, wf_##nt##_5, wf_##nt##_6, wf_##nt##_7; float bh_##nt;

#define LDW1(nt,kt) { u16x8 wv = *(const u16x8*)(wr + (kt)*32 + lg*8); \
  wf_##nt##_##kt = __builtin_bit_cast(f32x4, wv); \
  asm volatile("" : "+a"(wf_##nt##_##kt)); }

#define LDW(nt) { int nrow = ((nt)>>2)*256 + wid*64 + ((nt)&3)*16 + lr; \
  bh_##nt = bhh[nrow]; const u16* wr = whb + (size_t)nrow*RH; \
  LDW1(nt,0) LDW1(nt,1) LDW1(nt,2) LDW1(nt,3) LDW1(nt,4) LDW1(nt,5) LDW1(nt,6) LDW1(nt,7) }

#define MFMA1(acc, af, wf) asm volatile( \
  "v_mfma_f32_16x16x32_bf16 %0, %1, %2, %0" : "+v"(acc) : "v"(af), "a"(wf));

#define MST(kt) { \
  f32x4 hv4 = __builtin_bit_cast(f32x4, *(const u16x8*)(hrd + (kt)*32 + lg*8)); \
  f32x4 af; \
  af[0] = lr==0 ? hv4[0] : 0.f; af[1] = lr==0 ? hv4[1] : 0.f; \
  af[2] = lr==0 ? hv4[2] : 0.f; af[3] = lr==0 ? hv4[3] : 0.f; \
  MFMA1(acc0,  af, wf_0_##kt)  MFMA1(acc1,  af, wf_1_##kt) \
  MFMA1(acc2,  af, wf_2_##kt)  MFMA1(acc3,  af, wf_3_##kt) \
  MFMA1(acc4,  af, wf_4_##kt)  MFMA1(acc5,  af, wf_5_##kt) \
  MFMA1(acc6,  af, wf_6_##kt)  MFMA1(acc7,  af, wf_7_##kt) \
  MFMA1(acc8,  af, wf_8_##kt)  MFMA1(acc9,  af, wf_9_##kt) \
  MFMA1(acc10, af, wf_10_##kt) MFMA1(acc11, af, wf_11_##kt) }

// gates for one jt (lanes 0-15 active): t < len guaranteed inside the loop
#define GATE1(jt, aR, aZ, aN, bR, bZ, bN) { \
  int j = wid*64 + (jt)*16 + l; \
  float xrv = bf2f(xgr[j]); \
  float xzv = bf2f(xgr[256 + j]); \
  float xnv = bf2f(xgr[512 + j]); \
  float hr = aR[0] + bR; float hz = aZ[0] + bZ; float hn = aN[0] + bN; \
  float rg = 1.f/(1.f + __expf(-(xrv + hr))); \
  float zg = 1.f/(1.f + __expf(-(xzv + hz))); \
  float nn = xnv + rg*hn; \
  float tg = 1.f - 2.f/(__expf(2.f*nn) + 1.f); \
  float hv = (1.f - zg)*tg + zg*hst[jt]; \
  hst[jt] = hv; \
  u16 hb = f2bf(hv); \
  hwr[j] = hb; \
  outp[j] = hb; \
}

__global__ __launch_bounds__(256,1) __attribute__((amdgpu_waves_per_eu(1,1))) void k_gru(
    const u16* __restrict__ xgc, const u16* __restrict__ whb, const float* __restrict__ bhh,
    const int* __restrict__ lens, u16* __restrict__ hseq, float* __restrict__ hsave,
    int t0, int t1, int chk)
{
  int tid = threadIdx.x;
  int wid = tid >> 6, l = tid & 63;
  int lr = l & 15, lg = l >> 4;
  int b = blockIdx.x;                       // one batch row per block
  __shared__ __align__(16) u16 lds_h[2][256];    // 1 KB, double-buffered
  __shared__ __align__(16) u16 lds_xg[2][1024];  // 4 KB (768 used + 512B pad)

  int mylen = lens[b];
  int tend = mylen < t1 ? mylen : t1;
  int nsteps = tend - t0; if(nsteps < 0) nsteps = 0;

  // Whh bf16 B-fragments: 96 AGPR-pinned values (proven resident, R9)
  DECLW(0) DECLW(1) DECLW(2)  DECLW(3)  DECLW(4)  DECLW(5)
  DECLW(6) DECLW(7) DECLW(8)  DECLW(9)  DECLW(10) DECLW(11)
  LDW(0) LDW(1) LDW(2)  LDW(3)  LDW(4)  LDW(5)
  LDW(6) LDW(7) LDW(8)  LDW(9)  LDW(10) LDW(11)

  // h init into lds_h[0] (linear, single row)
  {
    u16 v = 0;
    if(t0 > 0) v = f2bf(hsave[(size_t)b*RH + tid]);
    lds_h[0][tid] = v;
  }
  float hst[4];
  #pragma unroll
  for(int jt=0;jt<4;++jt){
    int j = wid*64 + jt*16 + lr;
    hst[jt] = (t0>0) ? hsave[(size_t)b*RH + j] : 0.f;
  }

  // staging: 96 granules of 16B; wave0 -> granules 0-63, wave1 -> 64-127 (96-127 pad)
  int g = (wid==0) ? l : (64 + (l & 31));   // wave1 lanes 32-63 duplicate 64-95 reads
  const u16* xsrc = xgc + ((size_t)b*chk)*G3 + g*8;
  int lwb = (wid==0) ? 0 : 512;             // wave LDS base in u16 units

  // prologue: stage t0 into buf0, full drain, publish
  if(nsteps > 0 && wid < 2)
    stage16(xsrc, &lds_xg[0][lwb], nullptr);
  xsrc += G3;
  asm volatile("s_waitcnt vmcnt(0)" ::: "memory");
  asm volatile("s_waitcnt lgkmcnt(0)" ::: "memory");
  __builtin_amdgcn_sched_barrier(0);
  __builtin_amdgcn_s_barrier();
  __builtin_amdgcn_sched_barrier(0);

  u16* outbase = hseq + ((size_t)b*NTT + t0)*RH;
  for(int s=0; s<nsteps; ++s){
    const u16* hrd = &lds_h[s&1][0];
    u16*       hwr = &lds_h[(s+1)&1][0];
    const u16* xgr = &lds_xg[s&1][0];
    int more = (s+1 < nsteps);

    // issue next-step stage early (lands during this step's compute)
    if(more && wid < 2)
      stage16(xsrc, &lds_xg[(s+1)&1][lwb], nullptr);
    xsrc += G3;

    // hg = h @ Whh^T  (A: broadcast read of the single h row, masked to lane-row 0)
    f32x4 acc0 = {}, acc1 = {}, acc2 = {}, acc3 = {}, acc4 = {}, acc5 = {},
          acc6 = {}, acc7 = {}, acc8 = {}, acc9 = {}, acc10 = {}, acc11 = {};
    MST(0) MST(1) MST(2) MST(3) MST(4) MST(5) MST(6) MST(7)

    // gates: lanes 0-15; reads xg[cur] (published at previous barrier)
    u16* outp = outbase;
    if(l < 16){
      GATE1(0, acc0, acc4, acc8,  bh_0, bh_4, bh_8)
      GATE1(1, acc1, acc5, acc9,  bh_1, bh_5, bh_9)
      GATE1(2, acc2, acc6, acc10, bh_2, bh_6, bh_10)
      GATE1(3, acc3, acc7, acc11, bh_3, bh_7, bh_11)
    }
    outbase += RH;

    if(more){
      asm volatile("s_waitcnt lgkmcnt(0)" ::: "memory");  // h[nxt] writes + LDS reads done
      asm volatile("s_waitcnt vmcnt(4)" ::: "memory");    // stage load landed; 4 stores fly
      __builtin_amdgcn_sched_barrier(0);
      __builtin_amdgcn_s_barrier();                       // publish h[nxt] + xg[nxt]
      __builtin_amdgcn_sched_barrier(0);
    }
  }

  // zero-fill [max(tend,t0), t1) so hseq is fully written & deterministic
  if(l < 16){
    u16* zp = outbase;
    for(int t = (tend > t0 ? tend : t0); t < t1; ++t){
      #pragma unroll
      for(int jt=0;jt<4;++jt) zp[wid*64 + jt*16 + l] = 0;
      zp += RH;
    }
    // save exact f32 state for next chunk
    #pragma unroll
    for(int jt=0;jt<4;++jt)
      hsave[(size_t)b*RH + wid*64 + jt*16 + l] = hst[jt];
  }
}

// ---------------- launcher ----------------
extern "C" void kernel_launch(void* const* d_in, const int* in_sizes, int n_in,
                              void* d_out, int out_size, void* d_ws, size_t ws_size,
                              hipStream_t stream){
  (void)in_sizes; (void)n_in; (void)out_size;
  const int*   skills = (const int*)d_in[0];
  const int*   resp   = (const int*)d_in[1];
  const int*   lens   = (const int*)d_in[2];
  const int*   eidx   = (const int*)d_in[3];
  const float* ew     = (const float*)d_in[4];
  const float* emb    = (const float*)d_in[5];
  const float* gW[2][7];
  for(int l2=0;l2<2;++l2) for(int j=0;j<7;++j) gW[l2][j] = (const float*)d_in[6 + l2*7 + j];
  const float* remb  = (const float*)d_in[20];
  const float* Wih   = (const float*)d_in[21];
  const float* Whh   = (const float*)d_in[22];
  const float* bih   = (const float*)d_in[23];
  const float* bhh   = (const float*)d_in[24];
  const float* projW = (const float*)d_in[25];
  const float* projb = (const float*)d_in[26];

  char* p = (char*)d_ws;
  size_t o = 0;
  auto take = [&](size_t bytes)->char*{ char* r = p + o; o = (o + bytes + 255) & ~(size_t)255; return r; };
  int*   deg  = (int*)  take(4*N_NODES);
  int*   fill = (int*)  take(4*N_NODES);
  float* wsum = (float*)take(4*N_NODES);
  size_t zbytes = o;                        // deg+fill+wsum zeroed each call
  int*   off   = (int*)  take(4*(N_NODES+1));
  int*   csrs  = (int*)  take(4*NE_TOT);
  float* csrw  = (float*)take(4*NE_TOT);
  u16*   xl    = (u16*)  take(2UL*N_NODES*EMB);
  u16*   xr    = (u16*)  take(2UL*N_NODES*EMB);
  float* h1    = (float*)take(4UL*N_NODES*EMB);
  float* hsave = (float*)take(4UL*NB*RH);
  u16*   whb   = (u16*)  take(2UL*G3*RH);
  u16*   hseq  = (u16*)  take(2UL*NB*NTT*RH);
  size_t fixed_end = o;
  // xg chunk length: largest of {200,100,50,25} that fits ws_size
  int chk = 200;
  while(chk > 25 && fixed_end + 2UL*NB*(size_t)chk*G3 > ws_size) chk /= 2;
  u16*   xgc  = (u16*)  take(2UL*NB*(size_t)chk*G3);

  float* outP = (float*)d_out;                     // h_proj [256,200,128] f32
  float* outE = outP + (size_t)NB*NTT*EMB;         // skill_embs [10000,128] f32

  hipMemsetAsync(d_ws, 0, zbytes, stream);
  k_deg<<<(NE+255)/256, 256, 0, stream>>>(eidx, ew, deg, wsum);
  k_scan<<<1, 1024, 0, stream>>>(deg, wsum, off);
  k_scatter<<<(NE_TOT+255)/256, 256, 0, stream>>>(eidx, ew, wsum, off, fill, csrs, csrw);
  k_cvtw<<<(G3*RH+255)/256, 256, 0, stream>>>(Whh, whb, G3*RH);

  dim3 gN((N_NODES+127)/128, EMB/64);
  // layer 0 (A = emb f32 -> xl/xr bf16)
  k_gemm<0,false><<<gN, 256, 0, stream>>>(emb, gW[0][0], gW[0][1], xl, N_NODES, EMB, EMB,
                                 nullptr, nullptr, nullptr, 0,0, nullptr);
  k_gemm<0,false><<<gN, 256, 0, stream>>>(emb, gW[0][2], gW[0][3], xr, N_NODES, EMB, EMB,
                                 nullptr, nullptr, nullptr, 0,0, nullptr);
  k_attn<<<N_NODES/4, 256, 0, stream>>>(off, csrs, csrw, xl, xr, gW[0][4], gW[0][5], gW[0][6], h1);
  // layer 1 (A = h1 f32)
  k_gemm<0,false><<<gN, 256, 0, stream>>>(h1, gW[1][0], gW[1][1], xl, N_NODES, EMB, EMB,
                                 nullptr, nullptr, nullptr, 0,0, nullptr);
  k_gemm<0,false><<<gN, 256, 0, stream>>>(h1, gW[1][2], gW[1][3], xr, N_NODES, EMB, EMB,
                                 nullptr, nullptr, nullptr, 0,0, nullptr);
  k_attn<<<N_NODES/4, 256, 0, stream>>>(off, csrs, csrw, xl, xr, gW[1][4], gW[1][5], gW[1][6], outE);

  // chunked: xg = (skill_embs[skills]+resp_emb[resp]) @ Wih^T + bih, then GRU chunk
  for(int t0=0; t0<NTT; t0+=chk){
    k_gemm<1,false><<<dim3(NB*chk/128, G3/64), 256, 0, stream>>>(outE, Wih, bih, xgc,
                                 NB*chk, G3, EMB, skills, resp, remb, t0, chk, nullptr);
    k_gru<<<NB, 256, 0, stream>>>(xgc, whb, bhh, lens, hseq, hsave, t0, t0+chk, chk);
  }
  // proj: A = hseq bf16, out f32 (+ lens mask; hseq rows t>=len are exact zeros)
  k_gemm<2,true><<<dim3(NB*NTT/128, EMB/64), 256, 0, stream>>>(hseq, projW, projb, outP,
                                 NB*NTT, EMB, RH,
                                 nullptr, nullptr, nullptr, 0,0, lens);
}

// Round 15
// 761.845 us; speedup vs baseline: 2.4259x; 1.1396x over previous
//
#include <hip/hip_runtime.h>

#define N_NODES 10000
#define EMB     128
#define NE      320000
#define NE_TOT  330000   // + one self-loop per node
#define NB      256
#define NTT     200
#define RH      256
#define G3      768

typedef unsigned short u16;
typedef u16    u16x8  __attribute__((ext_vector_type(8)));
typedef __bf16 bf16x8 __attribute__((ext_vector_type(8)));
typedef float  f32x4  __attribute__((ext_vector_type(4)));

static __device__ __forceinline__ float bf2f(u16 u){
  unsigned int x = ((unsigned int)u) << 16;
  return __builtin_bit_cast(float, x);
}
static __device__ __forceinline__ u16 f2bf(float f){
  unsigned int x = __builtin_bit_cast(unsigned int, f);
  x += 0x7fffu + ((x >> 16) & 1u);
  return (u16)(x >> 16);
}

// async global->LDS, 16B per lane; lds dest must be the WAVE base (HW adds lane*16)
static __device__ __forceinline__ void stage16(const u16* g, u16* lds_wavebase, u16* lds_lane){
#if __has_builtin(__builtin_amdgcn_global_load_lds)
  __builtin_amdgcn_global_load_lds(
      (const __attribute__((address_space(1))) unsigned int*)g,
      (__attribute__((address_space(3))) unsigned int*)lds_wavebase, 16, 0, 0);
  (void)lds_lane;
#else
  *(u16x8*)lds_lane = *(const u16x8*)g;
#endif
}

// static-index selects (rule #20: no runtime-indexed register arrays)
static __device__ __forceinline__ float self4(f32x4 v, int r){
  float lo = (r&1) ? v[1] : v[0];
  float hi = (r&1) ? v[3] : v[2];
  return (r&2) ? hi : lo;
}
static __device__ __forceinline__ f32x4 seltile(f32x4 a, f32x4 b, f32x4 c, f32x4 d, int jt){
  f32x4 r;
  #pragma unroll
  for(int e=0;e<4;++e){
    float ab = (jt&1) ? b[e] : a[e];
    float cd = (jt&1) ? d[e] : c[e];
    r[e] = (jt&2) ? cd : ab;
  }
  return r;
}

// ---------------- CSR build ----------------
__global__ void k_deg(const int* __restrict__ eidx, const float* __restrict__ ew,
                      int* __restrict__ deg, float* __restrict__ wsum){
  int i = blockIdx.x*256 + threadIdx.x;
  if(i >= NE) return;
  int d = eidx[NE + i];
  atomicAdd(&deg[d], 1);
  atomicAdd(&wsum[d], ew[i]);
}

__global__ __launch_bounds__(1024) void k_scan(const int* __restrict__ deg,
                      float* __restrict__ wsum, int* __restrict__ off){
  __shared__ int part[1024];
  int tid = threadIdx.x;
  int n0 = tid*10;
  int s = 0;
  for(int i=0;i<10;++i){ int n=n0+i; if(n<N_NODES) s += deg[n]+1; }
  part[tid] = s;
  for(int i=0;i<10;++i){
    int n=n0+i;
    if(n<N_NODES){ int d=deg[n]; wsum[n] = wsum[n] / (float)(d>1?d:1); }
  }
  __syncthreads();
  for(int st=1; st<1024; st<<=1){
    int v = (tid>=st) ? part[tid-st] : 0;
    __syncthreads();
    part[tid] += v;
    __syncthreads();
  }
  int base = tid ? part[tid-1] : 0;
  for(int i=0;i<10;++i){ int n=n0+i; if(n<N_NODES){ off[n]=base; base += deg[n]+1; } }
  if(tid==999) off[N_NODES] = base;
}

__global__ void k_scatter(const int* __restrict__ eidx, const float* __restrict__ ew,
                          const float* __restrict__ la, const int* __restrict__ off,
                          int* __restrict__ fill, int* __restrict__ csrs, float* __restrict__ csrw){
  int i = blockIdx.x*256 + threadIdx.x;
  if(i >= NE_TOT) return;
  int s, d; float w;
  if(i < NE){ s = eidx[i]; d = eidx[NE+i]; w = ew[i]; }
  else      { int n = i-NE; s=n; d=n; w = la[n]; }   // self-loop, weight = mean incoming
  int pos = off[d] + atomicAdd(&fill[d], 1);
  csrs[pos] = s; csrw[pos] = w;
}

// ---------------- Whh f32 -> bf16 preconvert (once per call) ----------------
__global__ void k_cvtw(const float* __restrict__ W, u16* __restrict__ Wb, int n){
  int i = blockIdx.x*256 + threadIdx.x;
  if(i < n) Wb[i] = f2bf(W[i]);
}

// ---------------- MFMA GEMM: C = A @ W^T + bias ----------------
template<int AMODE, bool OUTF32>
__global__ __launch_bounds__(256) void k_gemm(
    const void* __restrict__ Av, const float* __restrict__ W, const float* __restrict__ bias,
    void* __restrict__ out,
    int M, int N, int K,
    const int* __restrict__ gidx, const int* __restrict__ ridx, const float* __restrict__ remb,
    int t0, int chk,
    const int* __restrict__ lens)
{
  int tid = threadIdx.x;
  int wid = tid >> 6, l = tid & 63;
  int lr = l & 15, lg = l >> 4;
  int bm = blockIdx.x*128 + wid*32;
  int bn = blockIdx.y*64;
  f32x4 acc[2][4] = {};
  int nk = K >> 5;
  for(int kt=0; kt<nk; ++kt){
    int k0 = kt*32 + lg*8;
    bf16x8 af[2];
    #pragma unroll
    for(int mi=0; mi<2; ++mi){
      int row = bm + mi*16 + lr;
      u16x8 v = {0,0,0,0,0,0,0,0};
      if(row < M){
        if constexpr(AMODE == 1){
          int b = row / chk, tt = row - b*chk;
          int gi = b*NTT + t0 + tt;
          const float* ar = (const float*)Av + (size_t)gidx[gi]*K + k0;
          const float* rr = remb + (size_t)ridx[gi]*K + k0;
          #pragma unroll
          for(int e=0;e<8;++e) v[e] = f2bf(ar[e] + rr[e]);
        } else if constexpr(AMODE == 0){
          const float* ar = (const float*)Av + (size_t)row*K + k0;
          #pragma unroll
          for(int e=0;e<8;++e) v[e] = f2bf(ar[e]);
        } else {
          v = *(const u16x8*)((const u16*)Av + (size_t)row*K + k0);
        }
      }
      af[mi] = __builtin_bit_cast(bf16x8, v);
    }
    #pragma unroll
    for(int nt=0; nt<4; ++nt){
      int col = bn + nt*16 + lr;
      const float* wr = W + (size_t)col*K + k0;
      u16x8 wv;
      #pragma unroll
      for(int e=0;e<8;++e) wv[e] = f2bf(wr[e]);
      bf16x8 bfr = __builtin_bit_cast(bf16x8, wv);
      acc[0][nt] = __builtin_amdgcn_mfma_f32_16x16x32_bf16(af[0], bfr, acc[0][nt], 0,0,0);
      acc[1][nt] = __builtin_amdgcn_mfma_f32_16x16x32_bf16(af[1], bfr, acc[1][nt], 0,0,0);
    }
  }
  #pragma unroll
  for(int mi=0; mi<2; ++mi){
    #pragma unroll
    for(int nt=0; nt<4; ++nt){
      int col = bn + nt*16 + lr;
      float bc = bias[col];
      #pragma unroll
      for(int r=0; r<4; ++r){
        int row = bm + mi*16 + lg*4 + r;
        if(row >= M) continue;
        float v = acc[mi][nt][r] + bc;
        if(lens){ int b = row/NTT; int t = row - b*NTT; if(t >= lens[b]) v = bc; }
        if constexpr(OUTF32) ((float*)out)[(size_t)row*N + col] = v;
        else                 ((u16*) out)[(size_t)row*N + col] = f2bf(v);
      }
    }
  }
}

// ---------------- GATv2 attention + aggregate + bias + ELU ----------------
__global__ __launch_bounds__(256) void k_attn(
    const int* __restrict__ off, const int* __restrict__ csrs, const float* __restrict__ csrw,
    const u16* __restrict__ xl, const u16* __restrict__ xr,
    const float* __restrict__ We, const float* __restrict__ att, const float* __restrict__ bias,
    float* __restrict__ hout)
{
  int wid = threadIdx.x >> 6, l = threadIdx.x & 63;
  int n = blockIdx.x*4 + wid;
  int d0 = 2*l;
  const unsigned int* xl2 = (const unsigned int*)xl;
  unsigned int xru = ((const unsigned int*)xr)[n*64 + l];
  float xrx = bf2f((u16)xru), xry = bf2f((u16)(xru>>16));
  float wex = We[d0],  wey = We[d0+1];
  float atx = att[d0], aty = att[d0+1];
  int p0 = off[n], p1 = off[n+1];
  float mx = -1e30f;
  for(int p=p0; p<p1; ++p){
    int s = csrs[p]; float w = csrw[p];
    unsigned int u = xl2[s*64 + l];
    float ax = bf2f((u16)u)       + xrx + w*wex;
    float ay = bf2f((u16)(u>>16)) + xry + w*wey;
    ax = ax > 0.f ? ax : 0.2f*ax;
    ay = ay > 0.f ? ay : 0.2f*ay;
    float c = ax*atx + ay*aty;
    c += __shfl_xor(c,1); c += __shfl_xor(c,2); c += __shfl_xor(c,4); c += __shfl_xor(c,8);
    mx = fmaxf(mx, c);
  }
  float den = 0.f, a0 = 0.f, a1 = 0.f;
  for(int p=p0; p<p1; ++p){
    int s = csrs[p]; float w = csrw[p];
    unsigned int u = xl2[s*64 + l];
    float xlx = bf2f((u16)u), xly = bf2f((u16)(u>>16));
    float ax = xlx + xrx + w*wex;
    float ay = xly + xry + w*wey;
    ax = ax > 0.f ? ax : 0.2f*ax;
    ay = ay > 0.f ? ay : 0.2f*ay;
    float c = ax*atx + ay*aty;
    c += __shfl_xor(c,1); c += __shfl_xor(c,2); c += __shfl_xor(c,4); c += __shfl_xor(c,8);
    float al = __expf(c - mx);
    den += al; a0 += al*xlx; a1 += al*xly;
  }
  float inv = 1.f/(den + 1e-16f);
  float o0 = a0*inv + bias[d0];
  float o1 = a1*inv + bias[d0+1];
  o0 = o0 > 0.f ? o0 : (__expf(o0) - 1.f);   // ELU
  o1 = o1 > 0.f ? o1 : (__expf(o1) - 1.f);
  hout[n*EMB + d0]   = o0;
  hout[n*EMB + d0+1] = o1;
}

// ---------------- GRU: 256 blocks x 1 batch row, 4 waves (1/SIMD) ----------------
// Swapped MFMA: A = Whh AGPR fragments (same layout), B = broadcast h -> output
// replicated across all 16 cols, so the 64 gate chains per wave distribute
// 1-per-lane (lane (lg,c): j = wid*64 + (c>>2)*16 + lg*4 + (c&3); acc picked via
// static cndmask selects). Bit-identical numerics (same dots, same k-tree, same
// kt accumulation order). Single barrier/step; counted vmcnt(1).

#define DECLW(nt) f32x4 wf_##nt##_0, wf_##nt##_1, wf_##nt##_2, wf_##nt##_3, \
                        wf_##nt##_4, wf_##nt##_5, wf_##nt##_6, wf_##nt##_7;

#define LDW1(nt,kt) { u16x8 wv = *(const u16x8*)(wr + (kt)*32 + lg*8); \
  wf_##nt##_##kt = __builtin_bit_cast(f32x4, wv); \
  asm volatile("" : "+a"(wf_##nt##_##kt)); }

#define LDW(nt) { int nrow = ((nt)>>2)*256 + wid*64 + ((nt)&3)*16 + lr; \
  const u16* wr = whb + (size_t)nrow*RH; \
  LDW1(nt,0) LDW1(nt,1) LDW1(nt,2) LDW1(nt,3) LDW1(nt,4) LDW1(nt,5) LDW1(nt,6) LDW1(nt,7) }

// D = A(AGPR wf) * B(VGPR h-broadcast) + D
#define MFMA1(acc, wf, hf) asm volatile( \
  "v_mfma_f32_16x16x32_bf16 %0, %1, %2, %0" : "+v"(acc) : "a"(wf), "v"(hf));

#define MST(kt) { \
  f32x4 hf = __builtin_bit_cast(f32x4, *(const u16x8*)(hrd + (kt)*32 + lg*8)); \
  MFMA1(acc0,  wf_0_##kt,  hf) MFMA1(acc1,  wf_1_##kt,  hf) \
  MFMA1(acc2,  wf_2_##kt,  hf) MFMA1(acc3,  wf_3_##kt,  hf) \
  MFMA1(acc4,  wf_4_##kt,  hf) MFMA1(acc5,  wf_5_##kt,  hf) \
  MFMA1(acc6,  wf_6_##kt,  hf) MFMA1(acc7,  wf_7_##kt,  hf) \
  MFMA1(acc8,  wf_8_##kt,  hf) MFMA1(acc9,  wf_9_##kt,  hf) \
  MFMA1(acc10, wf_10_##kt, hf) MFMA1(acc11, wf_11_##kt, hf) }

__global__ __launch_bounds__(256,1) __attribute__((amdgpu_waves_per_eu(1,1))) void k_gru(
    const u16* __restrict__ xgc, const u16* __restrict__ whb, const float* __restrict__ bhh,
    const int* __restrict__ lens, u16* __restrict__ hseq, float* __restrict__ hsave,
    int t0, int t1, int chk)
{
  int tid = threadIdx.x;
  int wid = tid >> 6, l = tid & 63;
  int lr = l & 15, lg = l >> 4;
  int b = blockIdx.x;                       // one batch row per block
  __shared__ __align__(16) u16 lds_h[2][256];    // 1 KB, double-buffered
  __shared__ __align__(16) u16 lds_xg[2][1024];  // 4 KB (768 used + 512B pad)

  int mylen = lens[b];
  int tend = mylen < t1 ? mylen : t1;
  int nsteps = tend - t0; if(nsteps < 0) nsteps = 0;

  // Whh bf16 A-fragments: 96 AGPR-pinned values (layout: row=lr, k=lg*8+e)
  DECLW(0) DECLW(1) DECLW(2)  DECLW(3)  DECLW(4)  DECLW(5)
  DECLW(6) DECLW(7) DECLW(8)  DECLW(9)  DECLW(10) DECLW(11)
  LDW(0) LDW(1) LDW(2)  LDW(3)  LDW(4)  LDW(5)
  LDW(6) LDW(7) LDW(8)  LDW(9)  LDW(10) LDW(11)

  // this lane's gate assignment: j = wid*64 + (lr>>2)*16 + lg*4 + (lr&3)
  int jt   = lr >> 2;
  int rsel = lr & 3;
  int j    = wid*64 + jt*16 + lg*4 + rsel;
  float bhR = bhh[      j];
  float bhZ = bhh[256 + j];
  float bhN = bhh[512 + j];

  // h init into lds_h[0] (linear, single row)
  {
    u16 v = 0;
    if(t0 > 0) v = f2bf(hsave[(size_t)b*RH + tid]);
    lds_h[0][tid] = v;
  }
  float hst = (t0>0) ? hsave[(size_t)b*RH + j] : 0.f;

  // staging: 96 granules of 16B; wave0 -> granules 0-63, wave1 -> 64-127 (96-127 pad)
  int g = (wid==0) ? l : (64 + (l & 31));   // wave1 lanes 32-63 duplicate 64-95 reads
  const u16* xsrc = xgc + ((size_t)b*chk)*G3 + g*8;
  int lwb = (wid==0) ? 0 : 512;             // wave LDS base in u16 units

  // prologue: stage t0 into buf0, full drain, publish
  if(nsteps > 0 && wid < 2)
    stage16(xsrc, &lds_xg[0][lwb], nullptr);
  xsrc += G3;
  asm volatile("s_waitcnt vmcnt(0)" ::: "memory");
  asm volatile("s_waitcnt lgkmcnt(0)" ::: "memory");
  __builtin_amdgcn_sched_barrier(0);
  __builtin_amdgcn_s_barrier();
  __builtin_amdgcn_sched_barrier(0);

  u16* outbase = hseq + ((size_t)b*NTT + t0)*RH;
  for(int s=0; s<nsteps; ++s){
    const u16* hrd = &lds_h[s&1][0];
    u16*       hwr = &lds_h[(s+1)&1][0];
    const u16* xgr = &lds_xg[s&1][0];
    int more = (s+1 < nsteps);

    // issue next-step stage early (lands during this step's compute)
    if(more && wid < 2)
      stage16(xsrc, &lds_xg[(s+1)&1][lwb], nullptr);
    xsrc += G3;

    // hg = Whh @ h  (A from AGPRs, B = broadcast h row; no masking needed)
    f32x4 acc0 = {}, acc1 = {}, acc2 = {}, acc3 = {}, acc4 = {}, acc5 = {},
          acc6 = {}, acc7 = {}, acc8 = {}, acc9 = {}, acc10 = {}, acc11 = {};
    MST(0) MST(1) MST(2) MST(3) MST(4) MST(5) MST(6) MST(7)

    // gates: 1 chain per lane (64/wave). acc rows replicated across cols.
    {
      f32x4 aR = seltile(acc0, acc1, acc2,  acc3,  jt);
      f32x4 aZ = seltile(acc4, acc5, acc6,  acc7,  jt);
      f32x4 aN = seltile(acc8, acc9, acc10, acc11, jt);
      float hr = self4(aR, rsel) + bhR;
      float hz = self4(aZ, rsel) + bhZ;
      float hn = self4(aN, rsel) + bhN;
      float xrv = bf2f(xgr[      j]);
      float xzv = bf2f(xgr[256 + j]);
      float xnv = bf2f(xgr[512 + j]);
      float rg = 1.f/(1.f + __expf(-(xrv + hr)));
      float zg = 1.f/(1.f + __expf(-(xzv + hz)));
      float nn = xnv + rg*hn;
      float tg = 1.f - 2.f/(__expf(2.f*nn) + 1.f);   // tanh
      float hv = (1.f - zg)*tg + zg*hst;
      hst = hv;
      u16 hb = f2bf(hv);
      hwr[j] = hb;
      outbase[j] = hb;
    }
    outbase += RH;

    if(more){
      asm volatile("s_waitcnt lgkmcnt(0)" ::: "memory");  // h[nxt] write + LDS reads done
      asm volatile("s_waitcnt vmcnt(1)" ::: "memory");    // stage load landed; store flies
      __builtin_amdgcn_sched_barrier(0);
      __builtin_amdgcn_s_barrier();                       // publish h[nxt] + xg[nxt]
      __builtin_amdgcn_sched_barrier(0);
    }
  }

  // zero-fill [max(tend,t0), t1) so hseq is fully written & deterministic
  {
    u16* zp = outbase;
    for(int t = (tend > t0 ? tend : t0); t < t1; ++t){
      zp[j] = 0;
      zp += RH;
    }
  }

  // save exact f32 state for next chunk
  hsave[(size_t)b*RH + j] = hst;
}

// ---------------- launcher ----------------
extern "C" void kernel_launch(void* const* d_in, const int* in_sizes, int n_in,
                              void* d_out, int out_size, void* d_ws, size_t ws_size,
                              hipStream_t stream){
  (void)in_sizes; (void)n_in; (void)out_size;
  const int*   skills = (const int*)d_in[0];
  const int*   resp   = (const int*)d_in[1];
  const int*   lens   = (const int*)d_in[2];
  const int*   eidx   = (const int*)d_in[3];
  const float* ew     = (const float*)d_in[4];
  const float* emb    = (const float*)d_in[5];
  const float* gW[2][7];
  for(int l2=0;l2<2;++l2) for(int j=0;j<7;++j) gW[l2][j] = (const float*)d_in[6 + l2*7 + j];
  const float* remb  = (const float*)d_in[20];
  const float* Wih   = (const float*)d_in[21];
  const float* Whh   = (const float*)d_in[22];
  const float* bih   = (const float*)d_in[23];
  const float* bhh   = (const float*)d_in[24];
  const float* projW = (const float*)d_in[25];
  const float* projb = (const float*)d_in[26];

  char* p = (char*)d_ws;
  size_t o = 0;
  auto take = [&](size_t bytes)->char*{ char* r = p + o; o = (o + bytes + 255) & ~(size_t)255; return r; };
  int*   deg  = (int*)  take(4*N_NODES);
  int*   fill = (int*)  take(4*N_NODES);
  float* wsum = (float*)take(4*N_NODES);
  size_t zbytes = o;                        // deg+fill+wsum zeroed each call
  int*   off   = (int*)  take(4*(N_NODES+1));
  int*   csrs  = (int*)  take(4*NE_TOT);
  float* csrw  = (float*)take(4*NE_TOT);
  u16*   xl    = (u16*)  take(2UL*N_NODES*EMB);
  u16*   xr    = (u16*)  take(2UL*N_NODES*EMB);
  float* h1    = (float*)take(4UL*N_NODES*EMB);
  float* hsave = (float*)take(4UL*NB*RH);
  u16*   whb   = (u16*)  take(2UL*G3*RH);
  u16*   hseq  = (u16*)  take(2UL*NB*NTT*RH);
  size_t fixed_end = o;
  // xg chunk length: largest of {200,100,50,25} that fits ws_size
  int chk = 200;
  while(chk > 25 && fixed_end + 2UL*NB*(size_t)chk*G3 > ws_size) chk /= 2;
  u16*   xgc  = (u16*)  take(2UL*NB*(size_t)chk*G3);

  float* outP = (float*)d_out;                     // h_proj [256,200,128] f32
  float* outE = outP + (size_t)NB*NTT*EMB;         // skill_embs [10000,128] f32

  hipMemsetAsync(d_ws, 0, zbytes, stream);
  k_deg<<<(NE+255)/256, 256, 0, stream>>>(eidx, ew, deg, wsum);
  k_scan<<<1, 1024, 0, stream>>>(deg, wsum, off);
  k_scatter<<<(NE_TOT+255)/256, 256, 0, stream>>>(eidx, ew, wsum, off, fill, csrs, csrw);
  k_cvtw<<<(G3*RH+255)/256, 256, 0, stream>>>(Whh, whb, G3*RH);

  dim3 gN((N_NODES+127)/128, EMB/64);
  // layer 0 (A = emb f32 -> xl/xr bf16)
  k_gemm<0,false><<<gN, 256, 0, stream>>>(emb, gW[0][0], gW[0][1], xl, N_NODES, EMB, EMB,
                                 nullptr, nullptr, nullptr, 0,0, nullptr);
  k_gemm<0,false><<<gN, 256, 0, stream>>>(emb, gW[0][2], gW[0][3], xr, N_NODES, EMB, EMB,
                                 nullptr, nullptr, nullptr, 0,0, nullptr);
  k_attn<<<N_NODES/4, 256, 0, stream>>>(off, csrs, csrw, xl, xr, gW[0][4], gW[0][5], gW[0][6], h1);
  // layer 1 (A = h1 f32)
  k_gemm<0,false><<<gN, 256, 0, stream>>>(h1, gW[1][0], gW[1][1], xl, N_NODES, EMB, EMB,
                                 nullptr, nullptr, nullptr, 0,0, nullptr);
  k_gemm<0,false><<<gN, 256, 0, stream>>>(h1, gW[1][2], gW[1][3], xr, N_NODES, EMB, EMB,
                                 nullptr, nullptr, nullptr, 0,0, nullptr);
  k_attn<<<N_NODES/4, 256, 0, stream>>>(off, csrs, csrw, xl, xr, gW[1][4], gW[1][5], gW[1][6], outE);

  // chunked: xg = (skill_embs[skills]+resp_emb[resp]) @ Wih^T + bih, then GRU chunk
  for(int t0=0; t0<NTT; t0+=chk){
    k_gemm<1,false><<<dim3(NB*chk/128, G3/64), 256, 0, stream>>>(outE, Wih, bih, xgc,
                                 NB*chk, G3, EMB, skills, resp, remb, t0, chk, nullptr);
    k_gru<<<NB, 256, 0, stream>>>(xgc, whb, bhh, lens, hseq, hsave, t0, t0+chk, chk);
  }
  // proj: A = hseq bf16, out f32 (+ lens mask; hseq rows t>=len are exact zeros)
  k_gemm<2,true><<<dim3(NB*NTT/128, EMB/64), 256, 0, stream>>>(hseq, projW, projb, outP,
                                 NB*NTT, EMB, RH,
                                 nullptr, nullptr, nullptr, 0,0, lens);
}

// Round 17
// 679.497 us; speedup vs baseline: 2.7199x; 1.1212x over previous
//
#include <hip/hip_runtime.h>

#define N_NODES 10000
#define EMB     128
#define NE      320000
#define NE_TOT  330000   // + one self-loop per node
#define NB      256
#define NTT     200
#define RH      256
#define G3      768

typedef unsigned short u16;
typedef u16    u16x8  __attribute__((ext_vector_type(8)));
typedef __bf16 bf16x8 __attribute__((ext_vector_type(8)));
typedef float  f32x4  __attribute__((ext_vector_type(4)));

static __device__ __forceinline__ float bf2f(u16 u){
  unsigned int x = ((unsigned int)u) << 16;
  return __builtin_bit_cast(float, x);
}
static __device__ __forceinline__ u16 f2bf(float f){
  unsigned int x = __builtin_bit_cast(unsigned int, f);
  x += 0x7fffu + ((x >> 16) & 1u);
  return (u16)(x >> 16);
}

// async global->LDS, 16B per lane; lds dest must be the WAVE base (HW adds lane*16)
static __device__ __forceinline__ void stage16(const u16* g, u16* lds_wavebase, u16* lds_lane){
#if __has_builtin(__builtin_amdgcn_global_load_lds)
  __builtin_amdgcn_global_load_lds(
      (const __attribute__((address_space(1))) unsigned int*)g,
      (__attribute__((address_space(3))) unsigned int*)lds_wavebase, 16, 0, 0);
  (void)lds_lane;
#else
  *(u16x8*)lds_lane = *(const u16x8*)g;
#endif
}

// static-index selects (rule #20: no runtime-indexed register arrays)
static __device__ __forceinline__ float self4(f32x4 v, int r){
  float lo = (r&1) ? v[1] : v[0];
  float hi = (r&1) ? v[3] : v[2];
  return (r&2) ? hi : lo;
}
static __device__ __forceinline__ f32x4 seltile(f32x4 a, f32x4 b, f32x4 c, f32x4 d, int jt){
  f32x4 r;
  #pragma unroll
  for(int e=0;e<4;++e){
    float ab = (jt&1) ? b[e] : a[e];
    float cd = (jt&1) ? d[e] : c[e];
    r[e] = (jt&2) ? cd : ab;
  }
  return r;
}

// ---------------- CSR build ----------------
__global__ void k_deg(const int* __restrict__ eidx, const float* __restrict__ ew,
                      int* __restrict__ deg, float* __restrict__ wsum){
  int i = blockIdx.x*256 + threadIdx.x;
  if(i >= NE) return;
  int d = eidx[NE + i];
  atomicAdd(&deg[d], 1);
  atomicAdd(&wsum[d], ew[i]);
}

__global__ __launch_bounds__(1024) void k_scan(const int* __restrict__ deg,
                      float* __restrict__ wsum, int* __restrict__ off){
  __shared__ int part[1024];
  int tid = threadIdx.x;
  int n0 = tid*10;
  int s = 0;
  for(int i=0;i<10;++i){ int n=n0+i; if(n<N_NODES) s += deg[n]+1; }
  part[tid] = s;
  for(int i=0;i<10;++i){
    int n=n0+i;
    if(n<N_NODES){ int d=deg[n]; wsum[n] = wsum[n] / (float)(d>1?d:1); }
  }
  __syncthreads();
  for(int st=1; st<1024; st<<=1){
    int v = (tid>=st) ? part[tid-st] : 0;
    __syncthreads();
    part[tid] += v;
    __syncthreads();
  }
  int base = tid ? part[tid-1] : 0;
  for(int i=0;i<10;++i){ int n=n0+i; if(n<N_NODES){ off[n]=base; base += deg[n]+1; } }
  if(tid==999) off[N_NODES] = base;
}

__global__ void k_scatter(const int* __restrict__ eidx, const float* __restrict__ ew,
                          const float* __restrict__ la, const int* __restrict__ off,
                          int* __restrict__ fill, int* __restrict__ csrs, float* __restrict__ csrw){
  int i = blockIdx.x*256 + threadIdx.x;
  if(i >= NE_TOT) return;
  int s, d; float w;
  if(i < NE){ s = eidx[i]; d = eidx[NE+i]; w = ew[i]; }
  else      { int n = i-NE; s=n; d=n; w = la[n]; }   // self-loop, weight = mean incoming
  int pos = off[d] + atomicAdd(&fill[d], 1);
  csrs[pos] = s; csrw[pos] = w;
}

// ---------------- all weights f32 -> bf16, packed (once per call) ----------------
// layout: g0l@0, g0r@16384, g1l@32768, g1r@49152, wih@65536, whh@163840, proj@360448
#define WB_TOT 393216
__global__ __launch_bounds__(256) void k_cvtall(
    const float* __restrict__ g0l, const float* __restrict__ g0r,
    const float* __restrict__ g1l, const float* __restrict__ g1r,
    const float* __restrict__ wih, const float* __restrict__ whh,
    const float* __restrict__ pw, u16* __restrict__ wb){
  int i = blockIdx.x*256 + threadIdx.x;
  if(i >= WB_TOT) return;
  float v;
  if(i < 65536){
    int seg = i >> 14, r = i & 16383;
    const float* s = (seg==0) ? g0l : (seg==1) ? g0r : (seg==2) ? g1l : g1r;
    v = s[r];
  } else if(i < 163840){ v = wih[i - 65536]; }
  else if(i < 360448){ v = whh[i - 163840]; }
  else               { v = pw [i - 360448]; }
  wb[i] = f2bf(v);
}

// ---------------- gather: xemb = bf16(skill_embs[skills] + resp_emb[resp]) ----------------
__global__ __launch_bounds__(256) void k_gather(
    const float* __restrict__ embN, const float* __restrict__ remb,
    const int* __restrict__ skills, const int* __restrict__ resp,
    u16* __restrict__ xemb){
  int i = blockIdx.x*256 + threadIdx.x;           // one per 8 elems
  if(i >= NB*NTT*EMB/8) return;
  int row = i >> 4;                               // 16 groups of 8 per row
  int g8  = (i & 15) * 8;
  const float* ar = embN + (size_t)skills[row]*EMB + g8;
  const float* rr = remb + (size_t)resp[row]*EMB + g8;
  u16x8 v;
  #pragma unroll
  for(int e=0;e<8;++e) v[e] = f2bf(ar[e] + rr[e]);
  *(u16x8*)(xemb + (size_t)row*EMB + g8) = v;
}

// ---------------- MFMA GEMM: C = A @ W^T + bias (W bf16 preconverted) ----------------
// AMODE: 0 = A f32 [M,K]; 2 = A bf16 [M,K]; 3 = A bf16 with chunk row map
//        (row -> b*NTT + t0 + row%chk).
// lens != null (proj): row=(b*NTT+t), t>=lens[b] -> bias only.
template<int AMODE, bool OUTF32>
__global__ __launch_bounds__(256) void k_gemm(
    const void* __restrict__ Av, const u16* __restrict__ W, const float* __restrict__ bias,
    void* __restrict__ out,
    int M, int N, int K,
    int t0, int chk,
    const int* __restrict__ lens)
{
  int tid = threadIdx.x;
  int wid = tid >> 6, l = tid & 63;
  int lr = l & 15, lg = l >> 4;
  int bm = blockIdx.x*128 + wid*32;
  int bn = blockIdx.y*64;
  f32x4 acc[2][4] = {};
  int nk = K >> 5;
  for(int kt=0; kt<nk; ++kt){
    int k0 = kt*32 + lg*8;
    bf16x8 af[2];
    #pragma unroll
    for(int mi=0; mi<2; ++mi){
      int row = bm + mi*16 + lr;
      u16x8 v = {0,0,0,0,0,0,0,0};
      if(row < M){
        if constexpr(AMODE == 0){
          const float* ar = (const float*)Av + (size_t)row*K + k0;
          #pragma unroll
          for(int e=0;e<8;++e) v[e] = f2bf(ar[e]);
        } else if constexpr(AMODE == 3){
          int b = row / chk, tt = row - b*chk;
          int arow = b*NTT + t0 + tt;
          v = *(const u16x8*)((const u16*)Av + (size_t)arow*K + k0);
        } else {
          v = *(const u16x8*)((const u16*)Av + (size_t)row*K + k0);
        }
      }
      af[mi] = __builtin_bit_cast(bf16x8, v);
    }
    #pragma unroll
    for(int nt=0; nt<4; ++nt){
      int col = bn + nt*16 + lr;
      u16x8 wv = *(const u16x8*)(W + (size_t)col*K + k0);
      bf16x8 bfr = __builtin_bit_cast(bf16x8, wv);
      acc[0][nt] = __builtin_amdgcn_mfma_f32_16x16x32_bf16(af[0], bfr, acc[0][nt], 0,0,0);
      acc[1][nt] = __builtin_amdgcn_mfma_f32_16x16x32_bf16(af[1], bfr, acc[1][nt], 0,0,0);
    }
  }
  #pragma unroll
  for(int mi=0; mi<2; ++mi){
    #pragma unroll
    for(int nt=0; nt<4; ++nt){
      int col = bn + nt*16 + lr;
      float bc = bias[col];
      #pragma unroll
      for(int r=0; r<4; ++r){
        int row = bm + mi*16 + lg*4 + r;
        if(row >= M) continue;
        float v = acc[mi][nt][r] + bc;
        if(lens){ int b = row/NTT; int t = row - b*NTT; if(t >= lens[b]) v = bc; }
        if constexpr(OUTF32) ((float*)out)[(size_t)row*N + col] = v;
        else                 ((u16*) out)[(size_t)row*N + col] = f2bf(v);
      }
    }
  }
}

// ---------------- GATv2 attention + aggregate + bias + ELU ----------------
__global__ __launch_bounds__(256) void k_attn(
    const int* __restrict__ off, const int* __restrict__ csrs, const float* __restrict__ csrw,
    const u16* __restrict__ xl, const u16* __restrict__ xr,
    const float* __restrict__ We, const float* __restrict__ att, const float* __restrict__ bias,
    float* __restrict__ hout)
{
  int wid = threadIdx.x >> 6, l = threadIdx.x & 63;
  int n = blockIdx.x*4 + wid;
  int d0 = 2*l;
  const unsigned int* xl2 = (const unsigned int*)xl;
  unsigned int xru = ((const unsigned int*)xr)[n*64 + l];
  float xrx = bf2f((u16)xru), xry = bf2f((u16)(xru>>16));
  float wex = We[d0],  wey = We[d0+1];
  float atx = att[d0], aty = att[d0+1];
  int p0 = off[n], p1 = off[n+1];
  float mx = -1e30f;
  for(int p=p0; p<p1; ++p){
    int s = csrs[p]; float w = csrw[p];
    unsigned int u = xl2[s*64 + l];
    float ax = bf2f((u16)u)       + xrx + w*wex;
    float ay = bf2f((u16)(u>>16)) + xry + w*wey;
    ax = ax > 0.f ? ax : 0.2f*ax;
    ay = ay > 0.f ? ay : 0.2f*ay;
    float c = ax*atx + ay*aty;
    c += __shfl_xor(c,1); c += __shfl_xor(c,2); c += __shfl_xor(c,4); c += __shfl_xor(c,8);
    mx = fmaxf(mx, c);
  }
  float den = 0.f, a0 = 0.f, a1 = 0.f;
  for(int p=p0; p<p1; ++p){
    int s = csrs[p]; float w = csrw[p];
    unsigned int u = xl2[s*64 + l];
    float xlx = bf2f((u16)u), xly = bf2f((u16)(u>>16));
    float ax = xlx + xrx + w*wex;
    float ay = xly + xry + w*wey;
    ax = ax > 0.f ? ax : 0.2f*ax;
    ay = ay > 0.f ? ay : 0.2f*ay;
    float c = ax*atx + ay*aty;
    c += __shfl_xor(c,1); c += __shfl_xor(c,2); c += __shfl_xor(c,4); c += __shfl_xor(c,8);
    float al = __expf(c - mx);
    den += al; a0 += al*xlx; a1 += al*xly;
  }
  float inv = 1.f/(den + 1e-16f);
  float o0 = a0*inv + bias[d0];
  float o1 = a1*inv + bias[d0+1];
  o0 = o0 > 0.f ? o0 : (__expf(o0) - 1.f);   // ELU
  o1 = o1 > 0.f ? o1 : (__expf(o1) - 1.f);
  hout[n*EMB + d0]   = o0;
  hout[n*EMB + d0+1] = o1;
}

// ---------------- GRU: 256 blocks x 1 batch row, 4 waves (1/SIMD) ----------------
// R15-verbatim schedule (the twice-passing one): swapped MFMA (A = Whh AGPR frags,
// B = broadcast h), ALL 12 MFMAs then gates 1-per-lane via static selects.
// Single barrier/step; counted vmcnt(1).

#define DECLW(nt) f32x4 wf_##nt##_0, wf_##nt##_1, wf_##nt##_2, wf_##nt##_3, \
                        wf_##nt##_4, wf_##nt##_5, wf_##nt##_6, wf_##nt##_7;

#define LDW1(nt,kt) { u16x8 wv = *(const u16x8*)(wr + (kt)*32 + lg*8); \
  wf_##nt##_##kt = __builtin_bit_cast(f32x4, wv); \
  asm volatile("" : "+a"(wf_##nt##_##kt)); }

#define LDW(nt) { int nrow = ((nt)>>2)*256 + wid*64 + ((nt)&3)*16 + lr; \
  const u16* wr = whb + (size_t)nrow*RH; \
  LDW1(nt,0) LDW1(nt,1) LDW1(nt,2) LDW1(nt,3) LDW1(nt,4) LDW1(nt,5) LDW1(nt,6) LDW1(nt,7) }

// D = A(AGPR wf) * B(VGPR h-broadcast) + D
#define MFMA1(acc, wf, hf) asm volatile( \
  "v_mfma_f32_16x16x32_bf16 %0, %1, %2, %0" : "+v"(acc) : "a"(wf), "v"(hf));

#define MST(kt) { \
  f32x4 hf = __builtin_bit_cast(f32x4, *(const u16x8*)(hrd + (kt)*32 + lg*8)); \
  MFMA1(acc0,  wf_0_##kt,  hf) MFMA1(acc1,  wf_1_##kt,  hf) \
  MFMA1(acc2,  wf_2_##kt,  hf) MFMA1(acc3,  wf_3_##kt,  hf) \
  MFMA1(acc4,  wf_4_##kt,  hf) MFMA1(acc5,  wf_5_##kt,  hf) \
  MFMA1(acc6,  wf_6_##kt,  hf) MFMA1(acc7,  wf_7_##kt,  hf) \
  MFMA1(acc8,  wf_8_##kt,  hf) MFMA1(acc9,  wf_9_##kt,  hf) \
  MFMA1(acc10, wf_10_##kt, hf) MFMA1(acc11, wf_11_##kt, hf) }

__global__ __launch_bounds__(256,1) __attribute__((amdgpu_waves_per_eu(1,1))) void k_gru(
    const u16* __restrict__ xgc, const u16* __restrict__ whb, const float* __restrict__ bhh,
    const int* __restrict__ lens, u16* __restrict__ hseq, float* __restrict__ hsave,
    int t0, int t1, int chk)
{
  int tid = threadIdx.x;
  int wid = tid >> 6, l = tid & 63;
  int lr = l & 15, lg = l >> 4;
  int b = blockIdx.x;                       // one batch row per block
  __shared__ __align__(16) u16 lds_h[2][256];    // 1 KB, double-buffered
  __shared__ __align__(16) u16 lds_xg[2][1024];  // 4 KB (768 used + 512B pad)

  int mylen = lens[b];
  int tend = mylen < t1 ? mylen : t1;
  int nsteps = tend - t0; if(nsteps < 0) nsteps = 0;

  // Whh bf16 A-fragments: 96 AGPR-pinned values (layout: row=lr, k=lg*8+e)
  DECLW(0) DECLW(1) DECLW(2)  DECLW(3)  DECLW(4)  DECLW(5)
  DECLW(6) DECLW(7) DECLW(8)  DECLW(9)  DECLW(10) DECLW(11)
  LDW(0) LDW(1) LDW(2)  LDW(3)  LDW(4)  LDW(5)
  LDW(6) LDW(7) LDW(8)  LDW(9)  LDW(10) LDW(11)

  // this lane's gate assignment: j = wid*64 + (lr>>2)*16 + lg*4 + (lr&3)
  int jt   = lr >> 2;
  int rsel = lr & 3;
  int j    = wid*64 + jt*16 + lg*4 + rsel;
  float bhR = bhh[      j];
  float bhZ = bhh[256 + j];
  float bhN = bhh[512 + j];

  // h init into lds_h[0] (linear, single row)
  {
    u16 v = 0;
    if(t0 > 0) v = f2bf(hsave[(size_t)b*RH + tid]);
    lds_h[0][tid] = v;
  }
  float hst = (t0>0) ? hsave[(size_t)b*RH + j] : 0.f;

  // staging: 96 granules of 16B; wave0 -> granules 0-63, wave1 -> 64-127 (96-127 pad)
  int g = (wid==0) ? l : (64 + (l & 31));   // wave1 lanes 32-63 duplicate 64-95 reads
  const u16* xsrc = xgc + ((size_t)b*chk)*G3 + g*8;
  int lwb = (wid==0) ? 0 : 512;             // wave LDS base in u16 units

  // prologue: stage t0 into buf0, full drain, publish
  if(nsteps > 0 && wid < 2)
    stage16(xsrc, &lds_xg[0][lwb], nullptr);
  xsrc += G3;
  asm volatile("s_waitcnt vmcnt(0)" ::: "memory");
  asm volatile("s_waitcnt lgkmcnt(0)" ::: "memory");
  __builtin_amdgcn_sched_barrier(0);
  __builtin_amdgcn_s_barrier();
  __builtin_amdgcn_sched_barrier(0);

  u16* outbase = hseq + ((size_t)b*NTT + t0)*RH;
  for(int s=0; s<nsteps; ++s){
    const u16* hrd = &lds_h[s&1][0];
    u16*       hwr = &lds_h[(s+1)&1][0];
    const u16* xgr = &lds_xg[s&1][0];
    int more = (s+1 < nsteps);

    // issue next-step stage early (lands during this step's compute)
    if(more && wid < 2)
      stage16(xsrc, &lds_xg[(s+1)&1][lwb], nullptr);
    xsrc += G3;

    // hg = Whh @ h  (A from AGPRs, B = broadcast h row; no masking needed)
    f32x4 acc0 = {}, acc1 = {}, acc2 = {}, acc3 = {}, acc4 = {}, acc5 = {},
          acc6 = {}, acc7 = {}, acc8 = {}, acc9 = {}, acc10 = {}, acc11 = {};
    MST(0) MST(1) MST(2) MST(3) MST(4) MST(5) MST(6) MST(7)

    // gates: 1 chain per lane (64/wave). acc rows replicated across cols.
    {
      f32x4 aR = seltile(acc0, acc1, acc2,  acc3,  jt);
      f32x4 aZ = seltile(acc4, acc5, acc6,  acc7,  jt);
      f32x4 aN = seltile(acc8, acc9, acc10, acc11, jt);
      float hr = self4(aR, rsel) + bhR;
      float hz = self4(aZ, rsel) + bhZ;
      float hn = self4(aN, rsel) + bhN;
      float xrv = bf2f(xgr[      j]);
      float xzv = bf2f(xgr[256 + j]);
      float xnv = bf2f(xgr[512 + j]);
      float rg = 1.f/(1.f + __expf(-(xrv + hr)));
      float zg = 1.f/(1.f + __expf(-(xzv + hz)));
      float nn = xnv + rg*hn;
      float tg = 1.f - 2.f/(__expf(2.f*nn) + 1.f);   // tanh
      float hv = (1.f - zg)*tg + zg*hst;
      hst = hv;
      u16 hb = f2bf(hv);
      hwr[j] = hb;
      outbase[j] = hb;
    }
    outbase += RH;

    if(more){
      asm volatile("s_waitcnt lgkmcnt(0)" ::: "memory");  // h[nxt] write + LDS reads done
      asm volatile("s_waitcnt vmcnt(1)" ::: "memory");    // stage load landed; store flies
      __builtin_amdgcn_sched_barrier(0);
      __builtin_amdgcn_s_barrier();                       // publish h[nxt] + xg[nxt]
      __builtin_amdgcn_sched_barrier(0);
    }
  }

  // zero-fill [max(tend,t0), t1) so hseq is fully written & deterministic
  {
    u16* zp = outbase;
    for(int t = (tend > t0 ? tend : t0); t < t1; ++t){
      zp[j] = 0;
      zp += RH;
    }
  }

  // save exact f32 state for next chunk
  hsave[(size_t)b*RH + j] = hst;
}

// ---------------- launcher ----------------
extern "C" void kernel_launch(void* const* d_in, const int* in_sizes, int n_in,
                              void* d_out, int out_size, void* d_ws, size_t ws_size,
                              hipStream_t stream){
  (void)in_sizes; (void)n_in; (void)out_size;
  const int*   skills = (const int*)d_in[0];
  const int*   resp   = (const int*)d_in[1];
  const int*   lens   = (const int*)d_in[2];
  const int*   eidx   = (const int*)d_in[3];
  const float* ew     = (const float*)d_in[4];
  const float* emb    = (const float*)d_in[5];
  const float* gW[2][7];
  for(int l2=0;l2<2;++l2) for(int j=0;j<7;++j) gW[l2][j] = (const float*)d_in[6 + l2*7 + j];
  const float* remb  = (const float*)d_in[20];
  const float* Wih   = (const float*)d_in[21];
  const float* Whh   = (const float*)d_in[22];
  const float* bih   = (const float*)d_in[23];
  const float* bhh   = (const float*)d_in[24];
  const float* projW = (const float*)d_in[25];
  const float* projb = (const float*)d_in[26];

  char* p = (char*)d_ws;
  size_t o = 0;
  auto take = [&](size_t bytes)->char*{ char* r = p + o; o = (o + bytes + 255) & ~(size_t)255; return r; };
  int*   deg  = (int*)  take(4*N_NODES);
  int*   fill = (int*)  take(4*N_NODES);
  float* wsum = (float*)take(4*N_NODES);
  size_t zbytes = o;                        // deg+fill+wsum zeroed each call
  int*   off   = (int*)  take(4*(N_NODES+1));
  int*   csrs  = (int*)  take(4*NE_TOT);
  float* csrw  = (float*)take(4*NE_TOT);
  u16*   xl    = (u16*)  take(2UL*N_NODES*EMB);
  u16*   xr    = (u16*)  take(2UL*N_NODES*EMB);
  float* h1    = (float*)take(4UL*N_NODES*EMB);
  float* hsave = (float*)take(4UL*NB*RH);
  u16*   wb    = (u16*)  take(2UL*WB_TOT);
  u16*   hseq  = (u16*)  take(2UL*NB*NTT*RH);
  u16*   xemb  = (u16*)  take(2UL*NB*NTT*EMB);
  size_t fixed_end = o;
  // xg chunk length: largest of {200,100,50,25} that fits ws_size
  int chk = 200;
  while(chk > 25 && fixed_end + 2UL*NB*(size_t)chk*G3 > ws_size) chk /= 2;
  u16*   xgc  = (u16*)  take(2UL*NB*(size_t)chk*G3);

  const u16* wb_g0l  = wb;
  const u16* wb_g0r  = wb + 16384;
  const u16* wb_g1l  = wb + 32768;
  const u16* wb_g1r  = wb + 49152;
  const u16* wb_wih  = wb + 65536;
  const u16* wb_whh  = wb + 163840;
  const u16* wb_proj = wb + 360448;

  float* outP = (float*)d_out;                     // h_proj [256,200,128] f32
  float* outE = outP + (size_t)NB*NTT*EMB;         // skill_embs [10000,128] f32

  hipMemsetAsync(d_ws, 0, zbytes, stream);
  k_deg<<<(NE+255)/256, 256, 0, stream>>>(eidx, ew, deg, wsum);
  k_scan<<<1, 1024, 0, stream>>>(deg, wsum, off);
  k_scatter<<<(NE_TOT+255)/256, 256, 0, stream>>>(eidx, ew, wsum, off, fill, csrs, csrw);
  k_cvtall<<<(WB_TOT+255)/256, 256, 0, stream>>>(gW[0][0], gW[0][2], gW[1][0], gW[1][2],
                                                 Wih, Whh, projW, (u16*)wb);

  dim3 gN((N_NODES+127)/128, EMB/64);
  // layer 0 (A = emb f32 -> xl/xr bf16)
  k_gemm<0,false><<<gN, 256, 0, stream>>>(emb, wb_g0l, gW[0][1], xl, N_NODES, EMB, EMB,
                                 0, 0, nullptr);
  k_gemm<0,false><<<gN, 256, 0, stream>>>(emb, wb_g0r, gW[0][3], xr, N_NODES, EMB, EMB,
                                 0, 0, nullptr);
  k_attn<<<N_NODES/4, 256, 0, stream>>>(off, csrs, csrw, xl, xr, gW[0][4], gW[0][5], gW[0][6], h1);
  // layer 1 (A = h1 f32)
  k_gemm<0,false><<<gN, 256, 0, stream>>>(h1, wb_g1l, gW[1][1], xl, N_NODES, EMB, EMB,
                                 0, 0, nullptr);
  k_gemm<0,false><<<gN, 256, 0, stream>>>(h1, wb_g1r, gW[1][3], xr, N_NODES, EMB, EMB,
                                 0, 0, nullptr);
  k_attn<<<N_NODES/4, 256, 0, stream>>>(off, csrs, csrw, xl, xr, gW[1][4], gW[1][5], gW[1][6], outE);

  // gather once: xemb = bf16(skill_embs[skills] + resp_emb[resp])
  k_gather<<<(NB*NTT*EMB/8 + 255)/256, 256, 0, stream>>>(outE, remb, skills, resp, xemb);

  // chunked: xg = xemb @ Wih^T + bih (bf16 A, bf16 W), then GRU chunk
  for(int t0=0; t0<NTT; t0+=chk){
    k_gemm<3,false><<<dim3(NB*chk/128, G3/64), 256, 0, stream>>>(xemb, wb_wih, bih, xgc,
                                 NB*chk, G3, EMB, t0, chk, nullptr);
    k_gru<<<NB, 256, 0, stream>>>(xgc, wb_whh, bhh, lens, hseq, hsave, t0, t0+chk, chk);
  }
  // proj: A = hseq bf16, out f32 (+ lens mask; hseq rows t>=len are exact zeros)
  k_gemm<2,true><<<dim3(NB*NTT/128, EMB/64), 256, 0, stream>>>(hseq, wb_proj, projb, outP,
                                 NB*NTT, EMB, RH, 0, 0, lens);
}

// Round 18
// 666.804 us; speedup vs baseline: 2.7717x; 1.0190x over previous
//
#include <hip/hip_runtime.h>

#define N_NODES 10000
#define EMB     128
#define NE      320000
#define NE_TOT  330000   // + one self-loop per node
#define NB      256
#define NTT     200
#define RH      256
#define G3      768

typedef unsigned short u16;
typedef u16    u16x8  __attribute__((ext_vector_type(8)));
typedef __bf16 bf16x8 __attribute__((ext_vector_type(8)));
typedef float  f32x4  __attribute__((ext_vector_type(4)));

static __device__ __forceinline__ float bf2f(u16 u){
  unsigned int x = ((unsigned int)u) << 16;
  return __builtin_bit_cast(float, x);
}
static __device__ __forceinline__ u16 f2bf(float f){
  unsigned int x = __builtin_bit_cast(unsigned int, f);
  x += 0x7fffu + ((x >> 16) & 1u);
  return (u16)(x >> 16);
}

// async global->LDS, 16B per lane; lds dest must be the WAVE base (HW adds lane*16)
static __device__ __forceinline__ void stage16(const u16* g, u16* lds_wavebase, u16* lds_lane){
#if __has_builtin(__builtin_amdgcn_global_load_lds)
  __builtin_amdgcn_global_load_lds(
      (const __attribute__((address_space(1))) unsigned int*)g,
      (__attribute__((address_space(3))) unsigned int*)lds_wavebase, 16, 0, 0);
  (void)lds_lane;
#else
  *(u16x8*)lds_lane = *(const u16x8*)g;
#endif
}

// static-index selects (rule #20: no runtime-indexed register arrays)
static __device__ __forceinline__ float self4(f32x4 v, int r){
  float lo = (r&1) ? v[1] : v[0];
  float hi = (r&1) ? v[3] : v[2];
  return (r&2) ? hi : lo;
}
static __device__ __forceinline__ f32x4 seltile(f32x4 a, f32x4 b, f32x4 c, f32x4 d, int jt){
  f32x4 r;
  #pragma unroll
  for(int e=0;e<4;++e){
    float ab = (jt&1) ? b[e] : a[e];
    float cd = (jt&1) ? d[e] : c[e];
    r[e] = (jt&2) ? cd : ab;
  }
  return r;
}

// ---------------- CSR build ----------------
__global__ void k_deg(const int* __restrict__ eidx, const float* __restrict__ ew,
                      int* __restrict__ deg, float* __restrict__ wsum){
  int i = blockIdx.x*256 + threadIdx.x;
  if(i >= NE) return;
  int d = eidx[NE + i];
  atomicAdd(&deg[d], 1);
  atomicAdd(&wsum[d], ew[i]);
}

__global__ __launch_bounds__(1024) void k_scan(const int* __restrict__ deg,
                      float* __restrict__ wsum, int* __restrict__ off){
  __shared__ int part[1024];
  int tid = threadIdx.x;
  int n0 = tid*10;
  int s = 0;
  for(int i=0;i<10;++i){ int n=n0+i; if(n<N_NODES) s += deg[n]+1; }
  part[tid] = s;
  for(int i=0;i<10;++i){
    int n=n0+i;
    if(n<N_NODES){ int d=deg[n]; wsum[n] = wsum[n] / (float)(d>1?d:1); }
  }
  __syncthreads();
  for(int st=1; st<1024; st<<=1){
    int v = (tid>=st) ? part[tid-st] : 0;
    __syncthreads();
    part[tid] += v;
    __syncthreads();
  }
  int base = tid ? part[tid-1] : 0;
  for(int i=0;i<10;++i){ int n=n0+i; if(n<N_NODES){ off[n]=base; base += deg[n]+1; } }
  if(tid==999) off[N_NODES] = base;
}

__global__ void k_scatter(const int* __restrict__ eidx, const float* __restrict__ ew,
                          const float* __restrict__ la, const int* __restrict__ off,
                          int* __restrict__ fill, int* __restrict__ csrs, float* __restrict__ csrw){
  int i = blockIdx.x*256 + threadIdx.x;
  if(i >= NE_TOT) return;
  int s, d; float w;
  if(i < NE){ s = eidx[i]; d = eidx[NE+i]; w = ew[i]; }
  else      { int n = i-NE; s=n; d=n; w = la[n]; }   // self-loop, weight = mean incoming
  int pos = off[d] + atomicAdd(&fill[d], 1);
  csrs[pos] = s; csrw[pos] = w;
}

// ---------------- weights + emb f32 -> bf16, packed (once per call) ----------------
// layout: g0l@0, g0r@16384, g1l@32768, g1r@49152, wih@65536, whh@163840,
//         proj@360448, emb@393216
#define WB_W   393216
#define WB_TOT (WB_W + N_NODES*EMB)
__global__ __launch_bounds__(256) void k_cvtall(
    const float* __restrict__ g0l, const float* __restrict__ g0r,
    const float* __restrict__ g1l, const float* __restrict__ g1r,
    const float* __restrict__ wih, const float* __restrict__ whh,
    const float* __restrict__ pw, const float* __restrict__ emb,
    u16* __restrict__ wb){
  int i = blockIdx.x*256 + threadIdx.x;
  if(i >= WB_TOT) return;
  float v;
  if(i < 65536){
    int seg = i >> 14, r = i & 16383;
    const float* s = (seg==0) ? g0l : (seg==1) ? g0r : (seg==2) ? g1l : g1r;
    v = s[r];
  } else if(i < 163840){ v = wih[i - 65536]; }
  else if(i < 360448){ v = whh[i - 163840]; }
  else if(i < WB_W)  { v = pw [i - 360448]; }
  else               { v = emb[i - WB_W]; }
  wb[i] = f2bf(v);
}

// ---------------- gather: xemb = bf16(skill_embs[skills] + resp_emb[resp]) ----------------
__global__ __launch_bounds__(256) void k_gather(
    const float* __restrict__ embN, const float* __restrict__ remb,
    const int* __restrict__ skills, const int* __restrict__ resp,
    u16* __restrict__ xemb){
  int i = blockIdx.x*256 + threadIdx.x;           // one per 8 elems
  if(i >= NB*NTT*EMB/8) return;
  int row = i >> 4;                               // 16 groups of 8 per row
  int g8  = (i & 15) * 8;
  const float* ar = embN + (size_t)skills[row]*EMB + g8;
  const float* rr = remb + (size_t)resp[row]*EMB + g8;
  u16x8 v;
  #pragma unroll
  for(int e=0;e<8;++e) v[e] = f2bf(ar[e] + rr[e]);
  *(u16x8*)(xemb + (size_t)row*EMB + g8) = v;
}

// ---------------- MFMA GEMM: C = A @ W^T + bias (A,W bf16) ----------------
// AMODE: 2 = A bf16 [M,K]; 3 = A bf16 with chunk row map (row -> b*NTT+t0+row%chk).
// MI: rows per wave = MI*16 (block = MI*64 rows).
// lens != null (proj): row=(b*NTT+t), t>=lens[b] -> bias only.
template<int AMODE, bool OUTF32, int MI>
__global__ __launch_bounds__(256) void k_gemm(
    const u16* __restrict__ Av, const u16* __restrict__ W, const float* __restrict__ bias,
    void* __restrict__ out,
    int M, int N, int K,
    int t0, int chk,
    const int* __restrict__ lens)
{
  int tid = threadIdx.x;
  int wid = tid >> 6, l = tid & 63;
  int lr = l & 15, lg = l >> 4;
  int bm = blockIdx.x*(MI*64) + wid*(MI*16);
  int bn = blockIdx.y*64;
  f32x4 acc[MI][4] = {};
  int nk = K >> 5;
  for(int kt=0; kt<nk; ++kt){
    int k0 = kt*32 + lg*8;
    bf16x8 af[MI];
    #pragma unroll
    for(int mi=0; mi<MI; ++mi){
      int row = bm + mi*16 + lr;
      u16x8 v = {0,0,0,0,0,0,0,0};
      if(row < M){
        if constexpr(AMODE == 3){
          int b = row / chk, tt = row - b*chk;
          int arow = b*NTT + t0 + tt;
          v = *(const u16x8*)(Av + (size_t)arow*K + k0);
        } else {
          v = *(const u16x8*)(Av + (size_t)row*K + k0);
        }
      }
      af[mi] = __builtin_bit_cast(bf16x8, v);
    }
    #pragma unroll
    for(int nt=0; nt<4; ++nt){
      int col = bn + nt*16 + lr;
      u16x8 wv = *(const u16x8*)(W + (size_t)col*K + k0);
      bf16x8 bfr = __builtin_bit_cast(bf16x8, wv);
      #pragma unroll
      for(int mi=0; mi<MI; ++mi)
        acc[mi][nt] = __builtin_amdgcn_mfma_f32_16x16x32_bf16(af[mi], bfr, acc[mi][nt], 0,0,0);
    }
  }
  #pragma unroll
  for(int mi=0; mi<MI; ++mi){
    #pragma unroll
    for(int nt=0; nt<4; ++nt){
      int col = bn + nt*16 + lr;
      float bc = bias[col];
      #pragma unroll
      for(int r=0; r<4; ++r){
        int row = bm + mi*16 + lg*4 + r;
        if(row >= M) continue;
        float v = acc[mi][nt][r] + bc;
        if(lens){ int b = row/NTT; int t = row - b*NTT; if(t >= lens[b]) v = bc; }
        if constexpr(OUTF32) ((float*)out)[(size_t)row*N + col] = v;
        else                 ((u16*) out)[(size_t)row*N + col] = f2bf(v);
      }
    }
  }
}

// ---------------- GATv2 attention + aggregate + bias + ELU ----------------
// BF16OUT: write bf16 (intermediate h1) else f32 (skill_embs output)
template<bool BF16OUT>
__global__ __launch_bounds__(256) void k_attn(
    const int* __restrict__ off, const int* __restrict__ csrs, const float* __restrict__ csrw,
    const u16* __restrict__ xl, const u16* __restrict__ xr,
    const float* __restrict__ We, const float* __restrict__ att, const float* __restrict__ bias,
    float* __restrict__ houtF, u16* __restrict__ houtB)
{
  int wid = threadIdx.x >> 6, l = threadIdx.x & 63;
  int n = blockIdx.x*4 + wid;
  int d0 = 2*l;
  const unsigned int* xl2 = (const unsigned int*)xl;
  unsigned int xru = ((const unsigned int*)xr)[n*64 + l];
  float xrx = bf2f((u16)xru), xry = bf2f((u16)(xru>>16));
  float wex = We[d0],  wey = We[d0+1];
  float atx = att[d0], aty = att[d0+1];
  int p0 = off[n], p1 = off[n+1];
  float mx = -1e30f;
  for(int p=p0; p<p1; ++p){
    int s = csrs[p]; float w = csrw[p];
    unsigned int u = xl2[s*64 + l];
    float ax = bf2f((u16)u)       + xrx + w*wex;
    float ay = bf2f((u16)(u>>16)) + xry + w*wey;
    ax = ax > 0.f ? ax : 0.2f*ax;
    ay = ay > 0.f ? ay : 0.2f*ay;
    float c = ax*atx + ay*aty;
    c += __shfl_xor(c,1); c += __shfl_xor(c,2); c += __shfl_xor(c,4); c += __shfl_xor(c,8);
    mx = fmaxf(mx, c);
  }
  float den = 0.f, a0 = 0.f, a1 = 0.f;
  for(int p=p0; p<p1; ++p){
    int s = csrs[p]; float w = csrw[p];
    unsigned int u = xl2[s*64 + l];
    float xlx = bf2f((u16)u), xly = bf2f((u16)(u>>16));
    float ax = xlx + xrx + w*wex;
    float ay = xly + xry + w*wey;
    ax = ax > 0.f ? ax : 0.2f*ax;
    ay = ay > 0.f ? ay : 0.2f*ay;
    float c = ax*atx + ay*aty;
    c += __shfl_xor(c,1); c += __shfl_xor(c,2); c += __shfl_xor(c,4); c += __shfl_xor(c,8);
    float al = __expf(c - mx);
    den += al; a0 += al*xlx; a1 += al*xly;
  }
  float inv = 1.f/(den + 1e-16f);
  float o0 = a0*inv + bias[d0];
  float o1 = a1*inv + bias[d0+1];
  o0 = o0 > 0.f ? o0 : (__expf(o0) - 1.f);   // ELU
  o1 = o1 > 0.f ? o1 : (__expf(o1) - 1.f);
  if constexpr(BF16OUT){
    houtB[n*EMB + d0]   = f2bf(o0);
    houtB[n*EMB + d0+1] = f2bf(o1);
  } else {
    houtF[n*EMB + d0]   = o0;
    houtF[n*EMB + d0+1] = o1;
  }
}

// ---------------- GRU: 256 blocks x 1 batch row, 4 waves (1/SIMD) ----------------
// R15/R17-verbatim schedule (the passing one): swapped MFMA (A = Whh AGPR frags,
// B = broadcast h), ALL 12 MFMAs then gates 1-per-lane via static selects.
// Single barrier/step; counted vmcnt(1). DO NOT reorder (R16 failure).

#define DECLW(nt) f32x4 wf_##nt##_0, wf_##nt##_1, wf_##nt##_2, wf_##nt##_3, \
                        wf_##nt##_4, wf_##nt##_5, wf_##nt##_6, wf_##nt##_7;

#define LDW1(nt,kt) { u16x8 wv = *(const u16x8*)(wr + (kt)*32 + lg*8); \
  wf_##nt##_##kt = __builtin_bit_cast(f32x4, wv); \
  asm volatile("" : "+a"(wf_##nt##_##kt)); }

#define LDW(nt) { int nrow = ((nt)>>2)*256 + wid*64 + ((nt)&3)*16 + lr; \
  const u16* wr = whb + (size_t)nrow*RH; \
  LDW1(nt,0) LDW1(nt,1) LDW1(nt,2) LDW1(nt,3) LDW1(nt,4) LDW1(nt,5) LDW1(nt,6) LDW1(nt,7) }

// D = A(AGPR wf) * B(VGPR h-broadcast) + D
#define MFMA1(acc, wf, hf) asm volatile( \
  "v_mfma_f32_16x16x32_bf16 %0, %1, %2, %0" : "+v"(acc) : "a"(wf), "v"(hf));

#define MST(kt) { \
  f32x4 hf = __builtin_bit_cast(f32x4, *(const u16x8*)(hrd + (kt)*32 + lg*8)); \
  MFMA1(acc0,  wf_0_##kt,  hf) MFMA1(acc1,  wf_1_##kt,  hf) \
  MFMA1(acc2,  wf_2_##kt,  hf) MFMA1(acc3,  wf_3_##kt,  hf) \
  MFMA1(acc4,  wf_4_##kt,  hf) MFMA1(acc5,  wf_5_##kt,  hf) \
  MFMA1(acc6,  wf_6_##kt,  hf) MFMA1(acc7,  wf_7_##kt,  hf) \
  MFMA1(acc8,  wf_8_##kt,  hf) MFMA1(acc9,  wf_9_##kt,  hf) \
  MFMA1(acc10, wf_10_##kt, hf) MFMA1(acc11, wf_11_##kt, hf) }

__global__ __launch_bounds__(256,1) __attribute__((amdgpu_waves_per_eu(1,1))) void k_gru(
    const u16* __restrict__ xgc, const u16* __restrict__ whb, const float* __restrict__ bhh,
    const int* __restrict__ lens, u16* __restrict__ hseq, float* __restrict__ hsave,
    int t0, int t1, int chk)
{
  int tid = threadIdx.x;
  int wid = tid >> 6, l = tid & 63;
  int lr = l & 15, lg = l >> 4;
  int b = blockIdx.x;                       // one batch row per block
  __shared__ __align__(16) u16 lds_h[2][256];    // 1 KB, double-buffered
  __shared__ __align__(16) u16 lds_xg[2][1024];  // 4 KB (768 used + 512B pad)

  int mylen = lens[b];
  int tend = mylen < t1 ? mylen : t1;
  int nsteps = tend - t0; if(nsteps < 0) nsteps = 0;

  // Whh bf16 A-fragments: 96 AGPR-pinned values (layout: row=lr, k=lg*8+e)
  DECLW(0) DECLW(1) DECLW(2)  DECLW(3)  DECLW(4)  DECLW(5)
  DECLW(6) DECLW(7) DECLW(8)  DECLW(9)  DECLW(10) DECLW(11)
  LDW(0) LDW(1) LDW(2)  LDW(3)  LDW(4)  LDW(5)
  LDW(6) LDW(7) LDW(8)  LDW(9)  LDW(10) LDW(11)

  // this lane's gate assignment: j = wid*64 + (lr>>2)*16 + lg*4 + (lr&3)
  int jt   = lr >> 2;
  int rsel = lr & 3;
  int j    = wid*64 + jt*16 + lg*4 + rsel;
  float bhR = bhh[      j];
  float bhZ = bhh[256 + j];
  float bhN = bhh[512 + j];

  // h init into lds_h[0] (linear, single row)
  {
    u16 v = 0;
    if(t0 > 0) v = f2bf(hsave[(size_t)b*RH + tid]);
    lds_h[0][tid] = v;
  }
  float hst = (t0>0) ? hsave[(size_t)b*RH + j] : 0.f;

  // staging: 96 granules of 16B; wave0 -> granules 0-63, wave1 -> 64-127 (96-127 pad)
  int g = (wid==0) ? l : (64 + (l & 31));   // wave1 lanes 32-63 duplicate 64-95 reads
  const u16* xsrc = xgc + ((size_t)b*chk)*G3 + g*8;
  int lwb = (wid==0) ? 0 : 512;             // wave LDS base in u16 units

  // prologue: stage t0 into buf0, full drain, publish
  if(nsteps > 0 && wid < 2)
    stage16(xsrc, &lds_xg[0][lwb], nullptr);
  xsrc += G3;
  asm volatile("s_waitcnt vmcnt(0)" ::: "memory");
  asm volatile("s_waitcnt lgkmcnt(0)" ::: "memory");
  __builtin_amdgcn_sched_barrier(0);
  __builtin_amdgcn_s_barrier();
  __builtin_amdgcn_sched_barrier(0);

  u16* outbase = hseq + ((size_t)b*NTT + t0)*RH;
  for(int s=0; s<nsteps; ++s){
    const u16* hrd = &lds_h[s&1][0];
    u16*       hwr = &lds_h[(s+1)&1][0];
    const u16* xgr = &lds_xg[s&1][0];
    int more = (s+1 < nsteps);

    // issue next-step stage early (lands during this step's compute)
    if(more && wid < 2)
      stage16(xsrc, &lds_xg[(s+1)&1][lwb], nullptr);
    xsrc += G3;

    // hg = Whh @ h  (A from AGPRs, B = broadcast h row; no masking needed)
    f32x4 acc0 = {}, acc1 = {}, acc2 = {}, acc3 = {}, acc4 = {}, acc5 = {},
          acc6 = {}, acc7 = {}, acc8 = {}, acc9 = {}, acc10 = {}, acc11 = {};
    MST(0) MST(1) MST(2) MST(3) MST(4) MST(5) MST(6) MST(7)

    // gates: 1 chain per lane (64/wave). acc rows replicated across cols.
    {
      f32x4 aR = seltile(acc0, acc1, acc2,  acc3,  jt);
      f32x4 aZ = seltile(acc4, acc5, acc6,  acc7,  jt);
      f32x4 aN = seltile(acc8, acc9, acc10, acc11, jt);
      float hr = self4(aR, rsel) + bhR;
      float hz = self4(aZ, rsel) + bhZ;
      float hn = self4(aN, rsel) + bhN;
      float xrv = bf2f(xgr[      j]);
      float xzv = bf2f(xgr[256 + j]);
      float xnv = bf2f(xgr[512 + j]);
      float rg = 1.f/(1.f + __expf(-(xrv + hr)));
      float zg = 1.f/(1.f + __expf(-(xzv + hz)));
      float nn = xnv + rg*hn;
      float tg = 1.f - 2.f/(__expf(2.f*nn) + 1.f);   // tanh
      float hv = (1.f - zg)*tg + zg*hst;
      hst = hv;
      u16 hb = f2bf(hv);
      hwr[j] = hb;
      outbase[j] = hb;
    }
    outbase += RH;

    if(more){
      asm volatile("s_waitcnt lgkmcnt(0)" ::: "memory");  // h[nxt] write + LDS reads done
      asm volatile("s_waitcnt vmcnt(1)" ::: "memory");    // stage load landed; store flies
      __builtin_amdgcn_sched_barrier(0);
      __builtin_amdgcn_s_barrier();                       // publish h[nxt] + xg[nxt]
      __builtin_amdgcn_sched_barrier(0);
    }
  }

  // zero-fill [max(tend,t0), t1) so hseq is fully written & deterministic
  {
    u16* zp = outbase;
    for(int t = (tend > t0 ? tend : t0); t < t1; ++t){
      zp[j] = 0;
      zp += RH;
    }
  }

  // save exact f32 state for next chunk
  hsave[(size_t)b*RH + j] = hst;
}

// ---------------- launcher ----------------
extern "C" void kernel_launch(void* const* d_in, const int* in_sizes, int n_in,
                              void* d_out, int out_size, void* d_ws, size_t ws_size,
                              hipStream_t stream){
  (void)in_sizes; (void)n_in; (void)out_size;
  const int*   skills = (const int*)d_in[0];
  const int*   resp   = (const int*)d_in[1];
  const int*   lens   = (const int*)d_in[2];
  const int*   eidx   = (const int*)d_in[3];
  const float* ew     = (const float*)d_in[4];
  const float* emb    = (const float*)d_in[5];
  const float* gW[2][7];
  for(int l2=0;l2<2;++l2) for(int j=0;j<7;++j) gW[l2][j] = (const float*)d_in[6 + l2*7 + j];
  const float* remb  = (const float*)d_in[20];
  const float* Wih   = (const float*)d_in[21];
  const float* Whh   = (const float*)d_in[22];
  const float* bih   = (const float*)d_in[23];
  const float* bhh   = (const float*)d_in[24];
  const float* projW = (const float*)d_in[25];
  const float* projb = (const float*)d_in[26];

  char* p = (char*)d_ws;
  size_t o = 0;
  auto take = [&](size_t bytes)->char*{ char* r = p + o; o = (o + bytes + 255) & ~(size_t)255; return r; };
  int*   deg  = (int*)  take(4*N_NODES);
  int*   fill = (int*)  take(4*N_NODES);
  float* wsum = (float*)take(4*N_NODES);
  size_t zbytes = o;                        // deg+fill+wsum zeroed each call
  int*   off   = (int*)  take(4*(N_NODES+1));
  int*   csrs  = (int*)  take(4*NE_TOT);
  float* csrw  = (float*)take(4*NE_TOT);
  u16*   xl    = (u16*)  take(2UL*N_NODES*EMB);
  u16*   xr    = (u16*)  take(2UL*N_NODES*EMB);
  u16*   h1b   = (u16*)  take(2UL*N_NODES*EMB);
  float* hsave = (float*)take(4UL*NB*RH);
  u16*   wb    = (u16*)  take(2UL*WB_TOT);
  u16*   hseq  = (u16*)  take(2UL*NB*NTT*RH);
  u16*   xemb  = (u16*)  take(2UL*NB*NTT*EMB);
  size_t fixed_end = o;
  // xg chunk length: largest of {200,100,50,25} that fits ws_size
  int chk = 200;
  while(chk > 25 && fixed_end + 2UL*NB*(size_t)chk*G3 > ws_size) chk /= 2;
  u16*   xgc  = (u16*)  take(2UL*NB*(size_t)chk*G3);

  const u16* wb_g0l  = wb;
  const u16* wb_g0r  = wb + 16384;
  const u16* wb_g1l  = wb + 32768;
  const u16* wb_g1r  = wb + 49152;
  const u16* wb_wih  = wb + 65536;
  const u16* wb_whh  = wb + 163840;
  const u16* wb_proj = wb + 360448;
  const u16* wb_emb  = wb + WB_W;

  float* outP = (float*)d_out;                     // h_proj [256,200,128] f32
  float* outE = outP + (size_t)NB*NTT*EMB;         // skill_embs [10000,128] f32

  hipMemsetAsync(d_ws, 0, zbytes, stream);
  k_deg<<<(NE+255)/256, 256, 0, stream>>>(eidx, ew, deg, wsum);
  k_scan<<<1, 1024, 0, stream>>>(deg, wsum, off);
  k_scatter<<<(NE_TOT+255)/256, 256, 0, stream>>>(eidx, ew, wsum, off, fill, csrs, csrw);
  k_cvtall<<<(WB_TOT+255)/256, 256, 0, stream>>>(gW[0][0], gW[0][2], gW[1][0], gW[1][2],
                                                 Wih, Whh, projW, emb, (u16*)wb);

  dim3 gN((N_NODES+127)/128, EMB/64);
  // layer 0 (A = emb bf16 -> xl/xr bf16)
  k_gemm<2,false,2><<<gN, 256, 0, stream>>>(wb_emb, wb_g0l, gW[0][1], xl, N_NODES, EMB, EMB,
                                 0, 0, nullptr);
  k_gemm<2,false,2><<<gN, 256, 0, stream>>>(wb_emb, wb_g0r, gW[0][3], xr, N_NODES, EMB, EMB,
                                 0, 0, nullptr);
  k_attn<true><<<N_NODES/4, 256, 0, stream>>>(off, csrs, csrw, xl, xr,
                                 gW[0][4], gW[0][5], gW[0][6], nullptr, h1b);
  // layer 1 (A = h1 bf16)
  k_gemm<2,false,2><<<gN, 256, 0, stream>>>(h1b, wb_g1l, gW[1][1], xl, N_NODES, EMB, EMB,
                                 0, 0, nullptr);
  k_gemm<2,false,2><<<gN, 256, 0, stream>>>(h1b, wb_g1r, gW[1][3], xr, N_NODES, EMB, EMB,
                                 0, 0, nullptr);
  k_attn<false><<<N_NODES/4, 256, 0, stream>>>(off, csrs, csrw, xl, xr,
                                 gW[1][4], gW[1][5], gW[1][6], outE, nullptr);

  // gather once: xemb = bf16(skill_embs[skills] + resp_emb[resp])
  k_gather<<<(NB*NTT*EMB/8 + 255)/256, 256, 0, stream>>>(outE, remb, skills, resp, xemb);

  // chunked: xg = xemb @ Wih^T + bih (bf16, MI=4), then GRU chunk
  for(int t0=0; t0<NTT; t0+=chk){
    k_gemm<3,false,4><<<dim3(NB*chk/256, G3/64), 256, 0, stream>>>(xemb, wb_wih, bih, xgc,
                                 NB*chk, G3, EMB, t0, chk, nullptr);
    k_gru<<<NB, 256, 0, stream>>>(xgc, wb_whh, bhh, lens, hseq, hsave, t0, t0+chk, chk);
  }
  // proj: A = hseq bf16 (MI=4), out f32 (+ lens mask; hseq rows t>=len are zeros)
  k_gemm<2,true,4><<<dim3(NB*NTT/256, EMB/64), 256, 0, stream>>>(hseq, wb_proj, projb, outP,
                                 NB*NTT, EMB, RH, 0, 0, lens);
}

// Round 19
// 656.252 us; speedup vs baseline: 2.8162x; 1.0161x over previous
//
#include <hip/hip_runtime.h>

#define N_NODES 10000
#define EMB     128
#define NE      320000
#define NE_TOT  330000   // + one self-loop per node
#define NB      256
#define NTT     200
#define RH      256
#define G3      768

typedef unsigned short u16;
typedef u16    u16x8  __attribute__((ext_vector_type(8)));
typedef __bf16 bf16x8 __attribute__((ext_vector_type(8)));
typedef float  f32x4  __attribute__((ext_vector_type(4)));

static __device__ __forceinline__ float bf2f(u16 u){
  unsigned int x = ((unsigned int)u) << 16;
  return __builtin_bit_cast(float, x);
}
static __device__ __forceinline__ u16 f2bf(float f){
  unsigned int x = __builtin_bit_cast(unsigned int, f);
  x += 0x7fffu + ((x >> 16) & 1u);
  return (u16)(x >> 16);
}

// async global->LDS, 16B per lane; lds dest must be the WAVE base (HW adds lane*16)
static __device__ __forceinline__ void stage16(const u16* g, u16* lds_wavebase, u16* lds_lane){
#if __has_builtin(__builtin_amdgcn_global_load_lds)
  __builtin_amdgcn_global_load_lds(
      (const __attribute__((address_space(1))) unsigned int*)g,
      (__attribute__((address_space(3))) unsigned int*)lds_wavebase, 16, 0, 0);
  (void)lds_lane;
#else
  *(u16x8*)lds_lane = *(const u16x8*)g;
#endif
}

// static-index selects (rule #20: no runtime-indexed register arrays)
static __device__ __forceinline__ float self4(f32x4 v, int r){
  float lo = (r&1) ? v[1] : v[0];
  float hi = (r&1) ? v[3] : v[2];
  return (r&2) ? hi : lo;
}
static __device__ __forceinline__ f32x4 seltile(f32x4 a, f32x4 b, f32x4 c, f32x4 d, int jt){
  f32x4 r;
  #pragma unroll
  for(int e=0;e<4;++e){
    float ab = (jt&1) ? b[e] : a[e];
    float cd = (jt&1) ? d[e] : c[e];
    r[e] = (jt&2) ? cd : ab;
  }
  return r;
}

// ---------------- fused: edge-degree histogram + all f32->bf16 preconversion ----------------
// wb layout: g0l@0, g0r@16384, g1l@32768, g1r@49152, wih@65536, whh@163840,
//            proj@360448, emb@393216
#define WB_W   393216
#define WB_TOT (WB_W + N_NODES*EMB)
#define NDEG_BLK ((NE + 255)/256)
#define NCVT_BLK ((WB_TOT + 255)/256)
__global__ __launch_bounds__(256) void k_prep(
    const int* __restrict__ eidx, const float* __restrict__ ew,
    int* __restrict__ deg, float* __restrict__ wsum,
    const float* __restrict__ g0l, const float* __restrict__ g0r,
    const float* __restrict__ g1l, const float* __restrict__ g1r,
    const float* __restrict__ wih, const float* __restrict__ whh,
    const float* __restrict__ pw, const float* __restrict__ emb,
    u16* __restrict__ wb)
{
  int bid = blockIdx.x;
  if(bid < NDEG_BLK){
    int i = bid*256 + threadIdx.x;
    if(i >= NE) return;
    int d = eidx[NE + i];
    atomicAdd(&deg[d], 1);
    atomicAdd(&wsum[d], ew[i]);
  } else {
    int i = (bid - NDEG_BLK)*256 + threadIdx.x;
    if(i >= WB_TOT) return;
    float v;
    if(i < 65536){
      int seg = i >> 14, r = i & 16383;
      const float* s = (seg==0) ? g0l : (seg==1) ? g0r : (seg==2) ? g1l : g1r;
      v = s[r];
    } else if(i < 163840){ v = wih[i - 65536]; }
    else if(i < 360448){ v = whh[i - 163840]; }
    else if(i < WB_W)  { v = pw [i - 360448]; }
    else               { v = emb[i - WB_W]; }
    wb[i] = f2bf(v);
  }
}

__global__ __launch_bounds__(1024) void k_scan(const int* __restrict__ deg,
                      float* __restrict__ wsum, int* __restrict__ off){
  __shared__ int part[1024];
  int tid = threadIdx.x;
  int n0 = tid*10;
  int s = 0;
  for(int i=0;i<10;++i){ int n=n0+i; if(n<N_NODES) s += deg[n]+1; }
  part[tid] = s;
  for(int i=0;i<10;++i){
    int n=n0+i;
    if(n<N_NODES){ int d=deg[n]; wsum[n] = wsum[n] / (float)(d>1?d:1); }
  }
  __syncthreads();
  for(int st=1; st<1024; st<<=1){
    int v = (tid>=st) ? part[tid-st] : 0;
    __syncthreads();
    part[tid] += v;
    __syncthreads();
  }
  int base = tid ? part[tid-1] : 0;
  for(int i=0;i<10;++i){ int n=n0+i; if(n<N_NODES){ off[n]=base; base += deg[n]+1; } }
  if(tid==999) off[N_NODES] = base;
}

__global__ void k_scatter(const int* __restrict__ eidx, const float* __restrict__ ew,
                          const float* __restrict__ la, const int* __restrict__ off,
                          int* __restrict__ fill, int* __restrict__ csrs, float* __restrict__ csrw){
  int i = blockIdx.x*256 + threadIdx.x;
  if(i >= NE_TOT) return;
  int s, d; float w;
  if(i < NE){ s = eidx[i]; d = eidx[NE+i]; w = ew[i]; }
  else      { int n = i-NE; s=n; d=n; w = la[n]; }   // self-loop, weight = mean incoming
  int pos = off[d] + atomicAdd(&fill[d], 1);
  csrs[pos] = s; csrw[pos] = w;
}

// ---------------- gather: xemb = bf16(skill_embs[skills] + resp_emb[resp]) ----------------
__global__ __launch_bounds__(256) void k_gather(
    const float* __restrict__ embN, const float* __restrict__ remb,
    const int* __restrict__ skills, const int* __restrict__ resp,
    u16* __restrict__ xemb){
  int i = blockIdx.x*256 + threadIdx.x;           // one per 8 elems
  if(i >= NB*NTT*EMB/8) return;
  int row = i >> 4;                               // 16 groups of 8 per row
  int g8  = (i & 15) * 8;
  const float* ar = embN + (size_t)skills[row]*EMB + g8;
  const float* rr = remb + (size_t)resp[row]*EMB + g8;
  u16x8 v;
  #pragma unroll
  for(int e=0;e<8;++e) v[e] = f2bf(ar[e] + rr[e]);
  *(u16x8*)(xemb + (size_t)row*EMB + g8) = v;
}

// ---------------- MFMA GEMM: C = A @ W^T + bias (A,W bf16) ----------------
// AMODE: 2 = A bf16 [M,K]; 3 = A bf16 with chunk row map (row -> b*NTT+t0+row%chk).
// MI: rows per wave = MI*16 (block = MI*64 rows).
// lens != null (proj): row=(b*NTT+t), t>=lens[b] -> bias only.
template<int AMODE, bool OUTF32, int MI>
__global__ __launch_bounds__(256) void k_gemm(
    const u16* __restrict__ Av, const u16* __restrict__ W, const float* __restrict__ bias,
    void* __restrict__ out,
    int M, int N, int K,
    int t0, int chk,
    const int* __restrict__ lens)
{
  int tid = threadIdx.x;
  int wid = tid >> 6, l = tid & 63;
  int lr = l & 15, lg = l >> 4;
  int bm = blockIdx.x*(MI*64) + wid*(MI*16);
  int bn = blockIdx.y*64;
  f32x4 acc[MI][4] = {};
  int nk = K >> 5;
  for(int kt=0; kt<nk; ++kt){
    int k0 = kt*32 + lg*8;
    bf16x8 af[MI];
    #pragma unroll
    for(int mi=0; mi<MI; ++mi){
      int row = bm + mi*16 + lr;
      u16x8 v = {0,0,0,0,0,0,0,0};
      if(row < M){
        if constexpr(AMODE == 3){
          int b = row / chk, tt = row - b*chk;
          int arow = b*NTT + t0 + tt;
          v = *(const u16x8*)(Av + (size_t)arow*K + k0);
        } else {
          v = *(const u16x8*)(Av + (size_t)row*K + k0);
        }
      }
      af[mi] = __builtin_bit_cast(bf16x8, v);
    }
    #pragma unroll
    for(int nt=0; nt<4; ++nt){
      int col = bn + nt*16 + lr;
      u16x8 wv = *(const u16x8*)(W + (size_t)col*K + k0);
      bf16x8 bfr = __builtin_bit_cast(bf16x8, wv);
      #pragma unroll
      for(int mi=0; mi<MI; ++mi)
        acc[mi][nt] = __builtin_amdgcn_mfma_f32_16x16x32_bf16(af[mi], bfr, acc[mi][nt], 0,0,0);
    }
  }
  #pragma unroll
  for(int mi=0; mi<MI; ++mi){
    #pragma unroll
    for(int nt=0; nt<4; ++nt){
      int col = bn + nt*16 + lr;
      float bc = bias[col];
      #pragma unroll
      for(int r=0; r<4; ++r){
        int row = bm + mi*16 + lg*4 + r;
        if(row >= M) continue;
        float v = acc[mi][nt][r] + bc;
        if(lens){ int b = row/NTT; int t = row - b*NTT; if(t >= lens[b]) v = bc; }
        if constexpr(OUTF32) ((float*)out)[(size_t)row*N + col] = v;
        else                 ((u16*) out)[(size_t)row*N + col] = f2bf(v);
      }
    }
  }
}

// paired GEMM: z=0 -> (W0,b0,out0), z=1 -> (W1,b1,out1); bf16 A and out, MI=2
__global__ __launch_bounds__(256) void k_gemm2(
    const u16* __restrict__ Av,
    const u16* __restrict__ W0, const u16* __restrict__ W1,
    const float* __restrict__ b0, const float* __restrict__ b1,
    u16* __restrict__ out0, u16* __restrict__ out1,
    int M, int N, int K)
{
  const u16*   W    = blockIdx.z ? W1 : W0;
  const float* bias = blockIdx.z ? b1 : b0;
  u16*         out  = blockIdx.z ? out1 : out0;
  int tid = threadIdx.x;
  int wid = tid >> 6, l = tid & 63;
  int lr = l & 15, lg = l >> 4;
  int bm = blockIdx.x*128 + wid*32;
  int bn = blockIdx.y*64;
  f32x4 acc[2][4] = {};
  int nk = K >> 5;
  for(int kt=0; kt<nk; ++kt){
    int k0 = kt*32 + lg*8;
    bf16x8 af[2];
    #pragma unroll
    for(int mi=0; mi<2; ++mi){
      int row = bm + mi*16 + lr;
      u16x8 v = {0,0,0,0,0,0,0,0};
      if(row < M) v = *(const u16x8*)(Av + (size_t)row*K + k0);
      af[mi] = __builtin_bit_cast(bf16x8, v);
    }
    #pragma unroll
    for(int nt=0; nt<4; ++nt){
      int col = bn + nt*16 + lr;
      u16x8 wv = *(const u16x8*)(W + (size_t)col*K + k0);
      bf16x8 bfr = __builtin_bit_cast(bf16x8, wv);
      acc[0][nt] = __builtin_amdgcn_mfma_f32_16x16x32_bf16(af[0], bfr, acc[0][nt], 0,0,0);
      acc[1][nt] = __builtin_amdgcn_mfma_f32_16x16x32_bf16(af[1], bfr, acc[1][nt], 0,0,0);
    }
  }
  #pragma unroll
  for(int mi=0; mi<2; ++mi){
    #pragma unroll
    for(int nt=0; nt<4; ++nt){
      int col = bn + nt*16 + lr;
      float bc = bias[col];
      #pragma unroll
      for(int r=0; r<4; ++r){
        int row = bm + mi*16 + lg*4 + r;
        if(row >= M) continue;
        out[(size_t)row*N + col] = f2bf(acc[mi][nt][r] + bc);
      }
    }
  }
}

// ---------------- GATv2 attention + aggregate + bias + ELU ----------------
// BF16OUT: write bf16 (intermediate h1) else f32 (skill_embs output)
template<bool BF16OUT>
__global__ __launch_bounds__(256) void k_attn(
    const int* __restrict__ off, const int* __restrict__ csrs, const float* __restrict__ csrw,
    const u16* __restrict__ xl, const u16* __restrict__ xr,
    const float* __restrict__ We, const float* __restrict__ att, const float* __restrict__ bias,
    float* __restrict__ houtF, u16* __restrict__ houtB)
{
  int wid = threadIdx.x >> 6, l = threadIdx.x & 63;
  int n = blockIdx.x*4 + wid;
  int d0 = 2*l;
  const unsigned int* xl2 = (const unsigned int*)xl;
  unsigned int xru = ((const unsigned int*)xr)[n*64 + l];
  float xrx = bf2f((u16)xru), xry = bf2f((u16)(xru>>16));
  float wex = We[d0],  wey = We[d0+1];
  float atx = att[d0], aty = att[d0+1];
  int p0 = off[n], p1 = off[n+1];
  float mx = -1e30f;
  for(int p=p0; p<p1; ++p){
    int s = csrs[p]; float w = csrw[p];
    unsigned int u = xl2[s*64 + l];
    float ax = bf2f((u16)u)       + xrx + w*wex;
    float ay = bf2f((u16)(u>>16)) + xry + w*wey;
    ax = ax > 0.f ? ax : 0.2f*ax;
    ay = ay > 0.f ? ay : 0.2f*ay;
    float c = ax*atx + ay*aty;
    c += __shfl_xor(c,1); c += __shfl_xor(c,2); c += __shfl_xor(c,4); c += __shfl_xor(c,8);
    mx = fmaxf(mx, c);
  }
  float den = 0.f, a0 = 0.f, a1 = 0.f;
  for(int p=p0; p<p1; ++p){
    int s = csrs[p]; float w = csrw[p];
    unsigned int u = xl2[s*64 + l];
    float xlx = bf2f((u16)u), xly = bf2f((u16)(u>>16));
    float ax = xlx + xrx + w*wex;
    float ay = xly + xry + w*wey;
    ax = ax > 0.f ? ax : 0.2f*ax;
    ay = ay > 0.f ? ay : 0.2f*ay;
    float c = ax*atx + ay*aty;
    c += __shfl_xor(c,1); c += __shfl_xor(c,2); c += __shfl_xor(c,4); c += __shfl_xor(c,8);
    float al = __expf(c - mx);
    den += al; a0 += al*xlx; a1 += al*xly;
  }
  float inv = 1.f/(den + 1e-16f);
  float o0 = a0*inv + bias[d0];
  float o1 = a1*inv + bias[d0+1];
  o0 = o0 > 0.f ? o0 : (__expf(o0) - 1.f);   // ELU
  o1 = o1 > 0.f ? o1 : (__expf(o1) - 1.f);
  if constexpr(BF16OUT){
    houtB[n*EMB + d0]   = f2bf(o0);
    houtB[n*EMB + d0+1] = f2bf(o1);
  } else {
    houtF[n*EMB + d0]   = o0;
    houtF[n*EMB + d0+1] = o1;
  }
}

// ---------------- GRU: 256 blocks x 1 batch row, 4 waves (1/SIMD) ----------------
// R15/R17-verbatim MFMA/gate schedule (DO NOT reorder — R16 failure). Staging
// upgraded to TRIPLE buffer (prefetch depth 2): stage(t+2) issued at step top;
// end-of-step wait vmcnt(3) guarantees stage(t+1) retired (per-wave issue order:
// stage(s+1), store(s-1), stage(s+2), store(s)). Buffer (s+2)%3 == (s-1)%3 is
// overwritten only after the barrier that drained step s-1's LDS reads.

#define DECLW(nt) f32x4 wf_##nt##_0, wf_##nt##_1, wf_##nt##_2, wf_##nt##_3, \
                        wf_##nt##_4, wf_##nt##_5, wf_##nt##_6, wf_##nt##_7;

#define LDW1(nt,kt) { u16x8 wv = *(const u16x8*)(wr + (kt)*32 + lg*8); \
  wf_##nt##_##kt = __builtin_bit_cast(f32x4, wv); \
  asm volatile("" : "+a"(wf_##nt##_##kt)); }

#define LDW(nt) { int nrow = ((nt)>>2)*256 + wid*64 + ((nt)&3)*16 + lr; \
  const u16* wr = whb + (size_t)nrow*RH; \
  LDW1(nt,0) LDW1(nt,1) LDW1(nt,2) LDW1(nt,3) LDW1(nt,4) LDW1(nt,5) LDW1(nt,6) LDW1(nt,7) }

// D = A(AGPR wf) * B(VGPR h-broadcast) + D
#define MFMA1(acc, wf, hf) asm volatile( \
  "v_mfma_f32_16x16x32_bf16 %0, %1, %2, %0" : "+v"(acc) : "a"(wf), "v"(hf));

#define MST(kt) { \
  f32x4 hf = __builtin_bit_cast(f32x4, *(const u16x8*)(hrd + (kt)*32 + lg*8)); \
  MFMA1(acc0,  wf_0_##kt,  hf) MFMA1(acc1,  wf_1_##kt,  hf) \
  MFMA1(acc2,  wf_2_##kt,  hf) MFMA1(acc3,  wf_3_##kt,  hf) \
  MFMA1(acc4,  wf_4_##kt,  hf) MFMA1(acc5,  wf_5_##kt,  hf) \
  MFMA1(acc6,  wf_6_##kt,  hf) MFMA1(acc7,  wf_7_##kt,  hf) \
  MFMA1(acc8,  wf_8_##kt,  hf) MFMA1(acc9,  wf_9_##kt,  hf) \
  MFMA1(acc10, wf_10_##kt, hf) MFMA1(acc11, wf_11_##kt, hf) }

__global__ __launch_bounds__(256,1) __attribute__((amdgpu_waves_per_eu(1,1))) void k_gru(
    const u16* __restrict__ xgc, const u16* __restrict__ whb, const float* __restrict__ bhh,
    const int* __restrict__ lens, u16* __restrict__ hseq, float* __restrict__ hsave,
    int t0, int t1, int chk)
{
  int tid = threadIdx.x;
  int wid = tid >> 6, l = tid & 63;
  int lr = l & 15, lg = l >> 4;
  int b = blockIdx.x;                       // one batch row per block
  __shared__ __align__(16) u16 lds_h[2][256];    // 1 KB, double-buffered
  __shared__ __align__(16) u16 lds_xg[3][1024];  // 6 KB, TRIPLE-buffered

  int mylen = lens[b];
  int tend = mylen < t1 ? mylen : t1;
  int nsteps = tend - t0; if(nsteps < 0) nsteps = 0;

  // Whh bf16 A-fragments: 96 AGPR-pinned values (layout: row=lr, k=lg*8+e)
  DECLW(0) DECLW(1) DECLW(2)  DECLW(3)  DECLW(4)  DECLW(5)
  DECLW(6) DECLW(7) DECLW(8)  DECLW(9)  DECLW(10) DECLW(11)
  LDW(0) LDW(1) LDW(2)  LDW(3)  LDW(4)  LDW(5)
  LDW(6) LDW(7) LDW(8)  LDW(9)  LDW(10) LDW(11)

  // this lane's gate assignment: j = wid*64 + (lr>>2)*16 + lg*4 + (lr&3)
  int jt   = lr >> 2;
  int rsel = lr & 3;
  int j    = wid*64 + jt*16 + lg*4 + rsel;
  float bhR = bhh[      j];
  float bhZ = bhh[256 + j];
  float bhN = bhh[512 + j];

  // h init into lds_h[0] (linear, single row)
  {
    u16 v = 0;
    if(t0 > 0) v = f2bf(hsave[(size_t)b*RH + tid]);
    lds_h[0][tid] = v;
  }
  float hst = (t0>0) ? hsave[(size_t)b*RH + j] : 0.f;

  // staging: 96 granules of 16B; wave0 -> granules 0-63, wave1 -> 64-127 (96-127 pad)
  int g = (wid==0) ? l : (64 + (l & 31));   // wave1 lanes 32-63 duplicate 64-95 reads
  const u16* xsrc = xgc + ((size_t)b*chk)*G3 + g*8;
  int lwb = (wid==0) ? 0 : 512;             // wave LDS base in u16 units

  // prologue: stage t0 -> buf0 and t0+1 -> buf1, drain, publish
  if(nsteps > 0 && wid < 2)
    stage16(xsrc, &lds_xg[0][lwb], nullptr);
  xsrc += G3;
  if(nsteps > 1 && wid < 2)
    stage16(xsrc, &lds_xg[1][lwb], nullptr);
  xsrc += G3;
  asm volatile("s_waitcnt vmcnt(0)" ::: "memory");
  asm volatile("s_waitcnt lgkmcnt(0)" ::: "memory");
  __builtin_amdgcn_sched_barrier(0);
  __builtin_amdgcn_s_barrier();
  __builtin_amdgcn_sched_barrier(0);

  u16* outbase = hseq + ((size_t)b*NTT + t0)*RH;
  for(int s=0; s<nsteps; ++s){
    const u16* hrd = &lds_h[s&1][0];
    u16*       hwr = &lds_h[(s+1)&1][0];
    const u16* xgr = &lds_xg[s%3][0];
    int more = (s+1 < nsteps);

    // prefetch depth 2: stage t(s+2) into buf[(s+2)%3]
    if(s+2 < nsteps && wid < 2)
      stage16(xsrc, &lds_xg[(s+2)%3][lwb], nullptr);
    xsrc += G3;

    // hg = Whh @ h  (A from AGPRs, B = broadcast h row; no masking needed)
    f32x4 acc0 = {}, acc1 = {}, acc2 = {}, acc3 = {}, acc4 = {}, acc5 = {},
          acc6 = {}, acc7 = {}, acc8 = {}, acc9 = {}, acc10 = {}, acc11 = {};
    MST(0) MST(1) MST(2) MST(3) MST(4) MST(5) MST(6) MST(7)

    // gates: 1 chain per lane (64/wave). acc rows replicated across cols.
    {
      f32x4 aR = seltile(acc0, acc1, acc2,  acc3,  jt);
      f32x4 aZ = seltile(acc4, acc5, acc6,  acc7,  jt);
      f32x4 aN = seltile(acc8, acc9, acc10, acc11, jt);
      float hr = self4(aR, rsel) + bhR;
      float hz = self4(aZ, rsel) + bhZ;
      float hn = self4(aN, rsel) + bhN;
      float xrv = bf2f(xgr[      j]);
      float xzv = bf2f(xgr[256 + j]);
      float xnv = bf2f(xgr[512 + j]);
      float rg = 1.f/(1.f + __expf(-(xrv + hr)));
      float zg = 1.f/(1.f + __expf(-(xzv + hz)));
      float nn = xnv + rg*hn;
      float tg = 1.f - 2.f/(__expf(2.f*nn) + 1.f);   // tanh
      float hv = (1.f - zg)*tg + zg*hst;
      hst = hv;
      u16 hb = f2bf(hv);
      hwr[j] = hb;
      outbase[j] = hb;
    }
    outbase += RH;

    if(more){
      asm volatile("s_waitcnt lgkmcnt(0)" ::: "memory");  // h[nxt] write + LDS reads done
      asm volatile("s_waitcnt vmcnt(3)" ::: "memory");    // stage(s+1) retired; newer ops fly
      __builtin_amdgcn_sched_barrier(0);
      __builtin_amdgcn_s_barrier();                       // publish h[nxt] + xg[nxt]
      __builtin_amdgcn_sched_barrier(0);
    }
  }

  // zero-fill [max(tend,t0), t1) so hseq is fully written & deterministic
  {
    u16* zp = outbase;
    for(int t = (tend > t0 ? tend : t0); t < t1; ++t){
      zp[j] = 0;
      zp += RH;
    }
  }

  // save exact f32 state for next chunk
  hsave[(size_t)b*RH + j] = hst;
}

// ---------------- launcher ----------------
extern "C" void kernel_launch(void* const* d_in, const int* in_sizes, int n_in,
                              void* d_out, int out_size, void* d_ws, size_t ws_size,
                              hipStream_t stream){
  (void)in_sizes; (void)n_in; (void)out_size;
  const int*   skills = (const int*)d_in[0];
  const int*   resp   = (const int*)d_in[1];
  const int*   lens   = (const int*)d_in[2];
  const int*   eidx   = (const int*)d_in[3];
  const float* ew     = (const float*)d_in[4];
  const float* emb    = (const float*)d_in[5];
  const float* gW[2][7];
  for(int l2=0;l2<2;++l2) for(int j=0;j<7;++j) gW[l2][j] = (const float*)d_in[6 + l2*7 + j];
  const float* remb  = (const float*)d_in[20];
  const float* Wih   = (const float*)d_in[21];
  const float* Whh   = (const float*)d_in[22];
  const float* bih   = (const float*)d_in[23];
  const float* bhh   = (const float*)d_in[24];
  const float* projW = (const float*)d_in[25];
  const float* projb = (const float*)d_in[26];

  char* p = (char*)d_ws;
  size_t o = 0;
  auto take = [&](size_t bytes)->char*{ char* r = p + o; o = (o + bytes + 255) & ~(size_t)255; return r; };
  int*   deg  = (int*)  take(4*N_NODES);
  int*   fill = (int*)  take(4*N_NODES);
  float* wsum = (float*)take(4*N_NODES);
  size_t zbytes = o;                        // deg+fill+wsum zeroed each call
  int*   off   = (int*)  take(4*(N_NODES+1));
  int*   csrs  = (int*)  take(4*NE_TOT);
  float* csrw  = (float*)take(4*NE_TOT);
  u16*   xl    = (u16*)  take(2UL*N_NODES*EMB);
  u16*   xr    = (u16*)  take(2UL*N_NODES*EMB);
  u16*   h1b   = (u16*)  take(2UL*N_NODES*EMB);
  float* hsave = (float*)take(4UL*NB*RH);
  u16*   wb    = (u16*)  take(2UL*WB_TOT);
  u16*   hseq  = (u16*)  take(2UL*NB*NTT*RH);
  u16*   xemb  = (u16*)  take(2UL*NB*NTT*EMB);
  size_t fixed_end = o;
  // xg chunk length: largest of {200,100,50,25} that fits ws_size
  int chk = 200;
  while(chk > 25 && fixed_end + 2UL*NB*(size_t)chk*G3 > ws_size) chk /= 2;
  u16*   xgc  = (u16*)  take(2UL*NB*(size_t)chk*G3);

  const u16* wb_g0l  = wb;
  const u16* wb_g0r  = wb + 16384;
  const u16* wb_g1l  = wb + 32768;
  const u16* wb_g1r  = wb + 49152;
  const u16* wb_wih  = wb + 65536;
  const u16* wb_whh  = wb + 163840;
  const u16* wb_proj = wb + 360448;
  const u16* wb_emb  = wb + WB_W;

  float* outP = (float*)d_out;                     // h_proj [256,200,128] f32
  float* outE = outP + (size_t)NB*NTT*EMB;         // skill_embs [10000,128] f32

  hipMemsetAsync(d_ws, 0, zbytes, stream);
  k_prep<<<NDEG_BLK + NCVT_BLK, 256, 0, stream>>>(eidx, ew, deg, wsum,
                                 gW[0][0], gW[0][2], gW[1][0], gW[1][2],
                                 Wih, Whh, projW, emb, (u16*)wb);
  k_scan<<<1, 1024, 0, stream>>>(deg, wsum, off);
  k_scatter<<<(NE_TOT+255)/256, 256, 0, stream>>>(eidx, ew, wsum, off, fill, csrs, csrw);

  dim3 gN2((N_NODES+127)/128, EMB/64, 2);
  // layer 0: xl and xr in one paired launch
  k_gemm2<<<gN2, 256, 0, stream>>>(wb_emb, wb_g0l, wb_g0r, gW[0][1], gW[0][3],
                                   xl, xr, N_NODES, EMB, EMB);
  k_attn<true><<<N_NODES/4, 256, 0, stream>>>(off, csrs, csrw, xl, xr,
                                 gW[0][4], gW[0][5], gW[0][6], nullptr, h1b);
  // layer 1
  k_gemm2<<<gN2, 256, 0, stream>>>(h1b, wb_g1l, wb_g1r, gW[1][1], gW[1][3],
                                   xl, xr, N_NODES, EMB, EMB);
  k_attn<false><<<N_NODES/4, 256, 0, stream>>>(off, csrs, csrw, xl, xr,
                                 gW[1][4], gW[1][5], gW[1][6], outE, nullptr);

  // gather once: xemb = bf16(skill_embs[skills] + resp_emb[resp])
  k_gather<<<(NB*NTT*EMB/8 + 255)/256, 256, 0, stream>>>(outE, remb, skills, resp, xemb);

  // chunked: xg = xemb @ Wih^T + bih (bf16, MI=4), then GRU chunk
  for(int t0=0; t0<NTT; t0+=chk){
    k_gemm<3,false,4><<<dim3(NB*chk/256, G3/64), 256, 0, stream>>>(xemb, wb_wih, bih, xgc,
                                 NB*chk, G3, EMB, t0, chk, nullptr);
    k_gru<<<NB, 256, 0, stream>>>(xgc, wb_whh, bhh, lens, hseq, hsave, t0, t0+chk, chk);
  }
  // proj: A = hseq bf16 (MI=4), out f32 (+ lens mask; hseq rows t>=len are zeros)
  k_gemm<2,true,4><<<dim3(NB*NTT/256, EMB/64), 256, 0, stream>>>(hseq, wb_proj, projb, outP,
                                 NB*NTT, EMB, RH, 0, 0, lens);
}

// Round 20
// 595.379 us; speedup vs baseline: 3.1042x; 1.1022x over previous
//
#include <hip/hip_runtime.h>

#define N_NODES 10000
#define EMB     128
#define NE      320000
#define NE_TOT  330000   // + one self-loop per node
#define NB      256
#define NTT     200
#define RH      256
#define G3      768

typedef unsigned short u16;
typedef u16    u16x8  __attribute__((ext_vector_type(8)));
typedef __bf16 bf16x8 __attribute__((ext_vector_type(8)));
typedef float  f32x4  __attribute__((ext_vector_type(4)));

static __device__ __forceinline__ float bf2f(u16 u){
  unsigned int x = ((unsigned int)u) << 16;
  return __builtin_bit_cast(float, x);
}
static __device__ __forceinline__ u16 f2bf(float f){
  unsigned int x = __builtin_bit_cast(unsigned int, f);
  x += 0x7fffu + ((x >> 16) & 1u);
  return (u16)(x >> 16);
}

// async global->LDS, 16B per lane; lds dest must be the WAVE base (HW adds lane*16)
static __device__ __forceinline__ void stage16(const u16* g, u16* lds_wavebase, u16* lds_lane){
#if __has_builtin(__builtin_amdgcn_global_load_lds)
  __builtin_amdgcn_global_load_lds(
      (const __attribute__((address_space(1))) unsigned int*)g,
      (__attribute__((address_space(3))) unsigned int*)lds_wavebase, 16, 0, 0);
  (void)lds_lane;
#else
  *(u16x8*)lds_lane = *(const u16x8*)g;
#endif
}

// static-index selects (rule #20: no runtime-indexed register arrays)
static __device__ __forceinline__ float self4(f32x4 v, int r){
  float lo = (r&1) ? v[1] : v[0];
  float hi = (r&1) ? v[3] : v[2];
  return (r&2) ? hi : lo;
}
static __device__ __forceinline__ f32x4 seltile(f32x4 a, f32x4 b, f32x4 c, f32x4 d, int jt){
  f32x4 r;
  #pragma unroll
  for(int e=0;e<4;++e){
    float ab = (jt&1) ? b[e] : a[e];
    float cd = (jt&1) ? d[e] : c[e];
    r[e] = (jt&2) ? cd : ab;
  }
  return r;
}

// ---------------- fused: edge-degree histogram + all f32->bf16 preconversion ----------------
// wb layout: g0l@0, g0r@16384, g1l@32768, g1r@49152, wih@65536, whh@163840,
//            proj@360448, emb@393216
#define WB_W   393216
#define WB_TOT (WB_W + N_NODES*EMB)
#define NDEG_BLK ((NE + 255)/256)
#define NCVT_BLK ((WB_TOT + 255)/256)
__global__ __launch_bounds__(256) void k_prep(
    const int* __restrict__ eidx, const float* __restrict__ ew,
    int* __restrict__ deg, float* __restrict__ wsum,
    const float* __restrict__ g0l, const float* __restrict__ g0r,
    const float* __restrict__ g1l, const float* __restrict__ g1r,
    const float* __restrict__ wih, const float* __restrict__ whh,
    const float* __restrict__ pw, const float* __restrict__ emb,
    u16* __restrict__ wb)
{
  int bid = blockIdx.x;
  if(bid < NDEG_BLK){
    int i = bid*256 + threadIdx.x;
    if(i >= NE) return;
    int d = eidx[NE + i];
    atomicAdd(&deg[d], 1);
    atomicAdd(&wsum[d], ew[i]);
  } else {
    int i = (bid - NDEG_BLK)*256 + threadIdx.x;
    if(i >= WB_TOT) return;
    float v;
    if(i < 65536){
      int seg = i >> 14, r = i & 16383;
      const float* s = (seg==0) ? g0l : (seg==1) ? g0r : (seg==2) ? g1l : g1r;
      v = s[r];
    } else if(i < 163840){ v = wih[i - 65536]; }
    else if(i < 360448){ v = whh[i - 163840]; }
    else if(i < WB_W)  { v = pw [i - 360448]; }
    else               { v = emb[i - WB_W]; }
    wb[i] = f2bf(v);
  }
}

__global__ __launch_bounds__(1024) void k_scan(const int* __restrict__ deg,
                      float* __restrict__ wsum, int* __restrict__ off){
  __shared__ int part[1024];
  int tid = threadIdx.x;
  int n0 = tid*10;
  int s = 0;
  for(int i=0;i<10;++i){ int n=n0+i; if(n<N_NODES) s += deg[n]+1; }
  part[tid] = s;
  for(int i=0;i<10;++i){
    int n=n0+i;
    if(n<N_NODES){ int d=deg[n]; wsum[n] = wsum[n] / (float)(d>1?d:1); }
  }
  __syncthreads();
  for(int st=1; st<1024; st<<=1){
    int v = (tid>=st) ? part[tid-st] : 0;
    __syncthreads();
    part[tid] += v;
    __syncthreads();
  }
  int base = tid ? part[tid-1] : 0;
  for(int i=0;i<10;++i){ int n=n0+i; if(n<N_NODES){ off[n]=base; base += deg[n]+1; } }
  if(tid==999) off[N_NODES] = base;
}

__global__ void k_scatter(const int* __restrict__ eidx, const float* __restrict__ ew,
                          const float* __restrict__ la, const int* __restrict__ off,
                          int* __restrict__ fill, int* __restrict__ csrs, float* __restrict__ csrw){
  int i = blockIdx.x*256 + threadIdx.x;
  if(i >= NE_TOT) return;
  int s, d; float w;
  if(i < NE){ s = eidx[i]; d = eidx[NE+i]; w = ew[i]; }
  else      { int n = i-NE; s=n; d=n; w = la[n]; }   // self-loop, weight = mean incoming
  int pos = off[d] + atomicAdd(&fill[d], 1);
  csrs[pos] = s; csrw[pos] = w;
}

// ---------------- gather: xemb = bf16(skill_embs[skills] + resp_emb[resp]) ----------------
__global__ __launch_bounds__(256) void k_gather(
    const float* __restrict__ embN, const float* __restrict__ remb,
    const int* __restrict__ skills, const int* __restrict__ resp,
    u16* __restrict__ xemb){
  int i = blockIdx.x*256 + threadIdx.x;           // one per 8 elems
  if(i >= NB*NTT*EMB/8) return;
  int row = i >> 4;                               // 16 groups of 8 per row
  int g8  = (i & 15) * 8;
  const float* ar = embN + (size_t)skills[row]*EMB + g8;
  const float* rr = remb + (size_t)resp[row]*EMB + g8;
  u16x8 v;
  #pragma unroll
  for(int e=0;e<8;++e) v[e] = f2bf(ar[e] + rr[e]);
  *(u16x8*)(xemb + (size_t)row*EMB + g8) = v;
}

// ---------------- MFMA GEMM: C = A @ W^T + bias (A,W bf16) ----------------
// AMODE: 2 = A bf16 [M,K]; 3 = A bf16 with chunk row map (row -> b*NTT+t0+row%chk).
// MI: rows per wave = MI*16 (block = MI*64 rows).
// lens != null (proj): row=(b*NTT+t), t>=lens[b] -> bias only.
template<int AMODE, bool OUTF32, int MI>
__global__ __launch_bounds__(256) void k_gemm(
    const u16* __restrict__ Av, const u16* __restrict__ W, const float* __restrict__ bias,
    void* __restrict__ out,
    int M, int N, int K,
    int t0, int chk,
    const int* __restrict__ lens)
{
  int tid = threadIdx.x;
  int wid = tid >> 6, l = tid & 63;
  int lr = l & 15, lg = l >> 4;
  int bm = blockIdx.x*(MI*64) + wid*(MI*16);
  int bn = blockIdx.y*64;
  f32x4 acc[MI][4] = {};
  int nk = K >> 5;
  for(int kt=0; kt<nk; ++kt){
    int k0 = kt*32 + lg*8;
    bf16x8 af[MI];
    #pragma unroll
    for(int mi=0; mi<MI; ++mi){
      int row = bm + mi*16 + lr;
      u16x8 v = {0,0,0,0,0,0,0,0};
      if(row < M){
        if constexpr(AMODE == 3){
          int b = row / chk, tt = row - b*chk;
          int arow = b*NTT + t0 + tt;
          v = *(const u16x8*)(Av + (size_t)arow*K + k0);
        } else {
          v = *(const u16x8*)(Av + (size_t)row*K + k0);
        }
      }
      af[mi] = __builtin_bit_cast(bf16x8, v);
    }
    #pragma unroll
    for(int nt=0; nt<4; ++nt){
      int col = bn + nt*16 + lr;
      u16x8 wv = *(const u16x8*)(W + (size_t)col*K + k0);
      bf16x8 bfr = __builtin_bit_cast(bf16x8, wv);
      #pragma unroll
      for(int mi=0; mi<MI; ++mi)
        acc[mi][nt] = __builtin_amdgcn_mfma_f32_16x16x32_bf16(af[mi], bfr, acc[mi][nt], 0,0,0);
    }
  }
  #pragma unroll
  for(int mi=0; mi<MI; ++mi){
    #pragma unroll
    for(int nt=0; nt<4; ++nt){
      int col = bn + nt*16 + lr;
      float bc = bias[col];
      #pragma unroll
      for(int r=0; r<4; ++r){
        int row = bm + mi*16 + lg*4 + r;
        if(row >= M) continue;
        float v = acc[mi][nt][r] + bc;
        if(lens){ int b = row/NTT; int t = row - b*NTT; if(t >= lens[b]) v = bc; }
        if constexpr(OUTF32) ((float*)out)[(size_t)row*N + col] = v;
        else                 ((u16*) out)[(size_t)row*N + col] = f2bf(v);
      }
    }
  }
}

// paired GEMM: z=0 -> (W0,b0,out0), z=1 -> (W1,b1,out1); bf16 A and out, MI=2
__global__ __launch_bounds__(256) void k_gemm2(
    const u16* __restrict__ Av,
    const u16* __restrict__ W0, const u16* __restrict__ W1,
    const float* __restrict__ b0, const float* __restrict__ b1,
    u16* __restrict__ out0, u16* __restrict__ out1,
    int M, int N, int K)
{
  const u16*   W    = blockIdx.z ? W1 : W0;
  const float* bias = blockIdx.z ? b1 : b0;
  u16*         out  = blockIdx.z ? out1 : out0;
  int tid = threadIdx.x;
  int wid = tid >> 6, l = tid & 63;
  int lr = l & 15, lg = l >> 4;
  int bm = blockIdx.x*128 + wid*32;
  int bn = blockIdx.y*64;
  f32x4 acc[2][4] = {};
  int nk = K >> 5;
  for(int kt=0; kt<nk; ++kt){
    int k0 = kt*32 + lg*8;
    bf16x8 af[2];
    #pragma unroll
    for(int mi=0; mi<2; ++mi){
      int row = bm + mi*16 + lr;
      u16x8 v = {0,0,0,0,0,0,0,0};
      if(row < M) v = *(const u16x8*)(Av + (size_t)row*K + k0);
      af[mi] = __builtin_bit_cast(bf16x8, v);
    }
    #pragma unroll
    for(int nt=0; nt<4; ++nt){
      int col = bn + nt*16 + lr;
      u16x8 wv = *(const u16x8*)(W + (size_t)col*K + k0);
      bf16x8 bfr = __builtin_bit_cast(bf16x8, wv);
      acc[0][nt] = __builtin_amdgcn_mfma_f32_16x16x32_bf16(af[0], bfr, acc[0][nt], 0,0,0);
      acc[1][nt] = __builtin_amdgcn_mfma_f32_16x16x32_bf16(af[1], bfr, acc[1][nt], 0,0,0);
    }
  }
  #pragma unroll
  for(int mi=0; mi<2; ++mi){
    #pragma unroll
    for(int nt=0; nt<4; ++nt){
      int col = bn + nt*16 + lr;
      float bc = bias[col];
      #pragma unroll
      for(int r=0; r<4; ++r){
        int row = bm + mi*16 + lg*4 + r;
        if(row >= M) continue;
        out[(size_t)row*N + col] = f2bf(acc[mi][nt][r] + bc);
      }
    }
  }
}

// ---------------- GATv2 attention + aggregate + bias + ELU ----------------
// per-edge logit: message pre-act + LeakyReLU + per-head 16-lane dot (4x shfl)
static __device__ __forceinline__ float edge_logit(unsigned u, float w,
    float xrx, float xry, float wex, float wey, float atx, float aty){
  float ax = bf2f((u16)u)       + xrx + w*wex;
  float ay = bf2f((u16)(u>>16)) + xry + w*wey;
  ax = ax > 0.f ? ax : 0.2f*ax;
  ay = ay > 0.f ? ay : 0.2f*ay;
  float c = ax*atx + ay*aty;
  c += __shfl_xor(c,1); c += __shfl_xor(c,2); c += __shfl_xor(c,4); c += __shfl_xor(c,8);
  return c;
}

// BF16OUT: write bf16 (intermediate h1) else f32 (skill_embs output).
// Edge loops unrolled x4 with grouped loads (4 gathers in flight); accumulation
// remains in ORIGINAL edge order -> bit-identical to the scalar loop.
template<bool BF16OUT>
__global__ __launch_bounds__(256) void k_attn(
    const int* __restrict__ off, const int* __restrict__ csrs, const float* __restrict__ csrw,
    const u16* __restrict__ xl, const u16* __restrict__ xr,
    const float* __restrict__ We, const float* __restrict__ att, const float* __restrict__ bias,
    float* __restrict__ houtF, u16* __restrict__ houtB)
{
  int wid = threadIdx.x >> 6, l = threadIdx.x & 63;
  int n = blockIdx.x*4 + wid;
  int d0 = 2*l;
  const unsigned int* xl2 = (const unsigned int*)xl;
  unsigned int xru = ((const unsigned int*)xr)[n*64 + l];
  float xrx = bf2f((u16)xru), xry = bf2f((u16)(xru>>16));
  float wex = We[d0],  wey = We[d0+1];
  float atx = att[d0], aty = att[d0+1];
  int p0 = off[n], p1 = off[n+1];

  // pass 1: max logit (4-edge pipelined, in-order fmax)
  float mx = -1e30f;
  int p = p0;
  for(; p+4 <= p1; p += 4){
    int   s0 = csrs[p],   s1 = csrs[p+1], s2 = csrs[p+2], s3 = csrs[p+3];
    float w0 = csrw[p],   w1 = csrw[p+1], w2 = csrw[p+2], w3 = csrw[p+3];
    unsigned u0 = xl2[s0*64 + l], u1 = xl2[s1*64 + l],
             u2 = xl2[s2*64 + l], u3 = xl2[s3*64 + l];
    mx = fmaxf(mx, edge_logit(u0, w0, xrx, xry, wex, wey, atx, aty));
    mx = fmaxf(mx, edge_logit(u1, w1, xrx, xry, wex, wey, atx, aty));
    mx = fmaxf(mx, edge_logit(u2, w2, xrx, xry, wex, wey, atx, aty));
    mx = fmaxf(mx, edge_logit(u3, w3, xrx, xry, wex, wey, atx, aty));
  }
  for(; p < p1; ++p){
    int s = csrs[p]; float w = csrw[p];
    unsigned u = xl2[s*64 + l];
    mx = fmaxf(mx, edge_logit(u, w, xrx, xry, wex, wey, atx, aty));
  }

  // pass 2: softmax-weighted aggregation (4-edge pipelined, in-order adds)
  float den = 0.f, a0 = 0.f, a1 = 0.f;
  p = p0;
  for(; p+4 <= p1; p += 4){
    int   s0 = csrs[p],   s1 = csrs[p+1], s2 = csrs[p+2], s3 = csrs[p+3];
    float w0 = csrw[p],   w1 = csrw[p+1], w2 = csrw[p+2], w3 = csrw[p+3];
    unsigned u0 = xl2[s0*64 + l], u1 = xl2[s1*64 + l],
             u2 = xl2[s2*64 + l], u3 = xl2[s3*64 + l];
    {
      float al = __expf(edge_logit(u0, w0, xrx, xry, wex, wey, atx, aty) - mx);
      den += al; a0 += al*bf2f((u16)u0); a1 += al*bf2f((u16)(u0>>16));
    }
    {
      float al = __expf(edge_logit(u1, w1, xrx, xry, wex, wey, atx, aty) - mx);
      den += al; a0 += al*bf2f((u16)u1); a1 += al*bf2f((u16)(u1>>16));
    }
    {
      float al = __expf(edge_logit(u2, w2, xrx, xry, wex, wey, atx, aty) - mx);
      den += al; a0 += al*bf2f((u16)u2); a1 += al*bf2f((u16)(u2>>16));
    }
    {
      float al = __expf(edge_logit(u3, w3, xrx, xry, wex, wey, atx, aty) - mx);
      den += al; a0 += al*bf2f((u16)u3); a1 += al*bf2f((u16)(u3>>16));
    }
  }
  for(; p < p1; ++p){
    int s = csrs[p]; float w = csrw[p];
    unsigned u = xl2[s*64 + l];
    float al = __expf(edge_logit(u, w, xrx, xry, wex, wey, atx, aty) - mx);
    den += al; a0 += al*bf2f((u16)u); a1 += al*bf2f((u16)(u>>16));
  }

  float inv = 1.f/(den + 1e-16f);
  float o0 = a0*inv + bias[d0];
  float o1 = a1*inv + bias[d0+1];
  o0 = o0 > 0.f ? o0 : (__expf(o0) - 1.f);   // ELU
  o1 = o1 > 0.f ? o1 : (__expf(o1) - 1.f);
  if constexpr(BF16OUT){
    houtB[n*EMB + d0]   = f2bf(o0);
    houtB[n*EMB + d0+1] = f2bf(o1);
  } else {
    houtF[n*EMB + d0]   = o0;
    houtF[n*EMB + d0+1] = o1;
  }
}

// ---------------- GRU: 256 blocks x 1 batch row, 4 waves (1/SIMD) ----------------
// R15/R17-verbatim MFMA/gate schedule (DO NOT reorder — R16 failure). Triple-buffered
// staging (prefetch depth 2); end-of-step vmcnt(3). FROZEN at ~310 us.

#define DECLW(nt) f32x4 wf_##nt##_0, wf_##nt##_1, wf_##nt##_2, wf_##nt##_3, \
                        wf_##nt##_4, wf_##nt##_5, wf_##nt##_6, wf_##nt##_7;

#define LDW1(nt,kt) { u16x8 wv = *(const u16x8*)(wr + (kt)*32 + lg*8); \
  wf_##nt##_##kt = __builtin_bit_cast(f32x4, wv); \
  asm volatile("" : "+a"(wf_##nt##_##kt)); }

#define LDW(nt) { int nrow = ((nt)>>2)*256 + wid*64 + ((nt)&3)*16 + lr; \
  const u16* wr = whb + (size_t)nrow*RH; \
  LDW1(nt,0) LDW1(nt,1) LDW1(nt,2) LDW1(nt,3) LDW1(nt,4) LDW1(nt,5) LDW1(nt,6) LDW1(nt,7) }

// D = A(AGPR wf) * B(VGPR h-broadcast) + D
#define MFMA1(acc, wf, hf) asm volatile( \
  "v_mfma_f32_16x16x32_bf16 %0, %1, %2, %0" : "+v"(acc) : "a"(wf), "v"(hf));

#define MST(kt) { \
  f32x4 hf = __builtin_bit_cast(f32x4, *(const u16x8*)(hrd + (kt)*32 + lg*8)); \
  MFMA1(acc0,  wf_0_##kt,  hf) MFMA1(acc1,  wf_1_##kt,  hf) \
  MFMA1(acc2,  wf_2_##kt,  hf) MFMA1(acc3,  wf_3_##kt,  hf) \
  MFMA1(acc4,  wf_4_##kt,  hf) MFMA1(acc5,  wf_5_##kt,  hf) \
  MFMA1(acc6,  wf_6_##kt,  hf) MFMA1(acc7,  wf_7_##kt,  hf) \
  MFMA1(acc8,  wf_8_##kt,  hf) MFMA1(acc9,  wf_9_##kt,  hf) \
  MFMA1(acc10, wf_10_##kt, hf) MFMA1(acc11, wf_11_##kt, hf) }

__global__ __launch_bounds__(256,1) __attribute__((amdgpu_waves_per_eu(1,1))) void k_gru(
    const u16* __restrict__ xgc, const u16* __restrict__ whb, const float* __restrict__ bhh,
    const int* __restrict__ lens, u16* __restrict__ hseq, float* __restrict__ hsave,
    int t0, int t1, int chk)
{
  int tid = threadIdx.x;
  int wid = tid >> 6, l = tid & 63;
  int lr = l & 15, lg = l >> 4;
  int b = blockIdx.x;                       // one batch row per block
  __shared__ __align__(16) u16 lds_h[2][256];    // 1 KB, double-buffered
  __shared__ __align__(16) u16 lds_xg[3][1024];  // 6 KB, TRIPLE-buffered

  int mylen = lens[b];
  int tend = mylen < t1 ? mylen : t1;
  int nsteps = tend - t0; if(nsteps < 0) nsteps = 0;

  // Whh bf16 A-fragments: 96 AGPR-pinned values (layout: row=lr, k=lg*8+e)
  DECLW(0) DECLW(1) DECLW(2)  DECLW(3)  DECLW(4)  DECLW(5)
  DECLW(6) DECLW(7) DECLW(8)  DECLW(9)  DECLW(10) DECLW(11)
  LDW(0) LDW(1) LDW(2)  LDW(3)  LDW(4)  LDW(5)
  LDW(6) LDW(7) LDW(8)  LDW(9)  LDW(10) LDW(11)

  // this lane's gate assignment: j = wid*64 + (lr>>2)*16 + lg*4 + (lr&3)
  int jt   = lr >> 2;
  int rsel = lr & 3;
  int j    = wid*64 + jt*16 + lg*4 + rsel;
  float bhR = bhh[      j];
  float bhZ = bhh[256 + j];
  float bhN = bhh[512 + j];

  // h init into lds_h[0] (linear, single row)
  {
    u16 v = 0;
    if(t0 > 0) v = f2bf(hsave[(size_t)b*RH + tid]);
    lds_h[0][tid] = v;
  }
  float hst = (t0>0) ? hsave[(size_t)b*RH + j] : 0.f;

  // staging: 96 granules of 16B; wave0 -> granules 0-63, wave1 -> 64-127 (96-127 pad)
  int g = (wid==0) ? l : (64 + (l & 31));   // wave1 lanes 32-63 duplicate 64-95 reads
  const u16* xsrc = xgc + ((size_t)b*chk)*G3 + g*8;
  int lwb = (wid==0) ? 0 : 512;             // wave LDS base in u16 units

  // prologue: stage t0 -> buf0 and t0+1 -> buf1, drain, publish
  if(nsteps > 0 && wid < 2)
    stage16(xsrc, &lds_xg[0][lwb], nullptr);
  xsrc += G3;
  if(nsteps > 1 && wid < 2)
    stage16(xsrc, &lds_xg[1][lwb], nullptr);
  xsrc += G3;
  asm volatile("s_waitcnt vmcnt(0)" ::: "memory");
  asm volatile("s_waitcnt lgkmcnt(0)" ::: "memory");
  __builtin_amdgcn_sched_barrier(0);
  __builtin_amdgcn_s_barrier();
  __builtin_amdgcn_sched_barrier(0);

  u16* outbase = hseq + ((size_t)b*NTT + t0)*RH;
  for(int s=0; s<nsteps; ++s){
    const u16* hrd = &lds_h[s&1][0];
    u16*       hwr = &lds_h[(s+1)&1][0];
    const u16* xgr = &lds_xg[s%3][0];
    int more = (s+1 < nsteps);

    // prefetch depth 2: stage t(s+2) into buf[(s+2)%3]
    if(s+2 < nsteps && wid < 2)
      stage16(xsrc, &lds_xg[(s+2)%3][lwb], nullptr);
    xsrc += G3;

    // hg = Whh @ h  (A from AGPRs, B = broadcast h row; no masking needed)
    f32x4 acc0 = {}, acc1 = {}, acc2 = {}, acc3 = {}, acc4 = {}, acc5 = {},
          acc6 = {}, acc7 = {}, acc8 = {}, acc9 = {}, acc10 = {}, acc11 = {};
    MST(0) MST(1) MST(2) MST(3) MST(4) MST(5) MST(6) MST(7)

    // gates: 1 chain per lane (64/wave). acc rows replicated across cols.
    {
      f32x4 aR = seltile(acc0, acc1, acc2,  acc3,  jt);
      f32x4 aZ = seltile(acc4, acc5, acc6,  acc7,  jt);
      f32x4 aN = seltile(acc8, acc9, acc10, acc11, jt);
      float hr = self4(aR, rsel) + bhR;
      float hz = self4(aZ, rsel) + bhZ;
      float hn = self4(aN, rsel) + bhN;
      float xrv = bf2f(xgr[      j]);
      float xzv = bf2f(xgr[256 + j]);
      float xnv = bf2f(xgr[512 + j]);
      float rg = 1.f/(1.f + __expf(-(xrv + hr)));
      float zg = 1.f/(1.f + __expf(-(xzv + hz)));
      float nn = xnv + rg*hn;
      float tg = 1.f - 2.f/(__expf(2.f*nn) + 1.f);   // tanh
      float hv = (1.f - zg)*tg + zg*hst;
      hst = hv;
      u16 hb = f2bf(hv);
      hwr[j] = hb;
      outbase[j] = hb;
    }
    outbase += RH;

    if(more){
      asm volatile("s_waitcnt lgkmcnt(0)" ::: "memory");  // h[nxt] write + LDS reads done
      asm volatile("s_waitcnt vmcnt(3)" ::: "memory");    // stage(s+1) retired; newer ops fly
      __builtin_amdgcn_sched_barrier(0);
      __builtin_amdgcn_s_barrier();                       // publish h[nxt] + xg[nxt]
      __builtin_amdgcn_sched_barrier(0);
    }
  }

  // zero-fill [max(tend,t0), t1) so hseq is fully written & deterministic
  {
    u16* zp = outbase;
    for(int t = (tend > t0 ? tend : t0); t < t1; ++t){
      zp[j] = 0;
      zp += RH;
    }
  }

  // save exact f32 state for next chunk
  hsave[(size_t)b*RH + j] = hst;
}

// ---------------- launcher ----------------
extern "C" void kernel_launch(void* const* d_in, const int* in_sizes, int n_in,
                              void* d_out, int out_size, void* d_ws, size_t ws_size,
                              hipStream_t stream){
  (void)in_sizes; (void)n_in; (void)out_size;
  const int*   skills = (const int*)d_in[0];
  const int*   resp   = (const int*)d_in[1];
  const int*   lens   = (const int*)d_in[2];
  const int*   eidx   = (const int*)d_in[3];
  const float* ew     = (const float*)d_in[4];
  const float* emb    = (const float*)d_in[5];
  const float* gW[2][7];
  for(int l2=0;l2<2;++l2) for(int j=0;j<7;++j) gW[l2][j] = (const float*)d_in[6 + l2*7 + j];
  const float* remb  = (const float*)d_in[20];
  const float* Wih   = (const float*)d_in[21];
  const float* Whh   = (const float*)d_in[22];
  const float* bih   = (const float*)d_in[23];
  const float* bhh   = (const float*)d_in[24];
  const float* projW = (const float*)d_in[25];
  const float* projb = (const float*)d_in[26];

  char* p = (char*)d_ws;
  size_t o = 0;
  auto take = [&](size_t bytes)->char*{ char* r = p + o; o = (o + bytes + 255) & ~(size_t)255; return r; };
  int*   deg  = (int*)  take(4*N_NODES);
  int*   fill = (int*)  take(4*N_NODES);
  float* wsum = (float*)take(4*N_NODES);
  size_t zbytes = o;                        // deg+fill+wsum zeroed each call
  int*   off   = (int*)  take(4*(N_NODES+1));
  int*   csrs  = (int*)  take(4*NE_TOT);
  float* csrw  = (float*)take(4*NE_TOT);
  u16*   xl    = (u16*)  take(2UL*N_NODES*EMB);
  u16*   xr    = (u16*)  take(2UL*N_NODES*EMB);
  u16*   h1b   = (u16*)  take(2UL*N_NODES*EMB);
  float* hsave = (float*)take(4UL*NB*RH);
  u16*   wb    = (u16*)  take(2UL*WB_TOT);
  u16*   hseq  = (u16*)  take(2UL*NB*NTT*RH);
  u16*   xemb  = (u16*)  take(2UL*NB*NTT*EMB);
  size_t fixed_end = o;
  // xg chunk length: largest of {200,100,50,25} that fits ws_size
  int chk = 200;
  while(chk > 25 && fixed_end + 2UL*NB*(size_t)chk*G3 > ws_size) chk /= 2;
  u16*   xgc  = (u16*)  take(2UL*NB*(size_t)chk*G3);

  const u16* wb_g0l  = wb;
  const u16* wb_g0r  = wb + 16384;
  const u16* wb_g1l  = wb + 32768;
  const u16* wb_g1r  = wb + 49152;
  const u16* wb_wih  = wb + 65536;
  const u16* wb_whh  = wb + 163840;
  const u16* wb_proj = wb + 360448;
  const u16* wb_emb  = wb + WB_W;

  float* outP = (float*)d_out;                     // h_proj [256,200,128] f32
  float* outE = outP + (size_t)NB*NTT*EMB;         // skill_embs [10000,128] f32

  hipMemsetAsync(d_ws, 0, zbytes, stream);
  k_prep<<<NDEG_BLK + NCVT_BLK, 256, 0, stream>>>(eidx, ew, deg, wsum,
                                 gW[0][0], gW[0][2], gW[1][0], gW[1][2],
                                 Wih, Whh, projW, emb, (u16*)wb);
  k_scan<<<1, 1024, 0, stream>>>(deg, wsum, off);
  k_scatter<<<(NE_TOT+255)/256, 256, 0, stream>>>(eidx, ew, wsum, off, fill, csrs, csrw);

  dim3 gN2((N_NODES+127)/128, EMB/64, 2);
  // layer 0: xl and xr in one paired launch
  k_gemm2<<<gN2, 256, 0, stream>>>(wb_emb, wb_g0l, wb_g0r, gW[0][1], gW[0][3],
                                   xl, xr, N_NODES, EMB, EMB);
  k_attn<true><<<N_NODES/4, 256, 0, stream>>>(off, csrs, csrw, xl, xr,
                                 gW[0][4], gW[0][5], gW[0][6], nullptr, h1b);
  // layer 1
  k_gemm2<<<gN2, 256, 0, stream>>>(h1b, wb_g1l, wb_g1r, gW[1][1], gW[1][3],
                                   xl, xr, N_NODES, EMB, EMB);
  k_attn<false><<<N_NODES/4, 256, 0, stream>>>(off, csrs, csrw, xl, xr,
                                 gW[1][4], gW[1][5], gW[1][6], outE, nullptr);

  // gather once: xemb = bf16(skill_embs[skills] + resp_emb[resp])
  k_gather<<<(NB*NTT*EMB/8 + 255)/256, 256, 0, stream>>>(outE, remb, skills, resp, xemb);

  // chunked: xg = xemb @ Wih^T + bih (bf16, MI=4), then GRU chunk
  for(int t0=0; t0<NTT; t0+=chk){
    k_gemm<3,false,4><<<dim3(NB*chk/256, G3/64), 256, 0, stream>>>(xemb, wb_wih, bih, xgc,
                                 NB*chk, G3, EMB, t0, chk, nullptr);
    k_gru<<<NB, 256, 0, stream>>>(xgc, wb_whh, bhh, lens, hseq, hsave, t0, t0+chk, chk);
  }
  // proj: A = hseq bf16 (MI=4), out f32 (+ lens mask; hseq rows t>=len are zeros)
  k_gemm<2,true,4><<<dim3(NB*NTT/256, EMB/64), 256, 0, stream>>>(hseq, wb_proj, projb, outP,
                                 NB*NTT, EMB, RH, 0, 0, lens);
}

// Round 21
// 581.935 us; speedup vs baseline: 3.1759x; 1.0231x over previous
//
#include <hip/hip_runtime.h>

#define N_NODES 10000
#define EMB     128
#define NE      320000
#define NE_TOT  330000   // + one self-loop per node
#define NB      256
#define NTT     200
#define RH      256
#define G3      768

typedef unsigned short u16;
typedef u16    u16x8  __attribute__((ext_vector_type(8)));
typedef __bf16 bf16x8 __attribute__((ext_vector_type(8)));
typedef float  f32x4  __attribute__((ext_vector_type(4)));

static __device__ __forceinline__ float bf2f(u16 u){
  unsigned int x = ((unsigned int)u) << 16;
  return __builtin_bit_cast(float, x);
}
static __device__ __forceinline__ u16 f2bf(float f){
  unsigned int x = __builtin_bit_cast(unsigned int, f);
  x += 0x7fffu + ((x >> 16) & 1u);
  return (u16)(x >> 16);
}

// async global->LDS, 16B per lane; lds dest must be the WAVE base (HW adds lane*16)
static __device__ __forceinline__ void stage16(const u16* g, u16* lds_wavebase, u16* lds_lane){
#if __has_builtin(__builtin_amdgcn_global_load_lds)
  __builtin_amdgcn_global_load_lds(
      (const __attribute__((address_space(1))) unsigned int*)g,
      (__attribute__((address_space(3))) unsigned int*)lds_wavebase, 16, 0, 0);
  (void)lds_lane;
#else
  *(u16x8*)lds_lane = *(const u16x8*)g;
#endif
}

// static-index selects (rule #20: no runtime-indexed register arrays)
static __device__ __forceinline__ float self4(f32x4 v, int r){
  float lo = (r&1) ? v[1] : v[0];
  float hi = (r&1) ? v[3] : v[2];
  return (r&2) ? hi : lo;
}
static __device__ __forceinline__ f32x4 seltile(f32x4 a, f32x4 b, f32x4 c, f32x4 d, int jt){
  f32x4 r;
  #pragma unroll
  for(int e=0;e<4;++e){
    float ab = (jt&1) ? b[e] : a[e];
    float cd = (jt&1) ? d[e] : c[e];
    r[e] = (jt&2) ? cd : ab;
  }
  return r;
}

// ---------------- fused: edge-degree histogram + all f32->bf16 preconversion ----------------
// wb layout: g0l@0, g0r@16384, g1l@32768, g1r@49152, wih@65536, whh@163840,
//            proj@360448, emb@393216
#define WB_W   393216
#define WB_TOT (WB_W + N_NODES*EMB)
#define NDEG_BLK ((NE + 255)/256)
#define NCVT_BLK ((WB_TOT + 255)/256)
__global__ __launch_bounds__(256) void k_prep(
    const int* __restrict__ eidx, const float* __restrict__ ew,
    int* __restrict__ deg, float* __restrict__ wsum,
    const float* __restrict__ g0l, const float* __restrict__ g0r,
    const float* __restrict__ g1l, const float* __restrict__ g1r,
    const float* __restrict__ wih, const float* __restrict__ whh,
    const float* __restrict__ pw, const float* __restrict__ emb,
    u16* __restrict__ wb)
{
  int bid = blockIdx.x;
  if(bid < NDEG_BLK){
    int i = bid*256 + threadIdx.x;
    if(i >= NE) return;
    int d = eidx[NE + i];
    atomicAdd(&deg[d], 1);
    atomicAdd(&wsum[d], ew[i]);
  } else {
    int i = (bid - NDEG_BLK)*256 + threadIdx.x;
    if(i >= WB_TOT) return;
    float v;
    if(i < 65536){
      int seg = i >> 14, r = i & 16383;
      const float* s = (seg==0) ? g0l : (seg==1) ? g0r : (seg==2) ? g1l : g1r;
      v = s[r];
    } else if(i < 163840){ v = wih[i - 65536]; }
    else if(i < 360448){ v = whh[i - 163840]; }
    else if(i < WB_W)  { v = pw [i - 360448]; }
    else               { v = emb[i - WB_W]; }
    wb[i] = f2bf(v);
  }
}

__global__ __launch_bounds__(1024) void k_scan(const int* __restrict__ deg,
                      float* __restrict__ wsum, int* __restrict__ off){
  __shared__ int part[1024];
  int tid = threadIdx.x;
  int n0 = tid*10;
  int s = 0;
  for(int i=0;i<10;++i){ int n=n0+i; if(n<N_NODES) s += deg[n]+1; }
  part[tid] = s;
  for(int i=0;i<10;++i){
    int n=n0+i;
    if(n<N_NODES){ int d=deg[n]; wsum[n] = wsum[n] / (float)(d>1?d:1); }
  }
  __syncthreads();
  for(int st=1; st<1024; st<<=1){
    int v = (tid>=st) ? part[tid-st] : 0;
    __syncthreads();
    part[tid] += v;
    __syncthreads();
  }
  int base = tid ? part[tid-1] : 0;
  for(int i=0;i<10;++i){ int n=n0+i; if(n<N_NODES){ off[n]=base; base += deg[n]+1; } }
  if(tid==999) off[N_NODES] = base;
}

__global__ void k_scatter(const int* __restrict__ eidx, const float* __restrict__ ew,
                          const float* __restrict__ la, const int* __restrict__ off,
                          int* __restrict__ fill, int* __restrict__ csrs, float* __restrict__ csrw){
  int i = blockIdx.x*256 + threadIdx.x;
  if(i >= NE_TOT) return;
  int s, d; float w;
  if(i < NE){ s = eidx[i]; d = eidx[NE+i]; w = ew[i]; }
  else      { int n = i-NE; s=n; d=n; w = la[n]; }   // self-loop, weight = mean incoming
  int pos = off[d] + atomicAdd(&fill[d], 1);
  csrs[pos] = s; csrw[pos] = w;
}

// ---------------- gather: xemb = bf16(skill_embs[skills] + resp_emb[resp]) ----------------
__global__ __launch_bounds__(256) void k_gather(
    const float* __restrict__ embN, const float* __restrict__ remb,
    const int* __restrict__ skills, const int* __restrict__ resp,
    u16* __restrict__ xemb){
  int i = blockIdx.x*256 + threadIdx.x;           // one per 8 elems
  if(i >= NB*NTT*EMB/8) return;
  int row = i >> 4;                               // 16 groups of 8 per row
  int g8  = (i & 15) * 8;
  const float* ar = embN + (size_t)skills[row]*EMB + g8;
  const float* rr = remb + (size_t)resp[row]*EMB + g8;
  u16x8 v;
  #pragma unroll
  for(int e=0;e<8;++e) v[e] = f2bf(ar[e] + rr[e]);
  *(u16x8*)(xemb + (size_t)row*EMB + g8) = v;
}

// ---------------- MFMA GEMM: C = A @ W^T + bias (A,W bf16) ----------------
// AMODE: 2 = A bf16 [M,K]; 3 = A bf16 with chunk row map (row -> b*NTT+t0+row%chk).
// MI: rows per wave = MI*16 (block = MI*64 rows).
// lens != null (proj): row=(b*NTT+t), t>=lens[b] -> bias only.
template<int AMODE, bool OUTF32, int MI>
__global__ __launch_bounds__(256) void k_gemm(
    const u16* __restrict__ Av, const u16* __restrict__ W, const float* __restrict__ bias,
    void* __restrict__ out,
    int M, int N, int K,
    int t0, int chk,
    const int* __restrict__ lens)
{
  int tid = threadIdx.x;
  int wid = tid >> 6, l = tid & 63;
  int lr = l & 15, lg = l >> 4;
  int bm = blockIdx.x*(MI*64) + wid*(MI*16);
  int bn = blockIdx.y*64;
  f32x4 acc[MI][4] = {};
  int nk = K >> 5;
  for(int kt=0; kt<nk; ++kt){
    int k0 = kt*32 + lg*8;
    bf16x8 af[MI];
    #pragma unroll
    for(int mi=0; mi<MI; ++mi){
      int row = bm + mi*16 + lr;
      u16x8 v = {0,0,0,0,0,0,0,0};
      if(row < M){
        if constexpr(AMODE == 3){
          int b = row / chk, tt = row - b*chk;
          int arow = b*NTT + t0 + tt;
          v = *(const u16x8*)(Av + (size_t)arow*K + k0);
        } else {
          v = *(const u16x8*)(Av + (size_t)row*K + k0);
        }
      }
      af[mi] = __builtin_bit_cast(bf16x8, v);
    }
    #pragma unroll
    for(int nt=0; nt<4; ++nt){
      int col = bn + nt*16 + lr;
      u16x8 wv = *(const u16x8*)(W + (size_t)col*K + k0);
      bf16x8 bfr = __builtin_bit_cast(bf16x8, wv);
      #pragma unroll
      for(int mi=0; mi<MI; ++mi)
        acc[mi][nt] = __builtin_amdgcn_mfma_f32_16x16x32_bf16(af[mi], bfr, acc[mi][nt], 0,0,0);
    }
  }
  #pragma unroll
  for(int mi=0; mi<MI; ++mi){
    #pragma unroll
    for(int nt=0; nt<4; ++nt){
      int col = bn + nt*16 + lr;
      float bc = bias[col];
      #pragma unroll
      for(int r=0; r<4; ++r){
        int row = bm + mi*16 + lg*4 + r;
        if(row >= M) continue;
        float v = acc[mi][nt][r] + bc;
        if(lens){ int b = row/NTT; int t = row - b*NTT; if(t >= lens[b]) v = bc; }
        if constexpr(OUTF32) ((float*)out)[(size_t)row*N + col] = v;
        else                 ((u16*) out)[(size_t)row*N + col] = f2bf(v);
      }
    }
  }
}

// paired GEMM: z=0 -> (W0,b0,out0), z=1 -> (W1,b1,out1); bf16 A and out, MI=2
__global__ __launch_bounds__(256) void k_gemm2(
    const u16* __restrict__ Av,
    const u16* __restrict__ W0, const u16* __restrict__ W1,
    const float* __restrict__ b0, const float* __restrict__ b1,
    u16* __restrict__ out0, u16* __restrict__ out1,
    int M, int N, int K)
{
  const u16*   W    = blockIdx.z ? W1 : W0;
  const float* bias = blockIdx.z ? b1 : b0;
  u16*         out  = blockIdx.z ? out1 : out0;
  int tid = threadIdx.x;
  int wid = tid >> 6, l = tid & 63;
  int lr = l & 15, lg = l >> 4;
  int bm = blockIdx.x*128 + wid*32;
  int bn = blockIdx.y*64;
  f32x4 acc[2][4] = {};
  int nk = K >> 5;
  for(int kt=0; kt<nk; ++kt){
    int k0 = kt*32 + lg*8;
    bf16x8 af[2];
    #pragma unroll
    for(int mi=0; mi<2; ++mi){
      int row = bm + mi*16 + lr;
      u16x8 v = {0,0,0,0,0,0,0,0};
      if(row < M) v = *(const u16x8*)(Av + (size_t)row*K + k0);
      af[mi] = __builtin_bit_cast(bf16x8, v);
    }
    #pragma unroll
    for(int nt=0; nt<4; ++nt){
      int col = bn + nt*16 + lr;
      u16x8 wv = *(const u16x8*)(W + (size_t)col*K + k0);
      bf16x8 bfr = __builtin_bit_cast(bf16x8, wv);
      acc[0][nt] = __builtin_amdgcn_mfma_f32_16x16x32_bf16(af[0], bfr, acc[0][nt], 0,0,0);
      acc[1][nt] = __builtin_amdgcn_mfma_f32_16x16x32_bf16(af[1], bfr, acc[1][nt], 0,0,0);
    }
  }
  #pragma unroll
  for(int mi=0; mi<2; ++mi){
    #pragma unroll
    for(int nt=0; nt<4; ++nt){
      int col = bn + nt*16 + lr;
      float bc = bias[col];
      #pragma unroll
      for(int r=0; r<4; ++r){
        int row = bm + mi*16 + lg*4 + r;
        if(row >= M) continue;
        out[(size_t)row*N + col] = f2bf(acc[mi][nt][r] + bc);
      }
    }
  }
}

// ---------------- GATv2 attention + aggregate + bias + ELU ----------------
// per-edge logit: message pre-act + LeakyReLU + per-head 16-lane dot (4x shfl)
static __device__ __forceinline__ float edge_logit(unsigned u, float w,
    float xrx, float xry, float wex, float wey, float atx, float aty){
  float ax = bf2f((u16)u)       + xrx + w*wex;
  float ay = bf2f((u16)(u>>16)) + xry + w*wey;
  ax = ax > 0.f ? ax : 0.2f*ax;
  ay = ay > 0.f ? ay : 0.2f*ay;
  float c = ax*atx + ay*aty;
  c += __shfl_xor(c,1); c += __shfl_xor(c,2); c += __shfl_xor(c,4); c += __shfl_xor(c,8);
  return c;
}

// BF16OUT: write bf16 (intermediate h1) else f32 (skill_embs output).
// Pass 1: 8-edge pipelined, logits cached in LDS (exact f32, per head group).
// Pass 2: cached edges skip recompute entirely (read exact c from LDS), 8-edge
// pipelined gathers; accumulation in ORIGINAL edge order -> bit-identical.
#define ECAP 128
template<bool BF16OUT>
__global__ __launch_bounds__(256) void k_attn(
    const int* __restrict__ off, const int* __restrict__ csrs, const float* __restrict__ csrw,
    const u16* __restrict__ xl, const u16* __restrict__ xr,
    const float* __restrict__ We, const float* __restrict__ att, const float* __restrict__ bias,
    float* __restrict__ houtF, u16* __restrict__ houtB)
{
  __shared__ float lds_c[4][ECAP][4];   // [wave][edge][head] = 8 KB
  int wid = threadIdx.x >> 6, l = threadIdx.x & 63;
  int n = blockIdx.x*4 + wid;
  int d0 = 2*l;
  int head = l >> 4;
  bool cw = (l & 15) == 0;              // head-group writer lane
  const unsigned int* xl2 = (const unsigned int*)xl;
  unsigned int xru = ((const unsigned int*)xr)[n*64 + l];
  float xrx = bf2f((u16)xru), xry = bf2f((u16)(xru>>16));
  float wex = We[d0],  wey = We[d0+1];
  float atx = att[d0], aty = att[d0+1];
  int p0 = off[n], p1 = off[n+1];

  // pass 1: max logit (8-edge pipelined, in-order fmax) + LDS logit cache
  float mx = -1e30f;
  int p = p0;
  for(; p+8 <= p1; p += 8){
    int s0=csrs[p],s1=csrs[p+1],s2=csrs[p+2],s3=csrs[p+3],
        s4=csrs[p+4],s5=csrs[p+5],s6=csrs[p+6],s7=csrs[p+7];
    float w0=csrw[p],w1=csrw[p+1],w2=csrw[p+2],w3=csrw[p+3],
          w4=csrw[p+4],w5=csrw[p+5],w6=csrw[p+6],w7=csrw[p+7];
    unsigned u0=xl2[s0*64+l],u1=xl2[s1*64+l],u2=xl2[s2*64+l],u3=xl2[s3*64+l],
             u4=xl2[s4*64+l],u5=xl2[s5*64+l],u6=xl2[s6*64+l],u7=xl2[s7*64+l];
    #define P1E(i,ui,wi) { float c = edge_logit(ui, wi, xrx, xry, wex, wey, atx, aty); \
      int idx = p + (i) - p0; if(cw && idx < ECAP) lds_c[wid][idx][head] = c; \
      mx = fmaxf(mx, c); }
    P1E(0,u0,w0) P1E(1,u1,w1) P1E(2,u2,w2) P1E(3,u3,w3)
    P1E(4,u4,w4) P1E(5,u5,w5) P1E(6,u6,w6) P1E(7,u7,w7)
  }
  for(; p < p1; ++p){
    int s = csrs[p]; float w = csrw[p];
    unsigned u = xl2[s*64 + l];
    float c = edge_logit(u, w, xrx, xry, wex, wey, atx, aty);
    int idx = p - p0; if(cw && idx < ECAP) lds_c[wid][idx][head] = c;
    mx = fmaxf(mx, c);
  }

  // pass 2: softmax-weighted aggregation; cached edges read exact c from LDS
  float den = 0.f, a0 = 0.f, a1 = 0.f;
  int pc = (p1 - p0 < ECAP) ? p1 : p0 + ECAP;   // cached range end
  p = p0;
  for(; p+8 <= pc; p += 8){
    int s0=csrs[p],s1=csrs[p+1],s2=csrs[p+2],s3=csrs[p+3],
        s4=csrs[p+4],s5=csrs[p+5],s6=csrs[p+6],s7=csrs[p+7];
    unsigned u0=xl2[s0*64+l],u1=xl2[s1*64+l],u2=xl2[s2*64+l],u3=xl2[s3*64+l],
             u4=xl2[s4*64+l],u5=xl2[s5*64+l],u6=xl2[s6*64+l],u7=xl2[s7*64+l];
    #define P2E(i,ui) { float al = __expf(lds_c[wid][p+(i)-p0][head] - mx); \
      den += al; a0 += al*bf2f((u16)(ui)); a1 += al*bf2f((u16)((ui)>>16)); }
    P2E(0,u0) P2E(1,u1) P2E(2,u2) P2E(3,u3)
    P2E(4,u4) P2E(5,u5) P2E(6,u6) P2E(7,u7)
  }
  for(; p < pc; ++p){
    int s = csrs[p];
    unsigned u = xl2[s*64 + l];
    float al = __expf(lds_c[wid][p-p0][head] - mx);
    den += al; a0 += al*bf2f((u16)u); a1 += al*bf2f((u16)(u>>16));
  }
  for(; p < p1; ++p){                     // beyond cache: full recompute
    int s = csrs[p]; float w = csrw[p];
    unsigned u = xl2[s*64 + l];
    float al = __expf(edge_logit(u, w, xrx, xry, wex, wey, atx, aty) - mx);
    den += al; a0 += al*bf2f((u16)u); a1 += al*bf2f((u16)(u>>16));
  }

  float inv = 1.f/(den + 1e-16f);
  float o0 = a0*inv + bias[d0];
  float o1 = a1*inv + bias[d0+1];
  o0 = o0 > 0.f ? o0 : (__expf(o0) - 1.f);   // ELU
  o1 = o1 > 0.f ? o1 : (__expf(o1) - 1.f);
  if constexpr(BF16OUT){
    houtB[n*EMB + d0]   = f2bf(o0);
    houtB[n*EMB + d0+1] = f2bf(o1);
  } else {
    houtF[n*EMB + d0]   = o0;
    houtF[n*EMB + d0+1] = o1;
  }
}

// ---------------- GRU: 256 blocks x 1 batch row, 4 waves (1/SIMD) ----------------
// R15/R17-verbatim MFMA/gate schedule (DO NOT reorder — R16 failure). Triple-buffered
// staging (prefetch depth 2); end-of-step vmcnt(3). FROZEN at ~310 us.

#define DECLW(nt) f32x4 wf_##nt##_0, wf_##nt##_1, wf_##nt##_2, wf_##nt##_3, \
                        wf_##nt##_4, wf_##nt##_5, wf_##nt##_6, wf_##nt##_7;

#define LDW1(nt,kt) { u16x8 wv = *(const u16x8*)(wr + (kt)*32 + lg*8); \
  wf_##nt##_##kt = __builtin_bit_cast(f32x4, wv); \
  asm volatile("" : "+a"(wf_##nt##_##kt)); }

#define LDW(nt) { int nrow = ((nt)>>2)*256 + wid*64 + ((nt)&3)*16 + lr; \
  const u16* wr = whb + (size_t)nrow*RH; \
  LDW1(nt,0) LDW1(nt,1) LDW1(nt,2) LDW1(nt,3) LDW1(nt,4) LDW1(nt,5) LDW1(nt,6) LDW1(nt,7) }

// D = A(AGPR wf) * B(VGPR h-broadcast) + D
#define MFMA1(acc, wf, hf) asm volatile( \
  "v_mfma_f32_16x16x32_bf16 %0, %1, %2, %0" : "+v"(acc) : "a"(wf), "v"(hf));

#define MST(kt) { \
  f32x4 hf = __builtin_bit_cast(f32x4, *(const u16x8*)(hrd + (kt)*32 + lg*8)); \
  MFMA1(acc0,  wf_0_##kt,  hf) MFMA1(acc1,  wf_1_##kt,  hf) \
  MFMA1(acc2,  wf_2_##kt,  hf) MFMA1(acc3,  wf_3_##kt,  hf) \
  MFMA1(acc4,  wf_4_##kt,  hf) MFMA1(acc5,  wf_5_##kt,  hf) \
  MFMA1(acc6,  wf_6_##kt,  hf) MFMA1(acc7,  wf_7_##kt,  hf) \
  MFMA1(acc8,  wf_8_##kt,  hf) MFMA1(acc9,  wf_9_##kt,  hf) \
  MFMA1(acc10, wf_10_##kt, hf) MFMA1(acc11, wf_11_##kt, hf) }

__global__ __launch_bounds__(256,1) __attribute__((amdgpu_waves_per_eu(1,1))) void k_gru(
    const u16* __restrict__ xgc, const u16* __restrict__ whb, const float* __restrict__ bhh,
    const int* __restrict__ lens, u16* __restrict__ hseq, float* __restrict__ hsave,
    int t0, int t1, int chk)
{
  int tid = threadIdx.x;
  int wid = tid >> 6, l = tid & 63;
  int lr = l & 15, lg = l >> 4;
  int b = blockIdx.x;                       // one batch row per block
  __shared__ __align__(16) u16 lds_h[2][256];    // 1 KB, double-buffered
  __shared__ __align__(16) u16 lds_xg[3][1024];  // 6 KB, TRIPLE-buffered

  int mylen = lens[b];
  int tend = mylen < t1 ? mylen : t1;
  int nsteps = tend - t0; if(nsteps < 0) nsteps = 0;

  // Whh bf16 A-fragments: 96 AGPR-pinned values (layout: row=lr, k=lg*8+e)
  DECLW(0) DECLW(1) DECLW(2)  DECLW(3)  DECLW(4)  DECLW(5)
  DECLW(6) DECLW(7) DECLW(8)  DECLW(9)  DECLW(10) DECLW(11)
  LDW(0) LDW(1) LDW(2)  LDW(3)  LDW(4)  LDW(5)
  LDW(6) LDW(7) LDW(8)  LDW(9)  LDW(10) LDW(11)

  // this lane's gate assignment: j = wid*64 + (lr>>2)*16 + lg*4 + (lr&3)
  int jt   = lr >> 2;
  int rsel = lr & 3;
  int j    = wid*64 + jt*16 + lg*4 + rsel;
  float bhR = bhh[      j];
  float bhZ = bhh[256 + j];
  float bhN = bhh[512 + j];

  // h init into lds_h[0] (linear, single row)
  {
    u16 v = 0;
    if(t0 > 0) v = f2bf(hsave[(size_t)b*RH + tid]);
    lds_h[0][tid] = v;
  }
  float hst = (t0>0) ? hsave[(size_t)b*RH + j] : 0.f;

  // staging: 96 granules of 16B; wave0 -> granules 0-63, wave1 -> 64-127 (96-127 pad)
  int g = (wid==0) ? l : (64 + (l & 31));   // wave1 lanes 32-63 duplicate 64-95 reads
  const u16* xsrc = xgc + ((size_t)b*chk)*G3 + g*8;
  int lwb = (wid==0) ? 0 : 512;             // wave LDS base in u16 units

  // prologue: stage t0 -> buf0 and t0+1 -> buf1, drain, publish
  if(nsteps > 0 && wid < 2)
    stage16(xsrc, &lds_xg[0][lwb], nullptr);
  xsrc += G3;
  if(nsteps > 1 && wid < 2)
    stage16(xsrc, &lds_xg[1][lwb], nullptr);
  xsrc += G3;
  asm volatile("s_waitcnt vmcnt(0)" ::: "memory");
  asm volatile("s_waitcnt lgkmcnt(0)" ::: "memory");
  __builtin_amdgcn_sched_barrier(0);
  __builtin_amdgcn_s_barrier();
  __builtin_amdgcn_sched_barrier(0);

  u16* outbase = hseq + ((size_t)b*NTT + t0)*RH;
  for(int s=0; s<nsteps; ++s){
    const u16* hrd = &lds_h[s&1][0];
    u16*       hwr = &lds_h[(s+1)&1][0];
    const u16* xgr = &lds_xg[s%3][0];
    int more = (s+1 < nsteps);

    // prefetch depth 2: stage t(s+2) into buf[(s+2)%3]
    if(s+2 < nsteps && wid < 2)
      stage16(xsrc, &lds_xg[(s+2)%3][lwb], nullptr);
    xsrc += G3;

    // hg = Whh @ h  (A from AGPRs, B = broadcast h row; no masking needed)
    f32x4 acc0 = {}, acc1 = {}, acc2 = {}, acc3 = {}, acc4 = {}, acc5 = {},
          acc6 = {}, acc7 = {}, acc8 = {}, acc9 = {}, acc10 = {}, acc11 = {};
    MST(0) MST(1) MST(2) MST(3) MST(4) MST(5) MST(6) MST(7)

    // gates: 1 chain per lane (64/wave). acc rows replicated across cols.
    {
      f32x4 aR = seltile(acc0, acc1, acc2,  acc3,  jt);
      f32x4 aZ = seltile(acc4, acc5, acc6,  acc7,  jt);
      f32x4 aN = seltile(acc8, acc9, acc10, acc11, jt);
      float hr = self4(aR, rsel) + bhR;
      float hz = self4(aZ, rsel) + bhZ;
      float hn = self4(aN, rsel) + bhN;
      float xrv = bf2f(xgr[      j]);
      float xzv = bf2f(xgr[256 + j]);
      float xnv = bf2f(xgr[512 + j]);
      float rg = 1.f/(1.f + __expf(-(xrv + hr)));
      float zg = 1.f/(1.f + __expf(-(xzv + hz)));
      float nn = xnv + rg*hn;
      float tg = 1.f - 2.f/(__expf(2.f*nn) + 1.f);   // tanh
      float hv = (1.f - zg)*tg + zg*hst;
      hst = hv;
      u16 hb = f2bf(hv);
      hwr[j] = hb;
      outbase[j] = hb;
    }
    outbase += RH;

    if(more){
      asm volatile("s_waitcnt lgkmcnt(0)" ::: "memory");  // h[nxt] write + LDS reads done
      asm volatile("s_waitcnt vmcnt(3)" ::: "memory");    // stage(s+1) retired; newer ops fly
      __builtin_amdgcn_sched_barrier(0);
      __builtin_amdgcn_s_barrier();                       // publish h[nxt] + xg[nxt]
      __builtin_amdgcn_sched_barrier(0);
    }
  }

  // zero-fill [max(tend,t0), t1) so hseq is fully written & deterministic
  {
    u16* zp = outbase;
    for(int t = (tend > t0 ? tend : t0); t < t1; ++t){
      zp[j] = 0;
      zp += RH;
    }
  }

  // save exact f32 state for next chunk
  hsave[(size_t)b*RH + j] = hst;
}

// ---------------- launcher ----------------
extern "C" void kernel_launch(void* const* d_in, const int* in_sizes, int n_in,
                              void* d_out, int out_size, void* d_ws, size_t ws_size,
                              hipStream_t stream){
  (void)in_sizes; (void)n_in; (void)out_size;
  const int*   skills = (const int*)d_in[0];
  const int*   resp   = (const int*)d_in[1];
  const int*   lens   = (const int*)d_in[2];
  const int*   eidx   = (const int*)d_in[3];
  const float* ew     = (const float*)d_in[4];
  const float* emb    = (const float*)d_in[5];
  const float* gW[2][7];
  for(int l2=0;l2<2;++l2) for(int j=0;j<7;++j) gW[l2][j] = (const float*)d_in[6 + l2*7 + j];
  const float* remb  = (const float*)d_in[20];
  const float* Wih   = (const float*)d_in[21];
  const float* Whh   = (const float*)d_in[22];
  const float* bih   = (const float*)d_in[23];
  const float* bhh   = (const float*)d_in[24];
  const float* projW = (const float*)d_in[25];
  const float* projb = (const float*)d_in[26];

  char* p = (char*)d_ws;
  size_t o = 0;
  auto take = [&](size_t bytes)->char*{ char* r = p + o; o = (o + bytes + 255) & ~(size_t)255; return r; };
  int*   deg  = (int*)  take(4*N_NODES);
  int*   fill = (int*)  take(4*N_NODES);
  float* wsum = (float*)take(4*N_NODES);
  size_t zbytes = o;                        // deg+fill+wsum zeroed each call
  int*   off   = (int*)  take(4*(N_NODES+1));
  int*   csrs  = (int*)  take(4*NE_TOT);
  float* csrw  = (float*)take(4*NE_TOT);
  u16*   xl    = (u16*)  take(2UL*N_NODES*EMB);
  u16*   xr    = (u16*)  take(2UL*N_NODES*EMB);
  u16*   h1b   = (u16*)  take(2UL*N_NODES*EMB);
  float* hsave = (float*)take(4UL*NB*RH);
  u16*   wb    = (u16*)  take(2UL*WB_TOT);
  u16*   hseq  = (u16*)  take(2UL*NB*NTT*RH);
  u16*   xemb  = (u16*)  take(2UL*NB*NTT*EMB);
  size_t fixed_end = o;
  // xg chunk length: largest of {200,100,50,25} that fits ws_size
  int chk = 200;
  while(chk > 25 && fixed_end + 2UL*NB*(size_t)chk*G3 > ws_size) chk /= 2;
  u16*   xgc  = (u16*)  take(2UL*NB*(size_t)chk*G3);

  const u16* wb_g0l  = wb;
  const u16* wb_g0r  = wb + 16384;
  const u16* wb_g1l  = wb + 32768;
  const u16* wb_g1r  = wb + 49152;
  const u16* wb_wih  = wb + 65536;
  const u16* wb_whh  = wb + 163840;
  const u16* wb_proj = wb + 360448;
  const u16* wb_emb  = wb + WB_W;

  float* outP = (float*)d_out;                     // h_proj [256,200,128] f32
  float* outE = outP + (size_t)NB*NTT*EMB;         // skill_embs [10000,128] f32

  hipMemsetAsync(d_ws, 0, zbytes, stream);
  k_prep<<<NDEG_BLK + NCVT_BLK, 256, 0, stream>>>(eidx, ew, deg, wsum,
                                 gW[0][0], gW[0][2], gW[1][0], gW[1][2],
                                 Wih, Whh, projW, emb, (u16*)wb);
  k_scan<<<1, 1024, 0, stream>>>(deg, wsum, off);
  k_scatter<<<(NE_TOT+255)/256, 256, 0, stream>>>(eidx, ew, wsum, off, fill, csrs, csrw);

  dim3 gN2((N_NODES+127)/128, EMB/64, 2);
  // layer 0: xl and xr in one paired launch
  k_gemm2<<<gN2, 256, 0, stream>>>(wb_emb, wb_g0l, wb_g0r, gW[0][1], gW[0][3],
                                   xl, xr, N_NODES, EMB, EMB);
  k_attn<true><<<N_NODES/4, 256, 0, stream>>>(off, csrs, csrw, xl, xr,
                                 gW[0][4], gW[0][5], gW[0][6], nullptr, h1b);
  // layer 1
  k_gemm2<<<gN2, 256, 0, stream>>>(h1b, wb_g1l, wb_g1r, gW[1][1], gW[1][3],
                                   xl, xr, N_NODES, EMB, EMB);
  k_attn<false><<<N_NODES/4, 256, 0, stream>>>(off, csrs, csrw, xl, xr,
                                 gW[1][4], gW[1][5], gW[1][6], outE, nullptr);

  // gather once: xemb = bf16(skill_embs[skills] + resp_emb[resp])
  k_gather<<<(NB*NTT*EMB/8 + 255)/256, 256, 0, stream>>>(outE, remb, skills, resp, xemb);

  // chunked: xg = xemb @ Wih^T + bih (bf16, MI=4), then GRU chunk
  for(int t0=0; t0<NTT; t0+=chk){
    k_gemm<3,false,4><<<dim3(NB*chk/256, G3/64), 256, 0, stream>>>(xemb, wb_wih, bih, xgc,
                                 NB*chk, G3, EMB, t0, chk, nullptr);
    k_gru<<<NB, 256, 0, stream>>>(xgc, wb_whh, bhh, lens, hseq, hsave, t0, t0+chk, chk);
  }
  // proj: A = hseq bf16 (MI=4), out f32 (+ lens mask; hseq rows t>=len are zeros)
  k_gemm<2,true,4><<<dim3(NB*NTT/256, EMB/64), 256, 0, stream>>>(hseq, wb_proj, projb, outP,
                                 NB*NTT, EMB, RH, 0, 0, lens);
}